// Round 6
// baseline (598.002 us; speedup 1.0000x reference)
//
#include <hip/hip_runtime.h>
#include <cstdint>
#include <cstddef>

// ---------------- problem constants ----------------
#define NBATCH 8
#define MID 256
#define HIMG 64
#define WIMG 64
#define NA 9
#define NPRE 6000
#define NPOST 300
#define NANCH (HIMG*WIMG*NA)   // 36864
#define NWORDS 94              // ceil(6000/64)
#define GCOLS 6016             // 94*64 padded columns

// output float offsets
#define OUT_LOC   0
#define OUT_SCORE 1179648
#define OUT_ROIS  1769472
#define OUT_RIDX  1779072
#define OUT_ANCH  1781472

// workspace byte offsets
#define H_OFF    0ul
#define H_BYTES  (8ul*256*64*64*4)         // 33554432
#define WT_OFF   (H_OFF + H_BYTES)
#define WT_BYTES (2304ul*256*4)            // 2359296 = exactly w3h+w3l (half)
#define BOX_OFF  (WT_OFF + WT_BYTES)
#define BOX_BYTES (8ul*36864*4*4)          // 4718592
#define U_OFF    (BOX_OFF + BOX_BYTES)
#define U_BYTES  (8ul*36864*4)
#define CK_OFF   (U_OFF + U_BYTES)
#define CK_BYTES (8ul*8192*8)
#define CC_OFF   (CK_OFF + CK_BYTES)
#define CC_BYTES 64ul
#define BK_OFF   (CC_OFF + CC_BYTES)
#define BK_BYTES (8ul*6000*16)
#define M_OFF    (BK_OFF + BK_BYTES + 64)
#define M_BYTES  (8ul*NWORDS*GCOLS*8)      // 36.2 MB, column-major mask

typedef _Float16 f16x8 __attribute__((ext_vector_type(8)));
typedef _Float16 f16x4 __attribute__((ext_vector_type(4)));
typedef float f32x16 __attribute__((ext_vector_type(16)));

// ---------------- weight prep: conv1_w[oc][ic][ky][kx] -> w3{h,l}[s][kb][g][oc][8] fp16 hi/lo ----------
__global__ __launch_bounds__(256) void k_prep_w(const float* __restrict__ w,
                                                _Float16* __restrict__ w3h,
                                                _Float16* __restrict__ w3l) {
    int idx = blockIdx.x * 256 + threadIdx.x;   // 589824 = 9*16*2*256*8
    if (idx >= 589824) return;
    int e  = idx & 7;
    int t  = idx >> 3;
    int oc = t & 255; t >>= 8;
    int g  = t & 1;   t >>= 1;
    int kb = t & 15;  t >>= 4;
    int s  = t;                               // 0..8
    int ic = kb * 16 + g * 8 + e;
    float v = w[(oc * 256 + ic) * 9 + s];
    _Float16 vh = (_Float16)v;
    float r = v - (float)vh;                  // exact in fp32
    w3h[idx] = vh;
    w3l[idx] = (_Float16)(r * 2048.0f);
}

// ---------------- anchors output (exact double->f32 like numpy) + zero counters ----------------
__global__ void k_anchors(float* __restrict__ out, unsigned int* __restrict__ cc) {
    int idx = blockIdx.x * 256 + threadIdx.x;
    if (blockIdx.x == 0 && threadIdx.x < 16) cc[threadIdx.x] = 0u;
    if (idx >= NANCH) return;
    int p = idx / 9, a = idx - p * 9;
    int y = p >> 6, xg = p & 63;
    double rr = (a < 3) ? 0.5 : ((a < 6) ? 1.0 : 2.0);
    int sj = a % 3;
    double ssc = (sj == 0) ? 8.0 : ((sj == 1) ? 16.0 : 32.0);
    double hh = 7.0 * ssc * sqrt(rr);
    double ww = 7.0 * ssc * sqrt(1.0 / rr);
    float a0 = (float)(3.5 - 0.5 * hh), a2 = (float)(3.5 + 0.5 * hh);
    float b0 = (float)(3.5 - 0.5 * ww), b2 = (float)(3.5 + 0.5 * ww);
    float* dst = out + OUT_ANCH + (size_t)idx * 4;
    dst[0] = y * 16.0f + a0;
    dst[1] = xg * 16.0f + b0;
    dst[2] = y * 16.0f + a2;
    dst[3] = xg * 16.0f + b2;
}

// ---------------- conv1 3x3 + bias + relu via fp16 hi/lo split MFMA ----------------
// R6: 1024-thread block, 16 waves (4 per SIMD). Each wave owns 32oc x 64px:
// acc = 2 x f32x16 (64 AGPR) -> regs/wave <= 128 -> 2x the latency hiding of the
// 8-wave version. Per-output accumulation order unchanged -> bit-identical.
__global__ __launch_bounds__(1024) void k_conv1m(const float* __restrict__ x,
                                                 const _Float16* __restrict__ w3h,
                                                 const _Float16* __restrict__ w3l,
                                                 const float* __restrict__ bias,
                                                 float* __restrict__ h) {
    __shared__ __align__(16) _Float16 bt0[4 * 66 * 26];   // hi
    __shared__ __align__(16) _Float16 bt1[4 * 66 * 26];   // lo
    __shared__ float bsh[256];

    const int tid = threadIdx.x;
    const int lane = tid & 63;
    const int wv = tid >> 6;        // 0..15
    const int ocg = wv >> 1;        // 0..7 : oc block 32*ocg
    const int wn = wv & 1;          // 0..1 : image row y0+wn
    const int y0 = blockIdx.x * 2;
    const int n  = blockIdx.y;
    const int bl31 = lane & 31;
    const int g = lane >> 5;        // ic-subgroup for fragments

    for (int i = tid; i < 858; i += 1024) {
        ((f16x8*)bt0)[i] = (f16x8){};
        ((f16x8*)bt1)[i] = (f16x8){};
    }
    if (tid < 256) bsh[tid] = bias[tid];

    f32x16 acc1[2], acc2[2];
#pragma unroll
    for (int j = 0; j < 2; ++j)
#pragma unroll
        for (int e = 0; e < 16; ++e) { acc1[j][e] = 0.0f; acc2[j][e] = 0.0f; }

    // --- staging geometry: 16 waves = 4 halo rows x 4 ic-groups (4 ic each) ---
    const int scol = lane;          // 0..63
    const int sr   = wv & 3;        // halo row 0..3 -> gy = y0-1+sr
    const int sg   = wv >> 2;       // ic-subgroup 0..3 (4 ic each)
    const int sgy  = y0 - 1 + sr;
    const bool gyok = (sgy >= 0) && (sgy < 64);
    const float* xrow = x + (size_t)n * 1048576 + sgy * 64 + scol;
    const int bto = (sr * 66 + scol + 1) * 26 + sg * 4;

    // A fragment offset (halves): (g*256 + oc)*8, oc = ocg*32 + bl31
    const int aoffl = (g * 256 + ocg * 32 + bl31) * 8;
    const _Float16* wph = w3h + aoffl;
    const _Float16* wpl = w3l + aoffl;

    float xr[4];
#pragma unroll
    for (int q = 0; q < 4; ++q)
        xr[q] = gyok ? xrow[(size_t)(sg * 4 + q) * 4096] : 0.0f;

    for (int kb = 0; kb < 16; ++kb) {
        __syncthreads();            // previous bt fully consumed
        {
            f16x4 hh, hl;
#pragma unroll
            for (int q = 0; q < 4; ++q) {
                float v = xr[q];
                _Float16 vh = (_Float16)v;
                hh[q] = vh;
                hl[q] = (_Float16)((v - (float)vh) * 2048.0f);
            }
            *(f16x4*)&bt0[bto] = hh;
            *(f16x4*)&bt1[bto] = hl;
        }
        __syncthreads();            // bt ready
        if (kb < 15) {              // prefetch next kb's x values
#pragma unroll
            for (int q = 0; q < 4; ++q)
                xr[q] = gyok ? xrow[(size_t)((kb + 1) * 16 + sg * 4 + q) * 4096] : 0.0f;
        }
        const _Float16* wkh = wph + (size_t)kb * 4096;
        const _Float16* wkl = wpl + (size_t)kb * 4096;
#pragma unroll
        for (int s = 0; s < 9; ++s) {
            const _Float16* ph = wkh + (size_t)s * 65536;
            const _Float16* pl = wkl + (size_t)s * 65536;
            f16x8 Ah0 = *(const f16x8*)(ph);
            f16x8 Al0 = *(const f16x8*)(pl);

            const int dy = s / 3 - 1, dx = s % 3 - 1;
            const int entry0 = (wn + dy + 1) * 66 + dx + 1 + bl31;   // pcb=0
            const int e0 = entry0 * 26 + g * 8;
            const int e1 = (entry0 + 32) * 26 + g * 8;               // pcb=1
            f16x8 Bh0 = *(const f16x8*)&bt0[e0];
            f16x8 Bl0 = *(const f16x8*)&bt1[e0];
            f16x8 Bh1 = *(const f16x8*)&bt0[e1];
            f16x8 Bl1 = *(const f16x8*)&bt1[e1];

            acc1[0] = __builtin_amdgcn_mfma_f32_32x32x16_f16(Ah0, Bh0, acc1[0], 0, 0, 0);
            acc1[1] = __builtin_amdgcn_mfma_f32_32x32x16_f16(Ah0, Bh1, acc1[1], 0, 0, 0);
            acc2[0] = __builtin_amdgcn_mfma_f32_32x32x16_f16(Ah0, Bl0, acc2[0], 0, 0, 0);
            acc2[1] = __builtin_amdgcn_mfma_f32_32x32x16_f16(Ah0, Bl1, acc2[1], 0, 0, 0);
            acc2[0] = __builtin_amdgcn_mfma_f32_32x32x16_f16(Al0, Bh0, acc2[0], 0, 0, 0);
            acc2[1] = __builtin_amdgcn_mfma_f32_32x32x16_f16(Al0, Bh1, acc2[1], 0, 0, 0);
        }
    }

    // ---- epilogue: combine hi/lo accs, bias, relu, store ----
    // C/D 32x32 layout: col = lane&31, row = (reg&3) + 8*(reg>>2) + 4*(lane>>5)
    const int colw = lane & 31;
    const int rgh = (lane >> 5) * 4;
    float* hn = h + (size_t)n * 1048576 + (size_t)(y0 + wn) * 64;
#pragma unroll
    for (int pcb = 0; pcb < 2; ++pcb)
#pragma unroll
        for (int reg = 0; reg < 16; ++reg) {
            const int row = (reg & 3) + 8 * (reg >> 2) + rgh;
            const int oc = ocg * 32 + row;
            float v = acc1[pcb][reg] + acc2[pcb][reg] * 4.8828125e-4f + bsh[oc];
            hn[(size_t)oc * 4096 + pcb * 32 + colw] = fmaxf(v, 0.0f);
        }
}

// ---------------- 1x1 heads — unchanged (verified) ----------------
__global__ __launch_bounds__(256) void k_heads(const float* __restrict__ h,
                                               const float* __restrict__ loc_w,
                                               const float* __restrict__ score_w,
                                               const float* __restrict__ loc_b,
                                               const float* __restrict__ score_b,
                                               const int* __restrict__ ihp,
                                               const int* __restrict__ iwp,
                                               float* __restrict__ out,
                                               float* __restrict__ boxes,
                                               unsigned int* __restrict__ ubuf) {
    __shared__ float Wl[54 * 64];     // [c][kk]
    __shared__ float outb[128 * 57];  // [p][c] pitch 57
    const int tid = threadIdx.x;
    const int pl = tid & 127, chalf = tid >> 7;
    const int c0 = chalf * 27;
    const int ptile = blockIdx.x;
    const int n = blockIdx.y;
    const int pg = ptile * 128 + pl;

    float acc[27];
#pragma unroll
    for (int i = 0; i < 27; ++i) acc[i] = 0.f;

    for (int kc = 0; kc < 4; ++kc) {
        __syncthreads();
        for (int idx = tid; idx < 54 * 64; idx += 256) {
            int c = idx >> 6, kk = idx & 63;
            int gk = kc * 64 + kk;
            Wl[idx] = (c < 36) ? loc_w[c * 256 + gk] : score_w[(c - 36) * 256 + gk];
        }
        __syncthreads();
        for (int k4 = 0; k4 < 64; k4 += 4) {
            int gk = kc * 64 + k4;
            float hv0 = h[(n * 256 + gk + 0) * 4096 + pg];
            float hv1 = h[(n * 256 + gk + 1) * 4096 + pg];
            float hv2 = h[(n * 256 + gk + 2) * 4096 + pg];
            float hv3 = h[(n * 256 + gk + 3) * 4096 + pg];
#pragma unroll
            for (int ci = 0; ci < 27; ++ci) {
                float4 w4 = *(const float4*)&Wl[(c0 + ci) * 64 + k4];
                acc[ci] += hv0 * w4.x + hv1 * w4.y + hv2 * w4.z + hv3 * w4.w;
            }
        }
    }
#pragma unroll
    for (int ci = 0; ci < 27; ++ci) {
        int c = c0 + ci;
        float bv = (c < 36) ? loc_b[c] : score_b[c - 36];
        outb[pl * 57 + c] = acc[ci] + bv;
    }
    __syncthreads();

    const float fh = (float)(*ihp), fwid = (float)(*iwp);
    for (int slot = tid; slot < 128 * 9; slot += 256) {
        int pli = slot / 9, a = slot - pli * 9;
        int p = ptile * 128 + pli;
        int y = p >> 6, xg = p & 63;
        float l0 = outb[pli * 57 + a * 4 + 0];
        float l1 = outb[pli * 57 + a * 4 + 1];
        float l2 = outb[pli * 57 + a * 4 + 2];
        float l3 = outb[pli * 57 + a * 4 + 3];
        float s0 = outb[pli * 57 + 36 + a * 2 + 0];
        float s1 = outb[pli * 57 + 36 + a * 2 + 1];
        size_t base = (size_t)n * NANCH + (size_t)p * 9 + a;
        ((float4*)(out + OUT_LOC))[base] = make_float4(l0, l1, l2, l3);
        ((float2*)(out + OUT_SCORE))[base] = make_float2(s0, s1);
        float mx = fmaxf(s0, s1);
        float e0 = expf(s0 - mx), e1 = expf(s1 - mx);
        float fg = e1 / (e0 + e1);
        double rr = (a < 3) ? 0.5 : ((a < 6) ? 1.0 : 2.0);
        int sj = a % 3;
        double ssc = (sj == 0) ? 8.0 : ((sj == 1) ? 16.0 : 32.0);
        double hhd = 7.0 * ssc * sqrt(rr);
        double wwd = 7.0 * ssc * sqrt(1.0 / rr);
        float a0 = (float)(3.5 - 0.5 * hhd), a2 = (float)(3.5 + 0.5 * hhd);
        float b0 = (float)(3.5 - 0.5 * wwd), b2 = (float)(3.5 + 0.5 * wwd);
        float ay1 = y * 16.0f + a0, ay2 = y * 16.0f + a2;
        float ax1 = xg * 16.0f + b0, ax2 = xg * 16.0f + b2;
        float ah = ay2 - ay1, aw = ax2 - ax1;
        float acy = ay1 + 0.5f * ah, acx = ax1 + 0.5f * aw;
        float cy = l0 * ah + acy, cx = l1 * aw + acx;
        float bh = expf(l2) * ah, bw = expf(l3) * aw;
        float y1 = fminf(fmaxf(cy - 0.5f * bh, 0.f), fh);
        float x1 = fminf(fmaxf(cx - 0.5f * bw, 0.f), fwid);
        float y2 = fminf(fmaxf(cy + 0.5f * bh, 0.f), fh);
        float x2 = fminf(fmaxf(cx + 0.5f * bw, 0.f), fwid);
        ((float4*)boxes)[base] = make_float4(y1, x1, y2, x2);
        bool valid = ((y2 - y1) >= 16.0f) && ((x2 - x1) >= 16.0f);
        float sc = valid ? fg : -__builtin_inff();
        unsigned int ub = __float_as_uint(sc);
        ub = (ub & 0x80000000u) ? ~ub : (ub | 0x80000000u);
        ubuf[base] = ub;
    }
}

// ---------------- exact top-6000 per batch: byte-radix select + compact (unchanged) ----------------
__global__ __launch_bounds__(1024) void k_select(const unsigned int* __restrict__ ubuf,
                                                 unsigned long long* __restrict__ ckeys,
                                                 unsigned int* __restrict__ cc) {
    __shared__ unsigned int hist[256];
    __shared__ unsigned int selb;
    __shared__ int rank_s;
    __shared__ unsigned int lcnt;
    const int tid = threadIdx.x;
    const int b = blockIdx.x;
    const unsigned int* ub = ubuf + (size_t)b * NANCH;
    if (tid == 0) { rank_s = NPRE - 1; lcnt = 0; }
    unsigned int prefix = 0;
    for (int pass = 0; pass < 4; ++pass) {
        int shift = 24 - 8 * pass;
        if (tid < 256) hist[tid] = 0;
        __syncthreads();
        for (int i = tid; i < NANCH; i += 1024) {
            unsigned int u = ub[i];
            bool ok = (pass == 0) || ((u >> (shift + 8)) == (prefix >> (shift + 8)));
            if (ok) atomicAdd(&hist[(u >> shift) & 255], 1u);
        }
        __syncthreads();
        if (tid == 0) {
            int racc = 0; unsigned int bs = 0; int r = rank_s;
            for (int bb = 255; bb >= 0; --bb) {
                int c = (int)hist[bb];
                if (racc + c > r) { bs = (unsigned int)bb; rank_s = r - racc; break; }
                racc += c;
            }
            selb = bs;
        }
        __syncthreads();
        prefix |= (selb << shift);
        __syncthreads();
    }
    const unsigned int ustar = prefix;
    for (int i = tid; i < NANCH; i += 1024) {
        unsigned int u = ub[i];
        if (u >= ustar) {
            unsigned int pos = atomicAdd(&lcnt, 1u);
            if (pos < 8192)
                ckeys[(size_t)b * 8192 + pos] =
                    ((unsigned long long)u << 32) | (unsigned int)(0xFFFFFFFFu - (unsigned int)i);
        }
    }
    __syncthreads();
    if (tid == 0) cc[b] = (lcnt > 8192u) ? 8192u : lcnt;
}

// ---------------- bitonic sort 8192: in-register (8 keys/thread) + shuffle + minimal LDS ----------------
__device__ __forceinline__ void cswap_u64(unsigned long long& a, unsigned long long& c, bool desc) {
    bool sw = desc ? (a < c) : (a > c);
    unsigned long long t0 = sw ? c : a;
    unsigned long long t1 = sw ? a : c;
    a = t0; c = t1;
}
__device__ __forceinline__ void net8(unsigned long long v[8], bool d) {
    cswap_u64(v[0], v[4], d); cswap_u64(v[1], v[5], d); cswap_u64(v[2], v[6], d); cswap_u64(v[3], v[7], d);
    cswap_u64(v[0], v[2], d); cswap_u64(v[1], v[3], d); cswap_u64(v[4], v[6], d); cswap_u64(v[5], v[7], d);
    cswap_u64(v[0], v[1], d); cswap_u64(v[2], v[3], d); cswap_u64(v[4], v[5], d); cswap_u64(v[6], v[7], d);
}
__device__ __forceinline__ unsigned long long shfl_xor_u64(unsigned long long x, int lmask) {
    unsigned int lo = (unsigned int)x, hi = (unsigned int)(x >> 32);
    lo = __shfl_xor(lo, lmask, 64);
    hi = __shfl_xor(hi, lmask, 64);
    return ((unsigned long long)hi << 32) | lo;
}
__global__ __launch_bounds__(1024) void k_sort(const unsigned long long* __restrict__ ckeys,
                                               const unsigned int* __restrict__ cc,
                                               const float* __restrict__ boxes,
                                               float* __restrict__ bk) {
    __shared__ unsigned long long S[8192];
    const int tid = threadIdx.x;
    const int b = blockIdx.x;
    const int cnt = (int)cc[b];
    const int base = tid * 8;

    unsigned long long v[8];
#pragma unroll
    for (int e = 0; e < 8; ++e) {
        int i = base + e;
        v[e] = (i < cnt) ? ckeys[(size_t)b * 8192 + i] : 0ull;
    }

    cswap_u64(v[0], v[1], true);  cswap_u64(v[2], v[3], false);
    cswap_u64(v[4], v[5], true);  cswap_u64(v[6], v[7], false);
    cswap_u64(v[0], v[2], true);  cswap_u64(v[1], v[3], true);
    cswap_u64(v[4], v[6], false); cswap_u64(v[5], v[7], false);
    cswap_u64(v[0], v[1], true);  cswap_u64(v[2], v[3], true);
    cswap_u64(v[4], v[5], false); cswap_u64(v[6], v[7], false);
    net8(v, (tid & 1) == 0);

    for (int k = 16; k <= 8192; k <<= 1) {
        for (int j = k >> 1; j >= 8; j >>= 1) {
            const bool keep_max = (((base & k) == 0) != ((base & j) != 0));
            if (j >= 512) {
                __syncthreads();
#pragma unroll
                for (int e = 0; e < 8; ++e) S[base + e] = v[e];
                __syncthreads();
                const int pb = base ^ j;
#pragma unroll
                for (int e = 0; e < 8; ++e) {
                    unsigned long long p = S[pb + e];
                    v[e] = keep_max ? (v[e] >= p ? v[e] : p) : (v[e] <= p ? v[e] : p);
                }
            } else {
                const int lmask = j >> 3;
#pragma unroll
                for (int e = 0; e < 8; ++e) {
                    unsigned long long p = shfl_xor_u64(v[e], lmask);
                    v[e] = keep_max ? (v[e] >= p ? v[e] : p) : (v[e] <= p ? v[e] : p);
                }
            }
        }
        net8(v, (base & k) == 0);
    }

#pragma unroll
    for (int e = 0; e < 8; ++e) {
        int i = base + e;
        if (i < NPRE) {
            unsigned long long key = v[e];
            unsigned int idx = 0xFFFFFFFFu - (unsigned int)(key & 0xFFFFFFFFull);
            if (idx >= NANCH) idx = NANCH - 1;   // safety
            float4 bx = ((const float4*)boxes)[(size_t)b * NANCH + idx];
            ((float4*)bk)[(size_t)b * NPRE + i] = bx;
        }
    }
}

// ---------------- IoU bitmask, COLUMN-major — division-free, bit-exact predicate ----------------
__global__ __launch_bounds__(256) void k_mask(const float* __restrict__ bk,
                                              unsigned long long* __restrict__ MT) {
    const int iw = blockIdx.x;
    const int gb = blockIdx.y;
    const int b = blockIdx.z;
    if (iw > 4 * gb + 3) return;
    const int tid = threadIdx.x;
    __shared__ float4 jb[64];
    __shared__ float ja[64];
    if (tid < 64) {
        int j = iw * 64 + tid;
        float4 v = (j < NPRE) ? ((const float4*)bk)[(size_t)b * NPRE + j]
                              : make_float4(0.f, 0.f, 0.f, 0.f);
        jb[tid] = v;
        ja[tid] = (v.z - v.x) * (v.w - v.y);
    }
    __syncthreads();
    const int g = gb * 256 + tid;
    float4 bi = (g < NPRE) ? ((const float4*)bk)[(size_t)b * NPRE + g]
                           : make_float4(0.f, 0.f, 0.f, 0.f);
    float ai = (bi.z - bi.x) * (bi.w - bi.y);
    const double MD = (double)0.7f + 0x1p-25;   // exact rounding midpoint
    unsigned long long word = 0ull;
#pragma unroll 8
    for (int jj = 0; jj < 64; ++jj) {
        float4 bj = jb[jj];
        float aj = ja[jj];
        float ty = fmaxf(bi.x, bj.x), tx = fmaxf(bi.y, bj.y);
        float by = fminf(bi.z, bj.z), bx = fminf(bi.w, bj.w);
        float ihh = fmaxf(by - ty, 0.f), iww = fmaxf(bx - tx, 0.f);
        float inter = ihh * iww;
        float den = ai + aj - inter + 1e-9f;
        if ((double)inter >= MD * (double)den) word |= (1ull << jj);
    }
    if (g < GCOLS)
        MT[((size_t)b * NWORDS + iw) * GCOLS + g] = word;
}

// ---------------- greedy NMS with early break (unchanged) ----------------
__global__ __launch_bounds__(1024) void k_nms(const unsigned long long* __restrict__ MT,
                                              const float* __restrict__ bk,
                                              float* __restrict__ out) {
    const int b = blockIdx.x;
    const int tid = threadIdx.x;
    const int lane = tid & 63;
    __shared__ unsigned long long keptw[NWORDS];
    __shared__ unsigned long long dead[NWORDS];
    __shared__ int sel[NPOST];
    __shared__ int totkept;
    const unsigned long long* mtb = MT + (size_t)b * NWORDS * GCOLS;

    for (int i = tid; i < NWORDS; i += 1024) { dead[i] = 0ull; keptw[i] = 0ull; }
    if (tid == 0) totkept = 0;
    __syncthreads();

    for (int c = 0; c < NWORDS; ++c) {
        if (tid < 64) {   // wave 0: in-chunk greedy closure
            const int g = c * 64 + lane;
            unsigned long long diag = mtb[(size_t)c * GCOLS + g];
            bool deadl = (((dead[c] >> lane) & 1ull) != 0ull) || (g >= NPRE);
            unsigned long long undec = ~__ballot(deadl);
            unsigned long long kc = 0ull;
            while (undec) {
                int i = __builtin_ctzll(undec);
                kc |= (1ull << i);
                unsigned long long supm = __ballot((diag >> i) & 1ull);
                undec &= ~(supm | (1ull << i));
            }
            if (lane == 0) { keptw[c] = kc; totkept += __popcll(kc); }
        }
        __syncthreads();
        if (totkept >= NPOST) break;          // later chunks can't affect the output
        const unsigned long long kc = keptw[c];
        if (kc) {
            for (int g2 = (c + 1) * 64 + tid; g2 < GCOLS; g2 += 1024) {
                unsigned long long w = mtb[(size_t)c * GCOLS + g2] & kc;
                unsigned long long m = __ballot(w != 0ull);
                if (lane == 0 && m) atomicOr(&dead[g2 >> 6], m);
            }
        }
        __syncthreads();
    }

    if (tid == 0) {
        int pos = 0;
        for (int w = 0; w < NWORDS && pos < NPOST; ++w) {
            unsigned long long kw = keptw[w];
            while (kw && pos < NPOST) {
                int i2 = __builtin_ctzll(kw);
                sel[pos++] = w * 64 + i2;
                kw &= kw - 1;
            }
        }
        for (int w = 0; w < NWORDS && pos < NPOST; ++w) {
            int nvalid = NPRE - w * 64; if (nvalid > 64) nvalid = 64;
            unsigned long long vm = (nvalid >= 64) ? ~0ull : ((1ull << nvalid) - 1ull);
            unsigned long long sw = (~keptw[w]) & vm;
            while (sw && pos < NPOST) {
                int i2 = __builtin_ctzll(sw);
                sel[pos++] = w * 64 + i2;
                sw &= sw - 1;
            }
        }
    }
    __syncthreads();
    for (int s2 = tid; s2 < NPOST; s2 += 1024) {
        int i = sel[s2];
        float4 bx = ((const float4*)bk)[(size_t)b * NPRE + i];
        ((float4*)(out + OUT_ROIS))[b * NPOST + s2] = bx;
        out[OUT_RIDX + b * NPOST + s2] = (float)b;
    }
}

// ---------------- launch ----------------
extern "C" void kernel_launch(void* const* d_in, const int* in_sizes, int n_in,
                              void* d_out, int out_size, void* d_ws, size_t ws_size,
                              hipStream_t stream) {
    const float* x = (const float*)d_in[0];
    const float* conv1_w = (const float*)d_in[1];
    const float* conv1_b = (const float*)d_in[2];
    const float* score_w = (const float*)d_in[3];
    const float* score_b = (const float*)d_in[4];
    const float* loc_w = (const float*)d_in[5];
    const float* loc_b = (const float*)d_in[6];
    const int* ihp = (const int*)d_in[7];
    const int* iwp = (const int*)d_in[8];
    float* out = (float*)d_out;
    char* ws = (char*)d_ws;
    float* h = (float*)(ws + H_OFF);
    _Float16* w3h = (_Float16*)(ws + WT_OFF);
    _Float16* w3l = (_Float16*)(ws + WT_OFF + 1179648ul);
    float* boxes = (float*)(ws + BOX_OFF);
    unsigned int* ubuf = (unsigned int*)(ws + U_OFF);
    unsigned long long* ckeys = (unsigned long long*)(ws + CK_OFF);
    unsigned int* cc = (unsigned int*)(ws + CC_OFF);
    float* bk = (float*)(ws + BK_OFF);
    unsigned long long* MT = (unsigned long long*)(ws + M_OFF);

    hipLaunchKernelGGL(k_prep_w, dim3(2304), dim3(256), 0, stream, conv1_w, w3h, w3l);
    hipLaunchKernelGGL(k_anchors, dim3(144), dim3(256), 0, stream, out, cc);
    hipLaunchKernelGGL(k_conv1m, dim3(32, 8), dim3(1024), 0, stream, x, w3h, w3l, conv1_b, h);
    hipLaunchKernelGGL(k_heads, dim3(32, 8), dim3(256), 0, stream,
                       h, loc_w, score_w, loc_b, score_b, ihp, iwp, out, boxes, ubuf);
    hipLaunchKernelGGL(k_select, dim3(8), dim3(1024), 0, stream, ubuf, ckeys, cc);
    hipLaunchKernelGGL(k_sort, dim3(8), dim3(1024), 0, stream, ckeys, cc, boxes, bk);
    hipLaunchKernelGGL(k_mask, dim3(94, 24, 8), dim3(256), 0, stream, bk, MT);
    hipLaunchKernelGGL(k_nms, dim3(8), dim3(1024), 0, stream, MT, bk, out);
}

// Round 7
// 594.945 us; speedup vs baseline: 1.0051x; 1.0051x over previous
//
#include <hip/hip_runtime.h>
#include <cstdint>
#include <cstddef>

// ---------------- problem constants ----------------
#define NBATCH 8
#define MID 256
#define HIMG 64
#define WIMG 64
#define NA 9
#define NPRE 6000
#define NPOST 300
#define NANCH (HIMG*WIMG*NA)   // 36864
#define NWORDS 94              // ceil(6000/64)
#define GCOLS 6016             // 94*64 padded columns

// output float offsets
#define OUT_LOC   0
#define OUT_SCORE 1179648
#define OUT_ROIS  1769472
#define OUT_RIDX  1779072
#define OUT_ANCH  1781472

// workspace byte offsets
#define H_OFF    0ul
#define H_BYTES  (8ul*256*64*64*4)         // 33554432
#define WT_OFF   (H_OFF + H_BYTES)
#define WT_BYTES (2304ul*256*4)            // 2359296 = exactly w3h+w3l (half)
#define BOX_OFF  (WT_OFF + WT_BYTES)
#define BOX_BYTES (8ul*36864*4*4)          // 4718592
#define U_OFF    (BOX_OFF + BOX_BYTES)
#define U_BYTES  (8ul*36864*4)
#define CK_OFF   (U_OFF + U_BYTES)
#define CK_BYTES (8ul*8192*8)
#define CC_OFF   (CK_OFF + CK_BYTES)
#define CC_BYTES 64ul
#define BK_OFF   (CC_OFF + CC_BYTES)
#define BK_BYTES (8ul*6000*16)
#define M_OFF    (BK_OFF + BK_BYTES + 64)
#define M_BYTES  (8ul*NWORDS*GCOLS*8)      // 36.2 MB, column-major mask

typedef _Float16 f16x8 __attribute__((ext_vector_type(8)));
typedef _Float16 f16x4 __attribute__((ext_vector_type(4)));
typedef float f32x16 __attribute__((ext_vector_type(16)));

// ---------------- weight prep: conv1_w[oc][ic][ky][kx] -> w3{h,l}[s][kb][g][oc][8] fp16 hi/lo ----------
// R7: whole problem scaled by 64 (exact pow2). Residuals of 64-scaled values are fp16-normal,
// so cross terms accumulate UNSCALED into the main accumulator; epilogue multiplies by 2^-12.
__global__ __launch_bounds__(256) void k_prep_w(const float* __restrict__ w,
                                                _Float16* __restrict__ w3h,
                                                _Float16* __restrict__ w3l) {
    int idx = blockIdx.x * 256 + threadIdx.x;   // 589824 = 9*16*2*256*8
    if (idx >= 589824) return;
    int e  = idx & 7;
    int t  = idx >> 3;
    int oc = t & 255; t >>= 8;
    int g  = t & 1;   t >>= 1;
    int kb = t & 15;  t >>= 4;
    int s  = t;                               // 0..8
    int ic = kb * 16 + g * 8 + e;
    float v = w[(oc * 256 + ic) * 9 + s] * 64.0f;   // exact pow2 scale
    _Float16 vh = (_Float16)v;
    float r = v - (float)vh;                  // exact in fp32
    w3h[idx] = vh;
    w3l[idx] = (_Float16)r;                   // fp16-normal (64-scale)
}

// ---------------- anchors output (exact double->f32 like numpy) + zero counters ----------------
__global__ void k_anchors(float* __restrict__ out, unsigned int* __restrict__ cc) {
    int idx = blockIdx.x * 256 + threadIdx.x;
    if (blockIdx.x == 0 && threadIdx.x < 16) cc[threadIdx.x] = 0u;
    if (idx >= NANCH) return;
    int p = idx / 9, a = idx - p * 9;
    int y = p >> 6, xg = p & 63;
    double rr = (a < 3) ? 0.5 : ((a < 6) ? 1.0 : 2.0);
    int sj = a % 3;
    double ssc = (sj == 0) ? 8.0 : ((sj == 1) ? 16.0 : 32.0);
    double hh = 7.0 * ssc * sqrt(rr);
    double ww = 7.0 * ssc * sqrt(1.0 / rr);
    float a0 = (float)(3.5 - 0.5 * hh), a2 = (float)(3.5 + 0.5 * hh);
    float b0 = (float)(3.5 - 0.5 * ww), b2 = (float)(3.5 + 0.5 * ww);
    float* dst = out + OUT_ANCH + (size_t)idx * 4;
    dst[0] = y * 16.0f + a0;
    dst[1] = xg * 16.0f + b0;
    dst[2] = y * 16.0f + a2;
    dst[3] = xg * 16.0f + b2;
}

// ---------------- conv1 3x3 + bias + relu via fp16 hi/lo split MFMA ----------------
// R7: single accumulator (32 AGPR) via the 64-scale trick; freed registers used for an
// explicit next-step software pipeline of BOTH A (global) and B (LDS) fragments, plus
// s_setprio(1) around the MFMA cluster. 16 waves, wave = 32oc x 64px.
__global__ __launch_bounds__(1024) void k_conv1m(const float* __restrict__ x,
                                                 const _Float16* __restrict__ w3h,
                                                 const _Float16* __restrict__ w3l,
                                                 const float* __restrict__ bias,
                                                 float* __restrict__ h) {
    __shared__ __align__(16) _Float16 bt0[4 * 66 * 26];   // hi
    __shared__ __align__(16) _Float16 bt1[4 * 66 * 26];   // lo
    __shared__ float bsh[256];

    const int tid = threadIdx.x;
    const int lane = tid & 63;
    const int wv = tid >> 6;        // 0..15
    const int ocg = wv >> 1;        // 0..7 : oc block 32*ocg
    const int wn = wv & 1;          // 0..1 : image row y0+wn
    const int y0 = blockIdx.x * 2;
    const int n  = blockIdx.y;
    const int bl31 = lane & 31;
    const int g = lane >> 5;        // ic-subgroup for fragments

    for (int i = tid; i < 858; i += 1024) {
        ((f16x8*)bt0)[i] = (f16x8){};
        ((f16x8*)bt1)[i] = (f16x8){};
    }
    if (tid < 256) bsh[tid] = bias[tid];

    f32x16 acc[2];
#pragma unroll
    for (int j = 0; j < 2; ++j)
#pragma unroll
        for (int e = 0; e < 16; ++e) acc[j][e] = 0.0f;

    // --- staging geometry: 16 waves = 4 halo rows x 4 ic-groups (4 ic each) ---
    const int scol = lane;          // 0..63
    const int sr   = wv & 3;        // halo row 0..3 -> gy = y0-1+sr
    const int sg   = wv >> 2;       // ic-subgroup 0..3 (4 ic each)
    const int sgy  = y0 - 1 + sr;
    const bool gyok = (sgy >= 0) && (sgy < 64);
    const float* xrow = x + (size_t)n * 1048576 + sgy * 64 + scol;
    const int bto = (sr * 66 + scol + 1) * 26 + sg * 4;

    // A fragment offset (halves): (g*256 + oc)*8, oc = ocg*32 + bl31
    const int aoffl = (g * 256 + ocg * 32 + bl31) * 8;
    const _Float16* wph = w3h + aoffl;
    const _Float16* wpl = w3l + aoffl;

    float xr[4];
#pragma unroll
    for (int q = 0; q < 4; ++q)
        xr[q] = gyok ? xrow[(size_t)(sg * 4 + q) * 4096] : 0.0f;

    // A-pipeline prologue: fragments for (kb=0, s=0)
    f16x8 AhC = *(const f16x8*)(wph);
    f16x8 AlC = *(const f16x8*)(wpl);

    for (int kb = 0; kb < 16; ++kb) {
        __syncthreads();            // previous bt fully consumed
        {
            f16x4 hh, hl;
#pragma unroll
            for (int q = 0; q < 4; ++q) {
                float v = xr[q] * 64.0f;           // exact pow2 scale
                _Float16 vh = (_Float16)v;
                hh[q] = vh;
                hl[q] = (_Float16)(v - (float)vh); // fp16-normal residual
            }
            *(f16x4*)&bt0[bto] = hh;
            *(f16x4*)&bt1[bto] = hl;
        }
        __syncthreads();            // bt ready
        if (kb < 15) {              // prefetch next kb's x values
#pragma unroll
            for (int q = 0; q < 4; ++q)
                xr[q] = gyok ? xrow[(size_t)((kb + 1) * 16 + sg * 4 + q) * 4096] : 0.0f;
        }

        // B-pipeline prologue for this kb: fragments for s=0 (dy=-1, dx=-1)
        const int ent00 = wn * 66 + bl31;
        f16x8 Bh0C = *(const f16x8*)&bt0[ent00 * 26 + g * 8];
        f16x8 Bl0C = *(const f16x8*)&bt1[ent00 * 26 + g * 8];
        f16x8 Bh1C = *(const f16x8*)&bt0[(ent00 + 32) * 26 + g * 8];
        f16x8 Bl1C = *(const f16x8*)&bt1[(ent00 + 32) * 26 + g * 8];

        const int kbn_base = (kb < 15) ? (kb + 1) : 15;
        const _Float16* wkh = wph + (size_t)kb * 4096;
        const _Float16* wkl = wpl + (size_t)kb * 4096;
#pragma unroll
        for (int s = 0; s < 9; ++s) {
            // ---- issue next-step loads BEFORE this step's MFMAs ----
            const int sn  = (s == 8) ? 0 : (s + 1);
            const int kbn = (s == 8) ? kbn_base : kb;
            const _Float16* phn = wph + (size_t)kbn * 4096 + (size_t)sn * 65536;
            const _Float16* pln = wpl + (size_t)kbn * 4096 + (size_t)sn * 65536;
            f16x8 AhN = *(const f16x8*)(phn);
            f16x8 AlN = *(const f16x8*)(pln);

            f16x8 Bh0N = Bh0C, Bl0N = Bl0C, Bh1N = Bh1C, Bl1N = Bl1C;
            if (s < 8) {
                const int dyn = sn / 3 - 1, dxn = sn % 3 - 1;
                const int entn = (wn + dyn + 1) * 66 + dxn + 1 + bl31;
                const int en0 = entn * 26 + g * 8;
                const int en1 = (entn + 32) * 26 + g * 8;
                Bh0N = *(const f16x8*)&bt0[en0];
                Bl0N = *(const f16x8*)&bt1[en0];
                Bh1N = *(const f16x8*)&bt0[en1];
                Bl1N = *(const f16x8*)&bt1[en1];
            }

            __builtin_amdgcn_s_setprio(1);
            acc[0] = __builtin_amdgcn_mfma_f32_32x32x16_f16(AhC, Bh0C, acc[0], 0, 0, 0);
            acc[1] = __builtin_amdgcn_mfma_f32_32x32x16_f16(AhC, Bh1C, acc[1], 0, 0, 0);
            acc[0] = __builtin_amdgcn_mfma_f32_32x32x16_f16(AhC, Bl0C, acc[0], 0, 0, 0);
            acc[1] = __builtin_amdgcn_mfma_f32_32x32x16_f16(AhC, Bl1C, acc[1], 0, 0, 0);
            acc[0] = __builtin_amdgcn_mfma_f32_32x32x16_f16(AlC, Bh0C, acc[0], 0, 0, 0);
            acc[1] = __builtin_amdgcn_mfma_f32_32x32x16_f16(AlC, Bh1C, acc[1], 0, 0, 0);
            __builtin_amdgcn_s_setprio(0);

            AhC = AhN; AlC = AlN;
            Bh0C = Bh0N; Bl0C = Bl0N; Bh1C = Bh1N; Bl1C = Bl1N;
        }
    }

    // ---- epilogue: un-scale (2^-12), bias, relu, store ----
    // C/D 32x32 layout: col = lane&31, row = (reg&3) + 8*(reg>>2) + 4*(lane>>5)
    const int colw = lane & 31;
    const int rgh = (lane >> 5) * 4;
    float* hn = h + (size_t)n * 1048576 + (size_t)(y0 + wn) * 64;
#pragma unroll
    for (int pcb = 0; pcb < 2; ++pcb)
#pragma unroll
        for (int reg = 0; reg < 16; ++reg) {
            const int row = (reg & 3) + 8 * (reg >> 2) + rgh;
            const int oc = ocg * 32 + row;
            float v = acc[pcb][reg] * 2.44140625e-4f + bsh[oc];   // *2^-12
            hn[(size_t)oc * 4096 + pcb * 32 + colw] = fmaxf(v, 0.0f);
        }
}

// ---------------- 1x1 heads — unchanged (verified) ----------------
__global__ __launch_bounds__(256) void k_heads(const float* __restrict__ h,
                                               const float* __restrict__ loc_w,
                                               const float* __restrict__ score_w,
                                               const float* __restrict__ loc_b,
                                               const float* __restrict__ score_b,
                                               const int* __restrict__ ihp,
                                               const int* __restrict__ iwp,
                                               float* __restrict__ out,
                                               float* __restrict__ boxes,
                                               unsigned int* __restrict__ ubuf) {
    __shared__ float Wl[54 * 64];     // [c][kk]
    __shared__ float outb[128 * 57];  // [p][c] pitch 57
    const int tid = threadIdx.x;
    const int pl = tid & 127, chalf = tid >> 7;
    const int c0 = chalf * 27;
    const int ptile = blockIdx.x;
    const int n = blockIdx.y;
    const int pg = ptile * 128 + pl;

    float acc[27];
#pragma unroll
    for (int i = 0; i < 27; ++i) acc[i] = 0.f;

    for (int kc = 0; kc < 4; ++kc) {
        __syncthreads();
        for (int idx = tid; idx < 54 * 64; idx += 256) {
            int c = idx >> 6, kk = idx & 63;
            int gk = kc * 64 + kk;
            Wl[idx] = (c < 36) ? loc_w[c * 256 + gk] : score_w[(c - 36) * 256 + gk];
        }
        __syncthreads();
        for (int k4 = 0; k4 < 64; k4 += 4) {
            int gk = kc * 64 + k4;
            float hv0 = h[(n * 256 + gk + 0) * 4096 + pg];
            float hv1 = h[(n * 256 + gk + 1) * 4096 + pg];
            float hv2 = h[(n * 256 + gk + 2) * 4096 + pg];
            float hv3 = h[(n * 256 + gk + 3) * 4096 + pg];
#pragma unroll
            for (int ci = 0; ci < 27; ++ci) {
                float4 w4 = *(const float4*)&Wl[(c0 + ci) * 64 + k4];
                acc[ci] += hv0 * w4.x + hv1 * w4.y + hv2 * w4.z + hv3 * w4.w;
            }
        }
    }
#pragma unroll
    for (int ci = 0; ci < 27; ++ci) {
        int c = c0 + ci;
        float bv = (c < 36) ? loc_b[c] : score_b[c - 36];
        outb[pl * 57 + c] = acc[ci] + bv;
    }
    __syncthreads();

    const float fh = (float)(*ihp), fwid = (float)(*iwp);
    for (int slot = tid; slot < 128 * 9; slot += 256) {
        int pli = slot / 9, a = slot - pli * 9;
        int p = ptile * 128 + pli;
        int y = p >> 6, xg = p & 63;
        float l0 = outb[pli * 57 + a * 4 + 0];
        float l1 = outb[pli * 57 + a * 4 + 1];
        float l2 = outb[pli * 57 + a * 4 + 2];
        float l3 = outb[pli * 57 + a * 4 + 3];
        float s0 = outb[pli * 57 + 36 + a * 2 + 0];
        float s1 = outb[pli * 57 + 36 + a * 2 + 1];
        size_t base = (size_t)n * NANCH + (size_t)p * 9 + a;
        ((float4*)(out + OUT_LOC))[base] = make_float4(l0, l1, l2, l3);
        ((float2*)(out + OUT_SCORE))[base] = make_float2(s0, s1);
        float mx = fmaxf(s0, s1);
        float e0 = expf(s0 - mx), e1 = expf(s1 - mx);
        float fg = e1 / (e0 + e1);
        double rr = (a < 3) ? 0.5 : ((a < 6) ? 1.0 : 2.0);
        int sj = a % 3;
        double ssc = (sj == 0) ? 8.0 : ((sj == 1) ? 16.0 : 32.0);
        double hhd = 7.0 * ssc * sqrt(rr);
        double wwd = 7.0 * ssc * sqrt(1.0 / rr);
        float a0 = (float)(3.5 - 0.5 * hhd), a2 = (float)(3.5 + 0.5 * hhd);
        float b0 = (float)(3.5 - 0.5 * wwd), b2 = (float)(3.5 + 0.5 * wwd);
        float ay1 = y * 16.0f + a0, ay2 = y * 16.0f + a2;
        float ax1 = xg * 16.0f + b0, ax2 = xg * 16.0f + b2;
        float ah = ay2 - ay1, aw = ax2 - ax1;
        float acy = ay1 + 0.5f * ah, acx = ax1 + 0.5f * aw;
        float cy = l0 * ah + acy, cx = l1 * aw + acx;
        float bh = expf(l2) * ah, bw = expf(l3) * aw;
        float y1 = fminf(fmaxf(cy - 0.5f * bh, 0.f), fh);
        float x1 = fminf(fmaxf(cx - 0.5f * bw, 0.f), fwid);
        float y2 = fminf(fmaxf(cy + 0.5f * bh, 0.f), fh);
        float x2 = fminf(fmaxf(cx + 0.5f * bw, 0.f), fwid);
        ((float4*)boxes)[base] = make_float4(y1, x1, y2, x2);
        bool valid = ((y2 - y1) >= 16.0f) && ((x2 - x1) >= 16.0f);
        float sc = valid ? fg : -__builtin_inff();
        unsigned int ub = __float_as_uint(sc);
        ub = (ub & 0x80000000u) ? ~ub : (ub | 0x80000000u);
        ubuf[base] = ub;
    }
}

// ---------------- exact top-6000 per batch: byte-radix select + compact (unchanged) ----------------
__global__ __launch_bounds__(1024) void k_select(const unsigned int* __restrict__ ubuf,
                                                 unsigned long long* __restrict__ ckeys,
                                                 unsigned int* __restrict__ cc) {
    __shared__ unsigned int hist[256];
    __shared__ unsigned int selb;
    __shared__ int rank_s;
    __shared__ unsigned int lcnt;
    const int tid = threadIdx.x;
    const int b = blockIdx.x;
    const unsigned int* ub = ubuf + (size_t)b * NANCH;
    if (tid == 0) { rank_s = NPRE - 1; lcnt = 0; }
    unsigned int prefix = 0;
    for (int pass = 0; pass < 4; ++pass) {
        int shift = 24 - 8 * pass;
        if (tid < 256) hist[tid] = 0;
        __syncthreads();
        for (int i = tid; i < NANCH; i += 1024) {
            unsigned int u = ub[i];
            bool ok = (pass == 0) || ((u >> (shift + 8)) == (prefix >> (shift + 8)));
            if (ok) atomicAdd(&hist[(u >> shift) & 255], 1u);
        }
        __syncthreads();
        if (tid == 0) {
            int racc = 0; unsigned int bs = 0; int r = rank_s;
            for (int bb = 255; bb >= 0; --bb) {
                int c = (int)hist[bb];
                if (racc + c > r) { bs = (unsigned int)bb; rank_s = r - racc; break; }
                racc += c;
            }
            selb = bs;
        }
        __syncthreads();
        prefix |= (selb << shift);
        __syncthreads();
    }
    const unsigned int ustar = prefix;
    for (int i = tid; i < NANCH; i += 1024) {
        unsigned int u = ub[i];
        if (u >= ustar) {
            unsigned int pos = atomicAdd(&lcnt, 1u);
            if (pos < 8192)
                ckeys[(size_t)b * 8192 + pos] =
                    ((unsigned long long)u << 32) | (unsigned int)(0xFFFFFFFFu - (unsigned int)i);
        }
    }
    __syncthreads();
    if (tid == 0) cc[b] = (lcnt > 8192u) ? 8192u : lcnt;
}

// ---------------- bitonic sort 8192: in-register (8 keys/thread) + shuffle + minimal LDS ----------------
__device__ __forceinline__ void cswap_u64(unsigned long long& a, unsigned long long& c, bool desc) {
    bool sw = desc ? (a < c) : (a > c);
    unsigned long long t0 = sw ? c : a;
    unsigned long long t1 = sw ? a : c;
    a = t0; c = t1;
}
__device__ __forceinline__ void net8(unsigned long long v[8], bool d) {
    cswap_u64(v[0], v[4], d); cswap_u64(v[1], v[5], d); cswap_u64(v[2], v[6], d); cswap_u64(v[3], v[7], d);
    cswap_u64(v[0], v[2], d); cswap_u64(v[1], v[3], d); cswap_u64(v[4], v[6], d); cswap_u64(v[5], v[7], d);
    cswap_u64(v[0], v[1], d); cswap_u64(v[2], v[3], d); cswap_u64(v[4], v[5], d); cswap_u64(v[6], v[7], d);
}
__device__ __forceinline__ unsigned long long shfl_xor_u64(unsigned long long x, int lmask) {
    unsigned int lo = (unsigned int)x, hi = (unsigned int)(x >> 32);
    lo = __shfl_xor(lo, lmask, 64);
    hi = __shfl_xor(hi, lmask, 64);
    return ((unsigned long long)hi << 32) | lo;
}
__global__ __launch_bounds__(1024) void k_sort(const unsigned long long* __restrict__ ckeys,
                                               const unsigned int* __restrict__ cc,
                                               const float* __restrict__ boxes,
                                               float* __restrict__ bk) {
    __shared__ unsigned long long S[8192];
    const int tid = threadIdx.x;
    const int b = blockIdx.x;
    const int cnt = (int)cc[b];
    const int base = tid * 8;

    unsigned long long v[8];
#pragma unroll
    for (int e = 0; e < 8; ++e) {
        int i = base + e;
        v[e] = (i < cnt) ? ckeys[(size_t)b * 8192 + i] : 0ull;
    }

    cswap_u64(v[0], v[1], true);  cswap_u64(v[2], v[3], false);
    cswap_u64(v[4], v[5], true);  cswap_u64(v[6], v[7], false);
    cswap_u64(v[0], v[2], true);  cswap_u64(v[1], v[3], true);
    cswap_u64(v[4], v[6], false); cswap_u64(v[5], v[7], false);
    cswap_u64(v[0], v[1], true);  cswap_u64(v[2], v[3], true);
    cswap_u64(v[4], v[5], false); cswap_u64(v[6], v[7], false);
    net8(v, (tid & 1) == 0);

    for (int k = 16; k <= 8192; k <<= 1) {
        for (int j = k >> 1; j >= 8; j >>= 1) {
            const bool keep_max = (((base & k) == 0) != ((base & j) != 0));
            if (j >= 512) {
                __syncthreads();
#pragma unroll
                for (int e = 0; e < 8; ++e) S[base + e] = v[e];
                __syncthreads();
                const int pb = base ^ j;
#pragma unroll
                for (int e = 0; e < 8; ++e) {
                    unsigned long long p = S[pb + e];
                    v[e] = keep_max ? (v[e] >= p ? v[e] : p) : (v[e] <= p ? v[e] : p);
                }
            } else {
                const int lmask = j >> 3;
#pragma unroll
                for (int e = 0; e < 8; ++e) {
                    unsigned long long p = shfl_xor_u64(v[e], lmask);
                    v[e] = keep_max ? (v[e] >= p ? v[e] : p) : (v[e] <= p ? v[e] : p);
                }
            }
        }
        net8(v, (base & k) == 0);
    }

#pragma unroll
    for (int e = 0; e < 8; ++e) {
        int i = base + e;
        if (i < NPRE) {
            unsigned long long key = v[e];
            unsigned int idx = 0xFFFFFFFFu - (unsigned int)(key & 0xFFFFFFFFull);
            if (idx >= NANCH) idx = NANCH - 1;   // safety
            float4 bx = ((const float4*)boxes)[(size_t)b * NANCH + idx];
            ((float4*)bk)[(size_t)b * NPRE + i] = bx;
        }
    }
}

// ---------------- IoU bitmask, COLUMN-major — division-free, bit-exact predicate ----------------
__global__ __launch_bounds__(256) void k_mask(const float* __restrict__ bk,
                                              unsigned long long* __restrict__ MT) {
    const int iw = blockIdx.x;
    const int gb = blockIdx.y;
    const int b = blockIdx.z;
    if (iw > 4 * gb + 3) return;
    const int tid = threadIdx.x;
    __shared__ float4 jb[64];
    __shared__ float ja[64];
    if (tid < 64) {
        int j = iw * 64 + tid;
        float4 v = (j < NPRE) ? ((const float4*)bk)[(size_t)b * NPRE + j]
                              : make_float4(0.f, 0.f, 0.f, 0.f);
        jb[tid] = v;
        ja[tid] = (v.z - v.x) * (v.w - v.y);
    }
    __syncthreads();
    const int g = gb * 256 + tid;
    float4 bi = (g < NPRE) ? ((const float4*)bk)[(size_t)b * NPRE + g]
                           : make_float4(0.f, 0.f, 0.f, 0.f);
    float ai = (bi.z - bi.x) * (bi.w - bi.y);
    const double MD = (double)0.7f + 0x1p-25;   // exact rounding midpoint
    unsigned long long word = 0ull;
#pragma unroll 8
    for (int jj = 0; jj < 64; ++jj) {
        float4 bj = jb[jj];
        float aj = ja[jj];
        float ty = fmaxf(bi.x, bj.x), tx = fmaxf(bi.y, bj.y);
        float by = fminf(bi.z, bj.z), bx = fminf(bi.w, bj.w);
        float ihh = fmaxf(by - ty, 0.f), iww = fmaxf(bx - tx, 0.f);
        float inter = ihh * iww;
        float den = ai + aj - inter + 1e-9f;
        if ((double)inter >= MD * (double)den) word |= (1ull << jj);
    }
    if (g < GCOLS)
        MT[((size_t)b * NWORDS + iw) * GCOLS + g] = word;
}

// ---------------- greedy NMS with early break (unchanged) ----------------
__global__ __launch_bounds__(1024) void k_nms(const unsigned long long* __restrict__ MT,
                                              const float* __restrict__ bk,
                                              float* __restrict__ out) {
    const int b = blockIdx.x;
    const int tid = threadIdx.x;
    const int lane = tid & 63;
    __shared__ unsigned long long keptw[NWORDS];
    __shared__ unsigned long long dead[NWORDS];
    __shared__ int sel[NPOST];
    __shared__ int totkept;
    const unsigned long long* mtb = MT + (size_t)b * NWORDS * GCOLS;

    for (int i = tid; i < NWORDS; i += 1024) { dead[i] = 0ull; keptw[i] = 0ull; }
    if (tid == 0) totkept = 0;
    __syncthreads();

    for (int c = 0; c < NWORDS; ++c) {
        if (tid < 64) {   // wave 0: in-chunk greedy closure
            const int g = c * 64 + lane;
            unsigned long long diag = mtb[(size_t)c * GCOLS + g];
            bool deadl = (((dead[c] >> lane) & 1ull) != 0ull) || (g >= NPRE);
            unsigned long long undec = ~__ballot(deadl);
            unsigned long long kc = 0ull;
            while (undec) {
                int i = __builtin_ctzll(undec);
                kc |= (1ull << i);
                unsigned long long supm = __ballot((diag >> i) & 1ull);
                undec &= ~(supm | (1ull << i));
            }
            if (lane == 0) { keptw[c] = kc; totkept += __popcll(kc); }
        }
        __syncthreads();
        if (totkept >= NPOST) break;          // later chunks can't affect the output
        const unsigned long long kc = keptw[c];
        if (kc) {
            for (int g2 = (c + 1) * 64 + tid; g2 < GCOLS; g2 += 1024) {
                unsigned long long w = mtb[(size_t)c * GCOLS + g2] & kc;
                unsigned long long m = __ballot(w != 0ull);
                if (lane == 0 && m) atomicOr(&dead[g2 >> 6], m);
            }
        }
        __syncthreads();
    }

    if (tid == 0) {
        int pos = 0;
        for (int w = 0; w < NWORDS && pos < NPOST; ++w) {
            unsigned long long kw = keptw[w];
            while (kw && pos < NPOST) {
                int i2 = __builtin_ctzll(kw);
                sel[pos++] = w * 64 + i2;
                kw &= kw - 1;
            }
        }
        for (int w = 0; w < NWORDS && pos < NPOST; ++w) {
            int nvalid = NPRE - w * 64; if (nvalid > 64) nvalid = 64;
            unsigned long long vm = (nvalid >= 64) ? ~0ull : ((1ull << nvalid) - 1ull);
            unsigned long long sw = (~keptw[w]) & vm;
            while (sw && pos < NPOST) {
                int i2 = __builtin_ctzll(sw);
                sel[pos++] = w * 64 + i2;
                sw &= sw - 1;
            }
        }
    }
    __syncthreads();
    for (int s2 = tid; s2 < NPOST; s2 += 1024) {
        int i = sel[s2];
        float4 bx = ((const float4*)bk)[(size_t)b * NPRE + i];
        ((float4*)(out + OUT_ROIS))[b * NPOST + s2] = bx;
        out[OUT_RIDX + b * NPOST + s2] = (float)b;
    }
}

// ---------------- launch ----------------
extern "C" void kernel_launch(void* const* d_in, const int* in_sizes, int n_in,
                              void* d_out, int out_size, void* d_ws, size_t ws_size,
                              hipStream_t stream) {
    const float* x = (const float*)d_in[0];
    const float* conv1_w = (const float*)d_in[1];
    const float* conv1_b = (const float*)d_in[2];
    const float* score_w = (const float*)d_in[3];
    const float* score_b = (const float*)d_in[4];
    const float* loc_w = (const float*)d_in[5];
    const float* loc_b = (const float*)d_in[6];
    const int* ihp = (const int*)d_in[7];
    const int* iwp = (const int*)d_in[8];
    float* out = (float*)d_out;
    char* ws = (char*)d_ws;
    float* h = (float*)(ws + H_OFF);
    _Float16* w3h = (_Float16*)(ws + WT_OFF);
    _Float16* w3l = (_Float16*)(ws + WT_OFF + 1179648ul);
    float* boxes = (float*)(ws + BOX_OFF);
    unsigned int* ubuf = (unsigned int*)(ws + U_OFF);
    unsigned long long* ckeys = (unsigned long long*)(ws + CK_OFF);
    unsigned int* cc = (unsigned int*)(ws + CC_OFF);
    float* bk = (float*)(ws + BK_OFF);
    unsigned long long* MT = (unsigned long long*)(ws + M_OFF);

    hipLaunchKernelGGL(k_prep_w, dim3(2304), dim3(256), 0, stream, conv1_w, w3h, w3l);
    hipLaunchKernelGGL(k_anchors, dim3(144), dim3(256), 0, stream, out, cc);
    hipLaunchKernelGGL(k_conv1m, dim3(32, 8), dim3(1024), 0, stream, x, w3h, w3l, conv1_b, h);
    hipLaunchKernelGGL(k_heads, dim3(32, 8), dim3(256), 0, stream,
                       h, loc_w, score_w, loc_b, score_b, ihp, iwp, out, boxes, ubuf);
    hipLaunchKernelGGL(k_select, dim3(8), dim3(1024), 0, stream, ubuf, ckeys, cc);
    hipLaunchKernelGGL(k_sort, dim3(8), dim3(1024), 0, stream, ckeys, cc, boxes, bk);
    hipLaunchKernelGGL(k_mask, dim3(94, 24, 8), dim3(256), 0, stream, bk, MT);
    hipLaunchKernelGGL(k_nms, dim3(8), dim3(1024), 0, stream, MT, bk, out);
}

// Round 8
// 541.781 us; speedup vs baseline: 1.1038x; 1.0981x over previous
//
#include <hip/hip_runtime.h>
#include <cstdint>
#include <cstddef>

// ---------------- problem constants ----------------
#define NBATCH 8
#define MID 256
#define HIMG 64
#define WIMG 64
#define NA 9
#define NPRE 6000
#define NPOST 300
#define NANCH (HIMG*WIMG*NA)   // 36864
#define NWORDS 94              // ceil(6000/64)
#define GCOLS 6016             // 94*64 padded columns
#define LOROWS 16              // speculative mask rows for the NMS early-break fast path

// output float offsets
#define OUT_LOC   0
#define OUT_SCORE 1179648
#define OUT_ROIS  1769472
#define OUT_RIDX  1779072
#define OUT_ANCH  1781472

// workspace byte offsets
#define H_OFF    0ul
#define H_BYTES  (8ul*256*64*64*4)         // 33554432
#define WT_OFF   (H_OFF + H_BYTES)
#define WT_BYTES (2304ul*256*4)            // 2359296 = exactly w3h+w3l (half)
#define BOX_OFF  (WT_OFF + WT_BYTES)
#define BOX_BYTES (8ul*36864*4*4)          // 4718592
#define U_OFF    (BOX_OFF + BOX_BYTES)
#define U_BYTES  (8ul*36864*4)
#define CK_OFF   (U_OFF + U_BYTES)
#define CK_BYTES (8ul*8192*8)
#define CC_OFF   (CK_OFF + CK_BYTES)
#define CC_BYTES 64ul
#define BK_OFF   (CC_OFF + CC_BYTES)
#define BK_BYTES (8ul*6000*16)
#define M_OFF    (BK_OFF + BK_BYTES + 64)
#define M_BYTES  (8ul*NWORDS*GCOLS*8)      // 36.2 MB, column-major mask

typedef _Float16 f16x8 __attribute__((ext_vector_type(8)));
typedef _Float16 f16x4 __attribute__((ext_vector_type(4)));
typedef float f32x16 __attribute__((ext_vector_type(16)));

// ---------------- weight prep: conv1_w[oc][ic][ky][kx] -> w3{h,l}[s][kb][g][oc][8] fp16 hi/lo ----------
// Whole problem scaled by 64 (exact pow2); residuals fp16-normal; epilogue multiplies by 2^-12.
__global__ __launch_bounds__(256) void k_prep_w(const float* __restrict__ w,
                                                _Float16* __restrict__ w3h,
                                                _Float16* __restrict__ w3l) {
    int idx = blockIdx.x * 256 + threadIdx.x;   // 589824 = 9*16*2*256*8
    if (idx >= 589824) return;
    int e  = idx & 7;
    int t  = idx >> 3;
    int oc = t & 255; t >>= 8;
    int g  = t & 1;   t >>= 1;
    int kb = t & 15;  t >>= 4;
    int s  = t;                               // 0..8
    int ic = kb * 16 + g * 8 + e;
    float v = w[(oc * 256 + ic) * 9 + s] * 64.0f;   // exact pow2 scale
    _Float16 vh = (_Float16)v;
    float r = v - (float)vh;                  // exact in fp32
    w3h[idx] = vh;
    w3l[idx] = (_Float16)r;                   // fp16-normal (64-scale)
}

// ---------------- anchors output (exact double->f32 like numpy) + zero counters ----------------
__global__ void k_anchors(float* __restrict__ out, unsigned int* __restrict__ cc) {
    int idx = blockIdx.x * 256 + threadIdx.x;
    if (blockIdx.x == 0 && threadIdx.x < 16) cc[threadIdx.x] = 0u;
    if (idx >= NANCH) return;
    int p = idx / 9, a = idx - p * 9;
    int y = p >> 6, xg = p & 63;
    double rr = (a < 3) ? 0.5 : ((a < 6) ? 1.0 : 2.0);
    int sj = a % 3;
    double ssc = (sj == 0) ? 8.0 : ((sj == 1) ? 16.0 : 32.0);
    double hh = 7.0 * ssc * sqrt(rr);
    double ww = 7.0 * ssc * sqrt(1.0 / rr);
    float a0 = (float)(3.5 - 0.5 * hh), a2 = (float)(3.5 + 0.5 * hh);
    float b0 = (float)(3.5 - 0.5 * ww), b2 = (float)(3.5 + 0.5 * ww);
    float* dst = out + OUT_ANCH + (size_t)idx * 4;
    dst[0] = y * 16.0f + a0;
    dst[1] = xg * 16.0f + b0;
    dst[2] = y * 16.0f + a2;
    dst[3] = xg * 16.0f + b2;
}

// ---------------- conv1 3x3 + bias + relu via fp16 hi/lo split MFMA (unchanged from R7) ----------------
__global__ __launch_bounds__(1024) void k_conv1m(const float* __restrict__ x,
                                                 const _Float16* __restrict__ w3h,
                                                 const _Float16* __restrict__ w3l,
                                                 const float* __restrict__ bias,
                                                 float* __restrict__ h) {
    __shared__ __align__(16) _Float16 bt0[4 * 66 * 26];   // hi
    __shared__ __align__(16) _Float16 bt1[4 * 66 * 26];   // lo
    __shared__ float bsh[256];

    const int tid = threadIdx.x;
    const int lane = tid & 63;
    const int wv = tid >> 6;        // 0..15
    const int ocg = wv >> 1;        // 0..7 : oc block 32*ocg
    const int wn = wv & 1;          // 0..1 : image row y0+wn
    const int y0 = blockIdx.x * 2;
    const int n  = blockIdx.y;
    const int bl31 = lane & 31;
    const int g = lane >> 5;        // ic-subgroup for fragments

    for (int i = tid; i < 858; i += 1024) {
        ((f16x8*)bt0)[i] = (f16x8){};
        ((f16x8*)bt1)[i] = (f16x8){};
    }
    if (tid < 256) bsh[tid] = bias[tid];

    f32x16 acc[2];
#pragma unroll
    for (int j = 0; j < 2; ++j)
#pragma unroll
        for (int e = 0; e < 16; ++e) acc[j][e] = 0.0f;

    const int scol = lane;          // 0..63
    const int sr   = wv & 3;        // halo row 0..3 -> gy = y0-1+sr
    const int sg   = wv >> 2;       // ic-subgroup 0..3 (4 ic each)
    const int sgy  = y0 - 1 + sr;
    const bool gyok = (sgy >= 0) && (sgy < 64);
    const float* xrow = x + (size_t)n * 1048576 + sgy * 64 + scol;
    const int bto = (sr * 66 + scol + 1) * 26 + sg * 4;

    const int aoffl = (g * 256 + ocg * 32 + bl31) * 8;
    const _Float16* wph = w3h + aoffl;
    const _Float16* wpl = w3l + aoffl;

    float xr[4];
#pragma unroll
    for (int q = 0; q < 4; ++q)
        xr[q] = gyok ? xrow[(size_t)(sg * 4 + q) * 4096] : 0.0f;

    f16x8 AhC = *(const f16x8*)(wph);
    f16x8 AlC = *(const f16x8*)(wpl);

    for (int kb = 0; kb < 16; ++kb) {
        __syncthreads();
        {
            f16x4 hh, hl;
#pragma unroll
            for (int q = 0; q < 4; ++q) {
                float v = xr[q] * 64.0f;           // exact pow2 scale
                _Float16 vh = (_Float16)v;
                hh[q] = vh;
                hl[q] = (_Float16)(v - (float)vh); // fp16-normal residual
            }
            *(f16x4*)&bt0[bto] = hh;
            *(f16x4*)&bt1[bto] = hl;
        }
        __syncthreads();
        if (kb < 15) {
#pragma unroll
            for (int q = 0; q < 4; ++q)
                xr[q] = gyok ? xrow[(size_t)((kb + 1) * 16 + sg * 4 + q) * 4096] : 0.0f;
        }

        const int ent00 = wn * 66 + bl31;
        f16x8 Bh0C = *(const f16x8*)&bt0[ent00 * 26 + g * 8];
        f16x8 Bl0C = *(const f16x8*)&bt1[ent00 * 26 + g * 8];
        f16x8 Bh1C = *(const f16x8*)&bt0[(ent00 + 32) * 26 + g * 8];
        f16x8 Bl1C = *(const f16x8*)&bt1[(ent00 + 32) * 26 + g * 8];

        const int kbn_base = (kb < 15) ? (kb + 1) : 15;
        const _Float16* wkh = wph + (size_t)kb * 4096;
        const _Float16* wkl = wpl + (size_t)kb * 4096;
        (void)wkh; (void)wkl;
#pragma unroll
        for (int s = 0; s < 9; ++s) {
            const int sn  = (s == 8) ? 0 : (s + 1);
            const int kbn = (s == 8) ? kbn_base : kb;
            const _Float16* phn = wph + (size_t)kbn * 4096 + (size_t)sn * 65536;
            const _Float16* pln = wpl + (size_t)kbn * 4096 + (size_t)sn * 65536;
            f16x8 AhN = *(const f16x8*)(phn);
            f16x8 AlN = *(const f16x8*)(pln);

            f16x8 Bh0N = Bh0C, Bl0N = Bl0C, Bh1N = Bh1C, Bl1N = Bl1C;
            if (s < 8) {
                const int dyn = sn / 3 - 1, dxn = sn % 3 - 1;
                const int entn = (wn + dyn + 1) * 66 + dxn + 1 + bl31;
                const int en0 = entn * 26 + g * 8;
                const int en1 = (entn + 32) * 26 + g * 8;
                Bh0N = *(const f16x8*)&bt0[en0];
                Bl0N = *(const f16x8*)&bt1[en0];
                Bh1N = *(const f16x8*)&bt0[en1];
                Bl1N = *(const f16x8*)&bt1[en1];
            }

            __builtin_amdgcn_s_setprio(1);
            acc[0] = __builtin_amdgcn_mfma_f32_32x32x16_f16(AhC, Bh0C, acc[0], 0, 0, 0);
            acc[1] = __builtin_amdgcn_mfma_f32_32x32x16_f16(AhC, Bh1C, acc[1], 0, 0, 0);
            acc[0] = __builtin_amdgcn_mfma_f32_32x32x16_f16(AhC, Bl0C, acc[0], 0, 0, 0);
            acc[1] = __builtin_amdgcn_mfma_f32_32x32x16_f16(AhC, Bl1C, acc[1], 0, 0, 0);
            acc[0] = __builtin_amdgcn_mfma_f32_32x32x16_f16(AlC, Bh0C, acc[0], 0, 0, 0);
            acc[1] = __builtin_amdgcn_mfma_f32_32x32x16_f16(AlC, Bh1C, acc[1], 0, 0, 0);
            __builtin_amdgcn_s_setprio(0);

            AhC = AhN; AlC = AlN;
            Bh0C = Bh0N; Bl0C = Bl0N; Bh1C = Bh1N; Bl1C = Bl1N;
        }
    }

    const int colw = lane & 31;
    const int rgh = (lane >> 5) * 4;
    float* hn = h + (size_t)n * 1048576 + (size_t)(y0 + wn) * 64;
#pragma unroll
    for (int pcb = 0; pcb < 2; ++pcb)
#pragma unroll
        for (int reg = 0; reg < 16; ++reg) {
            const int row = (reg & 3) + 8 * (reg >> 2) + rgh;
            const int oc = ocg * 32 + row;
            float v = acc[pcb][reg] * 2.44140625e-4f + bsh[oc];   // *2^-12
            hn[(size_t)oc * 4096 + pcb * 32 + colw] = fmaxf(v, 0.0f);
        }
}

// ---------------- 1x1 heads — unchanged (verified) ----------------
__global__ __launch_bounds__(256) void k_heads(const float* __restrict__ h,
                                               const float* __restrict__ loc_w,
                                               const float* __restrict__ score_w,
                                               const float* __restrict__ loc_b,
                                               const float* __restrict__ score_b,
                                               const int* __restrict__ ihp,
                                               const int* __restrict__ iwp,
                                               float* __restrict__ out,
                                               float* __restrict__ boxes,
                                               unsigned int* __restrict__ ubuf) {
    __shared__ float Wl[54 * 64];     // [c][kk]
    __shared__ float outb[128 * 57];  // [p][c] pitch 57
    const int tid = threadIdx.x;
    const int pl = tid & 127, chalf = tid >> 7;
    const int c0 = chalf * 27;
    const int ptile = blockIdx.x;
    const int n = blockIdx.y;
    const int pg = ptile * 128 + pl;

    float acc[27];
#pragma unroll
    for (int i = 0; i < 27; ++i) acc[i] = 0.f;

    for (int kc = 0; kc < 4; ++kc) {
        __syncthreads();
        for (int idx = tid; idx < 54 * 64; idx += 256) {
            int c = idx >> 6, kk = idx & 63;
            int gk = kc * 64 + kk;
            Wl[idx] = (c < 36) ? loc_w[c * 256 + gk] : score_w[(c - 36) * 256 + gk];
        }
        __syncthreads();
        for (int k4 = 0; k4 < 64; k4 += 4) {
            int gk = kc * 64 + k4;
            float hv0 = h[(n * 256 + gk + 0) * 4096 + pg];
            float hv1 = h[(n * 256 + gk + 1) * 4096 + pg];
            float hv2 = h[(n * 256 + gk + 2) * 4096 + pg];
            float hv3 = h[(n * 256 + gk + 3) * 4096 + pg];
#pragma unroll
            for (int ci = 0; ci < 27; ++ci) {
                float4 w4 = *(const float4*)&Wl[(c0 + ci) * 64 + k4];
                acc[ci] += hv0 * w4.x + hv1 * w4.y + hv2 * w4.z + hv3 * w4.w;
            }
        }
    }
#pragma unroll
    for (int ci = 0; ci < 27; ++ci) {
        int c = c0 + ci;
        float bv = (c < 36) ? loc_b[c] : score_b[c - 36];
        outb[pl * 57 + c] = acc[ci] + bv;
    }
    __syncthreads();

    const float fh = (float)(*ihp), fwid = (float)(*iwp);
    for (int slot = tid; slot < 128 * 9; slot += 256) {
        int pli = slot / 9, a = slot - pli * 9;
        int p = ptile * 128 + pli;
        int y = p >> 6, xg = p & 63;
        float l0 = outb[pli * 57 + a * 4 + 0];
        float l1 = outb[pli * 57 + a * 4 + 1];
        float l2 = outb[pli * 57 + a * 4 + 2];
        float l3 = outb[pli * 57 + a * 4 + 3];
        float s0 = outb[pli * 57 + 36 + a * 2 + 0];
        float s1 = outb[pli * 57 + 36 + a * 2 + 1];
        size_t base = (size_t)n * NANCH + (size_t)p * 9 + a;
        ((float4*)(out + OUT_LOC))[base] = make_float4(l0, l1, l2, l3);
        ((float2*)(out + OUT_SCORE))[base] = make_float2(s0, s1);
        float mx = fmaxf(s0, s1);
        float e0 = expf(s0 - mx), e1 = expf(s1 - mx);
        float fg = e1 / (e0 + e1);
        double rr = (a < 3) ? 0.5 : ((a < 6) ? 1.0 : 2.0);
        int sj = a % 3;
        double ssc = (sj == 0) ? 8.0 : ((sj == 1) ? 16.0 : 32.0);
        double hhd = 7.0 * ssc * sqrt(rr);
        double wwd = 7.0 * ssc * sqrt(1.0 / rr);
        float a0 = (float)(3.5 - 0.5 * hhd), a2 = (float)(3.5 + 0.5 * hhd);
        float b0 = (float)(3.5 - 0.5 * wwd), b2 = (float)(3.5 + 0.5 * wwd);
        float ay1 = y * 16.0f + a0, ay2 = y * 16.0f + a2;
        float ax1 = xg * 16.0f + b0, ax2 = xg * 16.0f + b2;
        float ah = ay2 - ay1, aw = ax2 - ax1;
        float acy = ay1 + 0.5f * ah, acx = ax1 + 0.5f * aw;
        float cy = l0 * ah + acy, cx = l1 * aw + acx;
        float bh = expf(l2) * ah, bw = expf(l3) * aw;
        float y1 = fminf(fmaxf(cy - 0.5f * bh, 0.f), fh);
        float x1 = fminf(fmaxf(cx - 0.5f * bw, 0.f), fwid);
        float y2 = fminf(fmaxf(cy + 0.5f * bh, 0.f), fh);
        float x2 = fminf(fmaxf(cx + 0.5f * bw, 0.f), fwid);
        ((float4*)boxes)[base] = make_float4(y1, x1, y2, x2);
        bool valid = ((y2 - y1) >= 16.0f) && ((x2 - x1) >= 16.0f);
        float sc = valid ? fg : -__builtin_inff();
        unsigned int ub = __float_as_uint(sc);
        ub = (ub & 0x80000000u) ? ~ub : (ub | 0x80000000u);
        ubuf[base] = ub;
    }
}

// ---------------- exact top-6000 per batch: byte-radix select + compact (unchanged) ----------------
__global__ __launch_bounds__(1024) void k_select(const unsigned int* __restrict__ ubuf,
                                                 unsigned long long* __restrict__ ckeys,
                                                 unsigned int* __restrict__ cc) {
    __shared__ unsigned int hist[256];
    __shared__ unsigned int selb;
    __shared__ int rank_s;
    __shared__ unsigned int lcnt;
    const int tid = threadIdx.x;
    const int b = blockIdx.x;
    const unsigned int* ub = ubuf + (size_t)b * NANCH;
    if (tid == 0) { rank_s = NPRE - 1; lcnt = 0; }
    unsigned int prefix = 0;
    for (int pass = 0; pass < 4; ++pass) {
        int shift = 24 - 8 * pass;
        if (tid < 256) hist[tid] = 0;
        __syncthreads();
        for (int i = tid; i < NANCH; i += 1024) {
            unsigned int u = ub[i];
            bool ok = (pass == 0) || ((u >> (shift + 8)) == (prefix >> (shift + 8)));
            if (ok) atomicAdd(&hist[(u >> shift) & 255], 1u);
        }
        __syncthreads();
        if (tid == 0) {
            int racc = 0; unsigned int bs = 0; int r = rank_s;
            for (int bb = 255; bb >= 0; --bb) {
                int c = (int)hist[bb];
                if (racc + c > r) { bs = (unsigned int)bb; rank_s = r - racc; break; }
                racc += c;
            }
            selb = bs;
        }
        __syncthreads();
        prefix |= (selb << shift);
        __syncthreads();
    }
    const unsigned int ustar = prefix;
    for (int i = tid; i < NANCH; i += 1024) {
        unsigned int u = ub[i];
        if (u >= ustar) {
            unsigned int pos = atomicAdd(&lcnt, 1u);
            if (pos < 8192)
                ckeys[(size_t)b * 8192 + pos] =
                    ((unsigned long long)u << 32) | (unsigned int)(0xFFFFFFFFu - (unsigned int)i);
        }
    }
    __syncthreads();
    if (tid == 0) cc[b] = (lcnt > 8192u) ? 8192u : lcnt;
}

// ---------------- bitonic sort 8192: in-register (8 keys/thread) + shuffle + minimal LDS ----------------
__device__ __forceinline__ void cswap_u64(unsigned long long& a, unsigned long long& c, bool desc) {
    bool sw = desc ? (a < c) : (a > c);
    unsigned long long t0 = sw ? c : a;
    unsigned long long t1 = sw ? a : c;
    a = t0; c = t1;
}
__device__ __forceinline__ void net8(unsigned long long v[8], bool d) {
    cswap_u64(v[0], v[4], d); cswap_u64(v[1], v[5], d); cswap_u64(v[2], v[6], d); cswap_u64(v[3], v[7], d);
    cswap_u64(v[0], v[2], d); cswap_u64(v[1], v[3], d); cswap_u64(v[4], v[6], d); cswap_u64(v[5], v[7], d);
    cswap_u64(v[0], v[1], d); cswap_u64(v[2], v[3], d); cswap_u64(v[4], v[5], d); cswap_u64(v[6], v[7], d);
}
__device__ __forceinline__ unsigned long long shfl_xor_u64(unsigned long long x, int lmask) {
    unsigned int lo = (unsigned int)x, hi = (unsigned int)(x >> 32);
    lo = __shfl_xor(lo, lmask, 64);
    hi = __shfl_xor(hi, lmask, 64);
    return ((unsigned long long)hi << 32) | lo;
}
__global__ __launch_bounds__(1024) void k_sort(const unsigned long long* __restrict__ ckeys,
                                               const unsigned int* __restrict__ cc,
                                               const float* __restrict__ boxes,
                                               float* __restrict__ bk) {
    __shared__ unsigned long long S[8192];
    const int tid = threadIdx.x;
    const int b = blockIdx.x;
    const int cnt = (int)cc[b];
    const int base = tid * 8;

    unsigned long long v[8];
#pragma unroll
    for (int e = 0; e < 8; ++e) {
        int i = base + e;
        v[e] = (i < cnt) ? ckeys[(size_t)b * 8192 + i] : 0ull;
    }

    cswap_u64(v[0], v[1], true);  cswap_u64(v[2], v[3], false);
    cswap_u64(v[4], v[5], true);  cswap_u64(v[6], v[7], false);
    cswap_u64(v[0], v[2], true);  cswap_u64(v[1], v[3], true);
    cswap_u64(v[4], v[6], false); cswap_u64(v[5], v[7], false);
    cswap_u64(v[0], v[1], true);  cswap_u64(v[2], v[3], true);
    cswap_u64(v[4], v[5], false); cswap_u64(v[6], v[7], false);
    net8(v, (tid & 1) == 0);

    for (int k = 16; k <= 8192; k <<= 1) {
        for (int j = k >> 1; j >= 8; j >>= 1) {
            const bool keep_max = (((base & k) == 0) != ((base & j) != 0));
            if (j >= 512) {
                __syncthreads();
#pragma unroll
                for (int e = 0; e < 8; ++e) S[base + e] = v[e];
                __syncthreads();
                const int pb = base ^ j;
#pragma unroll
                for (int e = 0; e < 8; ++e) {
                    unsigned long long p = S[pb + e];
                    v[e] = keep_max ? (v[e] >= p ? v[e] : p) : (v[e] <= p ? v[e] : p);
                }
            } else {
                const int lmask = j >> 3;
#pragma unroll
                for (int e = 0; e < 8; ++e) {
                    unsigned long long p = shfl_xor_u64(v[e], lmask);
                    v[e] = keep_max ? (v[e] >= p ? v[e] : p) : (v[e] <= p ? v[e] : p);
                }
            }
        }
        net8(v, (base & k) == 0);
    }

#pragma unroll
    for (int e = 0; e < 8; ++e) {
        int i = base + e;
        if (i < NPRE) {
            unsigned long long key = v[e];
            unsigned int idx = 0xFFFFFFFFu - (unsigned int)(key & 0xFFFFFFFFull);
            if (idx >= NANCH) idx = NANCH - 1;   // safety
            float4 bx = ((const float4*)boxes)[(size_t)b * NANCH + idx];
            ((float4*)bk)[(size_t)b * NPRE + i] = bx;
        }
    }
}

// ---------------- IoU bitmask, COLUMN-major — division-free bit-exact predicate ----------------
// R8: iwbase/checkdone args. Speculative split: rows 0..LOROWS-1 first; hi rows only if the
// NMS early-break didn't fire within LOROWS chunks (cc[8+b] == 0).
__global__ __launch_bounds__(256) void k_mask(const float* __restrict__ bk,
                                              unsigned long long* __restrict__ MT,
                                              const unsigned int* __restrict__ cc,
                                              int iwbase, int checkdone) {
    const int iw = iwbase + blockIdx.x;
    const int gb = blockIdx.y;
    const int b = blockIdx.z;
    if (checkdone && cc[8 + b] != 0u) return;   // speculation succeeded; rows not needed
    if (iw > 4 * gb + 3) return;
    const int tid = threadIdx.x;
    __shared__ float4 jb[64];
    __shared__ float ja[64];
    if (tid < 64) {
        int j = iw * 64 + tid;
        float4 v = (j < NPRE) ? ((const float4*)bk)[(size_t)b * NPRE + j]
                              : make_float4(0.f, 0.f, 0.f, 0.f);
        jb[tid] = v;
        ja[tid] = (v.z - v.x) * (v.w - v.y);
    }
    __syncthreads();
    const int g = gb * 256 + tid;
    float4 bi = (g < NPRE) ? ((const float4*)bk)[(size_t)b * NPRE + g]
                           : make_float4(0.f, 0.f, 0.f, 0.f);
    float ai = (bi.z - bi.x) * (bi.w - bi.y);
    const double MD = (double)0.7f + 0x1p-25;   // exact rounding midpoint
    unsigned long long word = 0ull;
#pragma unroll 8
    for (int jj = 0; jj < 64; ++jj) {
        float4 bj = jb[jj];
        float aj = ja[jj];
        float ty = fmaxf(bi.x, bj.x), tx = fmaxf(bi.y, bj.y);
        float by = fminf(bi.z, bj.z), bx = fminf(bi.w, bj.w);
        float ihh = fmaxf(by - ty, 0.f), iww = fmaxf(bx - tx, 0.f);
        float inter = ihh * iww;
        float den = ai + aj - inter + 1e-9f;
        if ((double)inter >= MD * (double)den) word |= (1ull << jj);
    }
    if (g < GCOLS)
        MT[((size_t)b * NWORDS + iw) * GCOLS + g] = word;
}

// ---------------- greedy NMS, speculative try over first LOROWS chunks ----------------
// Kept decisions for chunk c depend only on chunks < c; if cumulative kept >= 300 within
// LOROWS chunks, the output is final (bit-identical to full NMS). Sets cc[8+b] done-flag.
__global__ __launch_bounds__(1024) void k_nms_try(const unsigned long long* __restrict__ MT,
                                                  const float* __restrict__ bk,
                                                  float* __restrict__ out,
                                                  unsigned int* __restrict__ cc) {
    const int b = blockIdx.x;
    const int tid = threadIdx.x;
    const int lane = tid & 63;
    __shared__ unsigned long long keptw[NWORDS];
    __shared__ unsigned long long dead[LOROWS];
    __shared__ int sel[NPOST];
    __shared__ int totkept;
    const unsigned long long* mtb = MT + (size_t)b * NWORDS * GCOLS;

    for (int i = tid; i < NWORDS; i += 1024) keptw[i] = 0ull;
    if (tid < LOROWS) dead[tid] = 0ull;
    if (tid == 0) totkept = 0;
    __syncthreads();

    for (int c = 0; c < LOROWS; ++c) {
        if (tid < 64) {   // wave 0: in-chunk greedy closure
            const int g = c * 64 + lane;
            unsigned long long diag = mtb[(size_t)c * GCOLS + g];
            bool deadl = (((dead[c] >> lane) & 1ull) != 0ull) || (g >= NPRE);
            unsigned long long undec = ~__ballot(deadl);
            unsigned long long kc = 0ull;
            while (undec) {
                int i = __builtin_ctzll(undec);
                kc |= (1ull << i);
                unsigned long long supm = __ballot((diag >> i) & 1ull);
                undec &= ~(supm | (1ull << i));
            }
            if (lane == 0) { keptw[c] = kc; totkept += __popcll(kc); }
        }
        __syncthreads();
        if (totkept >= NPOST) break;          // later chunks can't affect the output
        const unsigned long long kc = keptw[c];
        if (kc) {
            // propagate only into the LOROWS window (dead beyond it is irrelevant here)
            for (int g2 = (c + 1) * 64 + tid; g2 < LOROWS * 64; g2 += 1024) {
                unsigned long long w = mtb[(size_t)c * GCOLS + g2] & kc;
                unsigned long long m = __ballot(w != 0ull);
                if (lane == 0 && m) atomicOr(&dead[g2 >> 6], m);
            }
        }
        __syncthreads();
    }

    const int done = (totkept >= NPOST) ? 1 : 0;
    if (tid == 0) cc[8 + b] = (unsigned int)done;
    if (!done) return;                        // fall back to k_mask(hi) + k_nms_full

    if (tid == 0) {
        int pos = 0;
        for (int w = 0; w < NWORDS && pos < NPOST; ++w) {
            unsigned long long kw = keptw[w];
            while (kw && pos < NPOST) {
                int i2 = __builtin_ctzll(kw);
                sel[pos++] = w * 64 + i2;
                kw &= kw - 1;
            }
        }
    }
    __syncthreads();
    for (int s2 = tid; s2 < NPOST; s2 += 1024) {
        int i = sel[s2];
        float4 bx = ((const float4*)bk)[(size_t)b * NPRE + i];
        ((float4*)(out + OUT_ROIS))[b * NPOST + s2] = bx;
        out[OUT_RIDX + b * NPOST + s2] = (float)b;
    }
}

// ---------------- full greedy NMS fallback (runs only when try didn't finish) ----------------
__global__ __launch_bounds__(1024) void k_nms_full(const unsigned long long* __restrict__ MT,
                                                   const float* __restrict__ bk,
                                                   float* __restrict__ out,
                                                   const unsigned int* __restrict__ cc) {
    const int b = blockIdx.x;
    if (cc[8 + b] != 0u) return;              // speculation succeeded
    const int tid = threadIdx.x;
    const int lane = tid & 63;
    __shared__ unsigned long long keptw[NWORDS];
    __shared__ unsigned long long dead[NWORDS];
    __shared__ int sel[NPOST];
    __shared__ int totkept;
    const unsigned long long* mtb = MT + (size_t)b * NWORDS * GCOLS;

    for (int i = tid; i < NWORDS; i += 1024) { dead[i] = 0ull; keptw[i] = 0ull; }
    if (tid == 0) totkept = 0;
    __syncthreads();

    for (int c = 0; c < NWORDS; ++c) {
        if (tid < 64) {   // wave 0: in-chunk greedy closure
            const int g = c * 64 + lane;
            unsigned long long diag = mtb[(size_t)c * GCOLS + g];
            bool deadl = (((dead[c] >> lane) & 1ull) != 0ull) || (g >= NPRE);
            unsigned long long undec = ~__ballot(deadl);
            unsigned long long kc = 0ull;
            while (undec) {
                int i = __builtin_ctzll(undec);
                kc |= (1ull << i);
                unsigned long long supm = __ballot((diag >> i) & 1ull);
                undec &= ~(supm | (1ull << i));
            }
            if (lane == 0) { keptw[c] = kc; totkept += __popcll(kc); }
        }
        __syncthreads();
        if (totkept >= NPOST) break;          // later chunks can't affect the output
        const unsigned long long kc = keptw[c];
        if (kc) {
            for (int g2 = (c + 1) * 64 + tid; g2 < GCOLS; g2 += 1024) {
                unsigned long long w = mtb[(size_t)c * GCOLS + g2] & kc;
                unsigned long long m = __ballot(w != 0ull);
                if (lane == 0 && m) atomicOr(&dead[g2 >> 6], m);
            }
        }
        __syncthreads();
    }

    if (tid == 0) {
        int pos = 0;
        for (int w = 0; w < NWORDS && pos < NPOST; ++w) {
            unsigned long long kw = keptw[w];
            while (kw && pos < NPOST) {
                int i2 = __builtin_ctzll(kw);
                sel[pos++] = w * 64 + i2;
                kw &= kw - 1;
            }
        }
        for (int w = 0; w < NWORDS && pos < NPOST; ++w) {
            int nvalid = NPRE - w * 64; if (nvalid > 64) nvalid = 64;
            unsigned long long vm = (nvalid >= 64) ? ~0ull : ((1ull << nvalid) - 1ull);
            unsigned long long sw = (~keptw[w]) & vm;
            while (sw && pos < NPOST) {
                int i2 = __builtin_ctzll(sw);
                sel[pos++] = w * 64 + i2;
                sw &= sw - 1;
            }
        }
    }
    __syncthreads();
    for (int s2 = tid; s2 < NPOST; s2 += 1024) {
        int i = sel[s2];
        float4 bx = ((const float4*)bk)[(size_t)b * NPRE + i];
        ((float4*)(out + OUT_ROIS))[b * NPOST + s2] = bx;
        out[OUT_RIDX + b * NPOST + s2] = (float)b;
    }
}

// ---------------- launch ----------------
extern "C" void kernel_launch(void* const* d_in, const int* in_sizes, int n_in,
                              void* d_out, int out_size, void* d_ws, size_t ws_size,
                              hipStream_t stream) {
    const float* x = (const float*)d_in[0];
    const float* conv1_w = (const float*)d_in[1];
    const float* conv1_b = (const float*)d_in[2];
    const float* score_w = (const float*)d_in[3];
    const float* score_b = (const float*)d_in[4];
    const float* loc_w = (const float*)d_in[5];
    const float* loc_b = (const float*)d_in[6];
    const int* ihp = (const int*)d_in[7];
    const int* iwp = (const int*)d_in[8];
    float* out = (float*)d_out;
    char* ws = (char*)d_ws;
    float* h = (float*)(ws + H_OFF);
    _Float16* w3h = (_Float16*)(ws + WT_OFF);
    _Float16* w3l = (_Float16*)(ws + WT_OFF + 1179648ul);
    float* boxes = (float*)(ws + BOX_OFF);
    unsigned int* ubuf = (unsigned int*)(ws + U_OFF);
    unsigned long long* ckeys = (unsigned long long*)(ws + CK_OFF);
    unsigned int* cc = (unsigned int*)(ws + CC_OFF);
    float* bk = (float*)(ws + BK_OFF);
    unsigned long long* MT = (unsigned long long*)(ws + M_OFF);

    hipLaunchKernelGGL(k_prep_w, dim3(2304), dim3(256), 0, stream, conv1_w, w3h, w3l);
    hipLaunchKernelGGL(k_anchors, dim3(144), dim3(256), 0, stream, out, cc);
    hipLaunchKernelGGL(k_conv1m, dim3(32, 8), dim3(1024), 0, stream, x, w3h, w3l, conv1_b, h);
    hipLaunchKernelGGL(k_heads, dim3(32, 8), dim3(256), 0, stream,
                       h, loc_w, score_w, loc_b, score_b, ihp, iwp, out, boxes, ubuf);
    hipLaunchKernelGGL(k_select, dim3(8), dim3(1024), 0, stream, ubuf, ckeys, cc);
    hipLaunchKernelGGL(k_sort, dim3(8), dim3(1024), 0, stream, ckeys, cc, boxes, bk);
    // speculative low rows -> NMS try -> (conditional) high rows -> (conditional) full NMS
    hipLaunchKernelGGL(k_mask, dim3(LOROWS, 24, 8), dim3(256), 0, stream, bk, MT, cc, 0, 0);
    hipLaunchKernelGGL(k_nms_try, dim3(8), dim3(1024), 0, stream, MT, bk, out, cc);
    hipLaunchKernelGGL(k_mask, dim3(NWORDS - LOROWS, 24, 8), dim3(256), 0, stream, bk, MT, cc, LOROWS, 1);
    hipLaunchKernelGGL(k_nms_full, dim3(8), dim3(1024), 0, stream, MT, bk, out, cc);
}

// Round 9
// 497.319 us; speedup vs baseline: 1.2025x; 1.0894x over previous
//
#include <hip/hip_runtime.h>
#include <cstdint>
#include <cstddef>

// ---------------- problem constants ----------------
#define NBATCH 8
#define MID 256
#define HIMG 64
#define WIMG 64
#define NA 9
#define NPRE 6000
#define NPOST 300
#define NANCH (HIMG*WIMG*NA)   // 36864
#define NWORDS 94              // ceil(6000/64)
#define GCOLS 6016             // 94*64 padded columns
#define LOROWS 16              // speculative mask rows for the NMS early-break fast path

// output float offsets
#define OUT_LOC   0
#define OUT_SCORE 1179648
#define OUT_ROIS  1769472
#define OUT_RIDX  1779072
#define OUT_ANCH  1781472

// workspace byte offsets
#define H_OFF    0ul
#define H_BYTES  (8ul*256*64*64*4)         // 33554432
#define WT_OFF   (H_OFF + H_BYTES)
#define WT_BYTES (2304ul*256*4)            // 2359296 = exactly w3h+w3l (half)
#define BOX_OFF  (WT_OFF + WT_BYTES)
#define BOX_BYTES (8ul*36864*4*4)          // 4718592
#define U_OFF    (BOX_OFF + BOX_BYTES)
#define U_BYTES  (8ul*36864*4)
#define CK_OFF   (U_OFF + U_BYTES)
#define CK_BYTES (8ul*8192*8)
#define CC_OFF   (CK_OFF + CK_BYTES)
#define CC_BYTES 64ul
#define BK_OFF   (CC_OFF + CC_BYTES)
#define BK_BYTES (8ul*6000*16)
#define M_OFF    (BK_OFF + BK_BYTES + 64)
#define M_BYTES  (8ul*NWORDS*GCOLS*8)      // 36.2 MB, column-major mask

typedef _Float16 f16x8 __attribute__((ext_vector_type(8)));
typedef _Float16 f16x4 __attribute__((ext_vector_type(4)));
typedef float f32x16 __attribute__((ext_vector_type(16)));

// ---------------- weight prep: conv1_w[oc][ic][ky][kx] -> w3{h,l}[s][kb][g][oc][8] fp16 hi/lo ----------
// Whole problem scaled by 64 (exact pow2); residuals fp16-normal; epilogue multiplies by 2^-12.
__global__ __launch_bounds__(256) void k_prep_w(const float* __restrict__ w,
                                                _Float16* __restrict__ w3h,
                                                _Float16* __restrict__ w3l) {
    int idx = blockIdx.x * 256 + threadIdx.x;   // 589824 = 9*16*2*256*8
    if (idx >= 589824) return;
    int e  = idx & 7;
    int t  = idx >> 3;
    int oc = t & 255; t >>= 8;
    int g  = t & 1;   t >>= 1;
    int kb = t & 15;  t >>= 4;
    int s  = t;                               // 0..8
    int ic = kb * 16 + g * 8 + e;
    float v = w[(oc * 256 + ic) * 9 + s] * 64.0f;   // exact pow2 scale
    _Float16 vh = (_Float16)v;
    float r = v - (float)vh;                  // exact in fp32
    w3h[idx] = vh;
    w3l[idx] = (_Float16)r;                   // fp16-normal (64-scale)
}

// ---------------- anchors output (exact double->f32 like numpy) + zero counters ----------------
__global__ void k_anchors(float* __restrict__ out, unsigned int* __restrict__ cc) {
    int idx = blockIdx.x * 256 + threadIdx.x;
    if (blockIdx.x == 0 && threadIdx.x < 16) cc[threadIdx.x] = 0u;
    if (idx >= NANCH) return;
    int p = idx / 9, a = idx - p * 9;
    int y = p >> 6, xg = p & 63;
    double rr = (a < 3) ? 0.5 : ((a < 6) ? 1.0 : 2.0);
    int sj = a % 3;
    double ssc = (sj == 0) ? 8.0 : ((sj == 1) ? 16.0 : 32.0);
    double hh = 7.0 * ssc * sqrt(rr);
    double ww = 7.0 * ssc * sqrt(1.0 / rr);
    float a0 = (float)(3.5 - 0.5 * hh), a2 = (float)(3.5 + 0.5 * hh);
    float b0 = (float)(3.5 - 0.5 * ww), b2 = (float)(3.5 + 0.5 * ww);
    float* dst = out + OUT_ANCH + (size_t)idx * 4;
    dst[0] = y * 16.0f + a0;
    dst[1] = xg * 16.0f + b0;
    dst[2] = y * 16.0f + a2;
    dst[3] = xg * 16.0f + b2;
}

// ---------------- conv1 3x3 + bias + relu via fp16 hi/lo split MFMA (unchanged from R7) ----------------
__global__ __launch_bounds__(1024) void k_conv1m(const float* __restrict__ x,
                                                 const _Float16* __restrict__ w3h,
                                                 const _Float16* __restrict__ w3l,
                                                 const float* __restrict__ bias,
                                                 float* __restrict__ h) {
    __shared__ __align__(16) _Float16 bt0[4 * 66 * 26];   // hi
    __shared__ __align__(16) _Float16 bt1[4 * 66 * 26];   // lo
    __shared__ float bsh[256];

    const int tid = threadIdx.x;
    const int lane = tid & 63;
    const int wv = tid >> 6;        // 0..15
    const int ocg = wv >> 1;        // 0..7 : oc block 32*ocg
    const int wn = wv & 1;          // 0..1 : image row y0+wn
    const int y0 = blockIdx.x * 2;
    const int n  = blockIdx.y;
    const int bl31 = lane & 31;
    const int g = lane >> 5;        // ic-subgroup for fragments

    for (int i = tid; i < 858; i += 1024) {
        ((f16x8*)bt0)[i] = (f16x8){};
        ((f16x8*)bt1)[i] = (f16x8){};
    }
    if (tid < 256) bsh[tid] = bias[tid];

    f32x16 acc[2];
#pragma unroll
    for (int j = 0; j < 2; ++j)
#pragma unroll
        for (int e = 0; e < 16; ++e) acc[j][e] = 0.0f;

    const int scol = lane;          // 0..63
    const int sr   = wv & 3;        // halo row 0..3 -> gy = y0-1+sr
    const int sg   = wv >> 2;       // ic-subgroup 0..3 (4 ic each)
    const int sgy  = y0 - 1 + sr;
    const bool gyok = (sgy >= 0) && (sgy < 64);
    const float* xrow = x + (size_t)n * 1048576 + sgy * 64 + scol;
    const int bto = (sr * 66 + scol + 1) * 26 + sg * 4;

    const int aoffl = (g * 256 + ocg * 32 + bl31) * 8;
    const _Float16* wph = w3h + aoffl;
    const _Float16* wpl = w3l + aoffl;

    float xr[4];
#pragma unroll
    for (int q = 0; q < 4; ++q)
        xr[q] = gyok ? xrow[(size_t)(sg * 4 + q) * 4096] : 0.0f;

    f16x8 AhC = *(const f16x8*)(wph);
    f16x8 AlC = *(const f16x8*)(wpl);

    for (int kb = 0; kb < 16; ++kb) {
        __syncthreads();
        {
            f16x4 hh, hl;
#pragma unroll
            for (int q = 0; q < 4; ++q) {
                float v = xr[q] * 64.0f;           // exact pow2 scale
                _Float16 vh = (_Float16)v;
                hh[q] = vh;
                hl[q] = (_Float16)(v - (float)vh); // fp16-normal residual
            }
            *(f16x4*)&bt0[bto] = hh;
            *(f16x4*)&bt1[bto] = hl;
        }
        __syncthreads();
        if (kb < 15) {
#pragma unroll
            for (int q = 0; q < 4; ++q)
                xr[q] = gyok ? xrow[(size_t)((kb + 1) * 16 + sg * 4 + q) * 4096] : 0.0f;
        }

        const int ent00 = wn * 66 + bl31;
        f16x8 Bh0C = *(const f16x8*)&bt0[ent00 * 26 + g * 8];
        f16x8 Bl0C = *(const f16x8*)&bt1[ent00 * 26 + g * 8];
        f16x8 Bh1C = *(const f16x8*)&bt0[(ent00 + 32) * 26 + g * 8];
        f16x8 Bl1C = *(const f16x8*)&bt1[(ent00 + 32) * 26 + g * 8];

        const int kbn_base = (kb < 15) ? (kb + 1) : 15;
#pragma unroll
        for (int s = 0; s < 9; ++s) {
            const int sn  = (s == 8) ? 0 : (s + 1);
            const int kbn = (s == 8) ? kbn_base : kb;
            const _Float16* phn = wph + (size_t)kbn * 4096 + (size_t)sn * 65536;
            const _Float16* pln = wpl + (size_t)kbn * 4096 + (size_t)sn * 65536;
            f16x8 AhN = *(const f16x8*)(phn);
            f16x8 AlN = *(const f16x8*)(pln);

            f16x8 Bh0N = Bh0C, Bl0N = Bl0C, Bh1N = Bh1C, Bl1N = Bl1C;
            if (s < 8) {
                const int dyn = sn / 3 - 1, dxn = sn % 3 - 1;
                const int entn = (wn + dyn + 1) * 66 + dxn + 1 + bl31;
                const int en0 = entn * 26 + g * 8;
                const int en1 = (entn + 32) * 26 + g * 8;
                Bh0N = *(const f16x8*)&bt0[en0];
                Bl0N = *(const f16x8*)&bt1[en0];
                Bh1N = *(const f16x8*)&bt0[en1];
                Bl1N = *(const f16x8*)&bt1[en1];
            }

            __builtin_amdgcn_s_setprio(1);
            acc[0] = __builtin_amdgcn_mfma_f32_32x32x16_f16(AhC, Bh0C, acc[0], 0, 0, 0);
            acc[1] = __builtin_amdgcn_mfma_f32_32x32x16_f16(AhC, Bh1C, acc[1], 0, 0, 0);
            acc[0] = __builtin_amdgcn_mfma_f32_32x32x16_f16(AhC, Bl0C, acc[0], 0, 0, 0);
            acc[1] = __builtin_amdgcn_mfma_f32_32x32x16_f16(AhC, Bl1C, acc[1], 0, 0, 0);
            acc[0] = __builtin_amdgcn_mfma_f32_32x32x16_f16(AlC, Bh0C, acc[0], 0, 0, 0);
            acc[1] = __builtin_amdgcn_mfma_f32_32x32x16_f16(AlC, Bh1C, acc[1], 0, 0, 0);
            __builtin_amdgcn_s_setprio(0);

            AhC = AhN; AlC = AlN;
            Bh0C = Bh0N; Bl0C = Bl0N; Bh1C = Bh1N; Bl1C = Bl1N;
        }
    }

    const int colw = lane & 31;
    const int rgh = (lane >> 5) * 4;
    float* hn = h + (size_t)n * 1048576 + (size_t)(y0 + wn) * 64;
#pragma unroll
    for (int pcb = 0; pcb < 2; ++pcb)
#pragma unroll
        for (int reg = 0; reg < 16; ++reg) {
            const int row = (reg & 3) + 8 * (reg >> 2) + rgh;
            const int oc = ocg * 32 + row;
            float v = acc[pcb][reg] * 2.44140625e-4f + bsh[oc];   // *2^-12
            hn[(size_t)oc * 4096 + pcb * 32 + colw] = fmaxf(v, 0.0f);
        }
}

// ---------------- 1x1 heads — unchanged (verified) ----------------
__global__ __launch_bounds__(256) void k_heads(const float* __restrict__ h,
                                               const float* __restrict__ loc_w,
                                               const float* __restrict__ score_w,
                                               const float* __restrict__ loc_b,
                                               const float* __restrict__ score_b,
                                               const int* __restrict__ ihp,
                                               const int* __restrict__ iwp,
                                               float* __restrict__ out,
                                               float* __restrict__ boxes,
                                               unsigned int* __restrict__ ubuf) {
    __shared__ float Wl[54 * 64];     // [c][kk]
    __shared__ float outb[128 * 57];  // [p][c] pitch 57
    const int tid = threadIdx.x;
    const int pl = tid & 127, chalf = tid >> 7;
    const int c0 = chalf * 27;
    const int ptile = blockIdx.x;
    const int n = blockIdx.y;
    const int pg = ptile * 128 + pl;

    float acc[27];
#pragma unroll
    for (int i = 0; i < 27; ++i) acc[i] = 0.f;

    for (int kc = 0; kc < 4; ++kc) {
        __syncthreads();
        for (int idx = tid; idx < 54 * 64; idx += 256) {
            int c = idx >> 6, kk = idx & 63;
            int gk = kc * 64 + kk;
            Wl[idx] = (c < 36) ? loc_w[c * 256 + gk] : score_w[(c - 36) * 256 + gk];
        }
        __syncthreads();
        for (int k4 = 0; k4 < 64; k4 += 4) {
            int gk = kc * 64 + k4;
            float hv0 = h[(n * 256 + gk + 0) * 4096 + pg];
            float hv1 = h[(n * 256 + gk + 1) * 4096 + pg];
            float hv2 = h[(n * 256 + gk + 2) * 4096 + pg];
            float hv3 = h[(n * 256 + gk + 3) * 4096 + pg];
#pragma unroll
            for (int ci = 0; ci < 27; ++ci) {
                float4 w4 = *(const float4*)&Wl[(c0 + ci) * 64 + k4];
                acc[ci] += hv0 * w4.x + hv1 * w4.y + hv2 * w4.z + hv3 * w4.w;
            }
        }
    }
#pragma unroll
    for (int ci = 0; ci < 27; ++ci) {
        int c = c0 + ci;
        float bv = (c < 36) ? loc_b[c] : score_b[c - 36];
        outb[pl * 57 + c] = acc[ci] + bv;
    }
    __syncthreads();

    const float fh = (float)(*ihp), fwid = (float)(*iwp);
    for (int slot = tid; slot < 128 * 9; slot += 256) {
        int pli = slot / 9, a = slot - pli * 9;
        int p = ptile * 128 + pli;
        int y = p >> 6, xg = p & 63;
        float l0 = outb[pli * 57 + a * 4 + 0];
        float l1 = outb[pli * 57 + a * 4 + 1];
        float l2 = outb[pli * 57 + a * 4 + 2];
        float l3 = outb[pli * 57 + a * 4 + 3];
        float s0 = outb[pli * 57 + 36 + a * 2 + 0];
        float s1 = outb[pli * 57 + 36 + a * 2 + 1];
        size_t base = (size_t)n * NANCH + (size_t)p * 9 + a;
        ((float4*)(out + OUT_LOC))[base] = make_float4(l0, l1, l2, l3);
        ((float2*)(out + OUT_SCORE))[base] = make_float2(s0, s1);
        float mx = fmaxf(s0, s1);
        float e0 = expf(s0 - mx), e1 = expf(s1 - mx);
        float fg = e1 / (e0 + e1);
        double rr = (a < 3) ? 0.5 : ((a < 6) ? 1.0 : 2.0);
        int sj = a % 3;
        double ssc = (sj == 0) ? 8.0 : ((sj == 1) ? 16.0 : 32.0);
        double hhd = 7.0 * ssc * sqrt(rr);
        double wwd = 7.0 * ssc * sqrt(1.0 / rr);
        float a0 = (float)(3.5 - 0.5 * hhd), a2 = (float)(3.5 + 0.5 * hhd);
        float b0 = (float)(3.5 - 0.5 * wwd), b2 = (float)(3.5 + 0.5 * wwd);
        float ay1 = y * 16.0f + a0, ay2 = y * 16.0f + a2;
        float ax1 = xg * 16.0f + b0, ax2 = xg * 16.0f + b2;
        float ah = ay2 - ay1, aw = ax2 - ax1;
        float acy = ay1 + 0.5f * ah, acx = ax1 + 0.5f * aw;
        float cy = l0 * ah + acy, cx = l1 * aw + acx;
        float bh = expf(l2) * ah, bw = expf(l3) * aw;
        float y1 = fminf(fmaxf(cy - 0.5f * bh, 0.f), fh);
        float x1 = fminf(fmaxf(cx - 0.5f * bw, 0.f), fwid);
        float y2 = fminf(fmaxf(cy + 0.5f * bh, 0.f), fh);
        float x2 = fminf(fmaxf(cx + 0.5f * bw, 0.f), fwid);
        ((float4*)boxes)[base] = make_float4(y1, x1, y2, x2);
        bool valid = ((y2 - y1) >= 16.0f) && ((x2 - x1) >= 16.0f);
        float sc = valid ? fg : -__builtin_inff();
        unsigned int ub = __float_as_uint(sc);
        ub = (ub & 0x80000000u) ? ~ub : (ub | 0x80000000u);
        ubuf[base] = ub;
    }
}

// ---------------- exact top-6000 per batch: byte-radix select + compact ----------------
// R9: (1) pass-0 wave-aggregated histogram (scores concentrate in ~2-3 top-byte buckets ->
// per-lane LDS atomics serialized ~36864x; aggregate to one atomic per distinct byte per wave).
// (2) parallel suffix-sum bucket selection replacing the serial 256-iter scan.
// (3) wave-aggregated compaction (one lcnt atomic per wave). Selected key SET identical;
// ckeys order differs but k_sort totally orders unique keys -> downstream bit-identical.
__global__ __launch_bounds__(1024) void k_select(const unsigned int* __restrict__ ubuf,
                                                 unsigned long long* __restrict__ ckeys,
                                                 unsigned int* __restrict__ cc) {
    __shared__ unsigned int hist[256];
    __shared__ unsigned int selb;
    __shared__ int rank_s;
    __shared__ unsigned int lcnt;
    const int tid = threadIdx.x;
    const int lane = tid & 63;
    const int b = blockIdx.x;
    const unsigned int* ub = ubuf + (size_t)b * NANCH;
    if (tid == 0) { rank_s = NPRE - 1; lcnt = 0; }
    unsigned int prefix = 0;
    // NANCH = 36*1024 exactly -> every thread does 36 iterations (wave-uniform; ballots safe)
    for (int pass = 0; pass < 4; ++pass) {
        int shift = 24 - 8 * pass;
        if (tid < 256) hist[tid] = 0;
        __syncthreads();
        for (int i = tid; i < NANCH; i += 1024) {
            unsigned int u = ub[i];
            bool ok = (pass == 0) || ((u >> (shift + 8)) == (prefix >> (shift + 8)));
            unsigned int byt = (u >> shift) & 255u;
            if (pass == 0) {
                unsigned long long todo = __ballot(ok);
                while (todo) {
                    int src = __builtin_ctzll(todo);
                    unsigned int bb = __shfl(byt, src, 64);
                    unsigned long long m = __ballot(ok && (byt == bb));
                    if (lane == src) atomicAdd(&hist[bb], (unsigned int)__popcll(m));
                    todo &= ~m;
                }
            } else {
                if (ok) atomicAdd(&hist[byt], 1u);
            }
        }
        __syncthreads();
        const int r = rank_s;
        // in-place suffix sum: hist[t] = sum_{j>=t} count
        for (int off = 1; off < 256; off <<= 1) {
            unsigned int v = 0;
            if (tid < 256 && tid + off < 256) v = hist[tid + off];
            __syncthreads();
            if (tid < 256) hist[tid] += v;
            __syncthreads();
        }
        // selected bucket = max{bb : suffix(bb) > r}; rank_s = r - suffix(bb+1)
        if (tid < 256) {
            unsigned int inc = hist[tid];
            unsigned int above = (tid == 255) ? 0u : hist[tid + 1];
            if ((int)inc > r && (int)above <= r) {
                selb = (unsigned int)tid;
                rank_s = r - (int)above;
            }
        }
        __syncthreads();
        prefix |= (selb << shift);
        __syncthreads();
    }
    const unsigned int ustar = prefix;
    for (int i = tid; i < NANCH; i += 1024) {
        unsigned int u = ub[i];
        bool sel2 = (u >= ustar);
        unsigned long long m = __ballot(sel2);
        if (m) {
            int src = __builtin_ctzll(m);
            unsigned int base2 = 0;
            if (lane == src) base2 = atomicAdd(&lcnt, (unsigned int)__popcll(m));
            base2 = __shfl(base2, src, 64);
            if (sel2) {
                unsigned int pos = base2 + (unsigned int)__popcll(m & ((1ull << lane) - 1ull));
                if (pos < 8192)
                    ckeys[(size_t)b * 8192 + pos] =
                        ((unsigned long long)u << 32) | (unsigned int)(0xFFFFFFFFu - (unsigned int)i);
            }
        }
    }
    __syncthreads();
    if (tid == 0) cc[b] = (lcnt > 8192u) ? 8192u : lcnt;
}

// ---------------- bitonic sort 8192: in-register (8 keys/thread) + shuffle + minimal LDS ----------------
__device__ __forceinline__ void cswap_u64(unsigned long long& a, unsigned long long& c, bool desc) {
    bool sw = desc ? (a < c) : (a > c);
    unsigned long long t0 = sw ? c : a;
    unsigned long long t1 = sw ? a : c;
    a = t0; c = t1;
}
__device__ __forceinline__ void net8(unsigned long long v[8], bool d) {
    cswap_u64(v[0], v[4], d); cswap_u64(v[1], v[5], d); cswap_u64(v[2], v[6], d); cswap_u64(v[3], v[7], d);
    cswap_u64(v[0], v[2], d); cswap_u64(v[1], v[3], d); cswap_u64(v[4], v[6], d); cswap_u64(v[5], v[7], d);
    cswap_u64(v[0], v[1], d); cswap_u64(v[2], v[3], d); cswap_u64(v[4], v[5], d); cswap_u64(v[6], v[7], d);
}
__device__ __forceinline__ unsigned long long shfl_xor_u64(unsigned long long x, int lmask) {
    unsigned int lo = (unsigned int)x, hi = (unsigned int)(x >> 32);
    lo = __shfl_xor(lo, lmask, 64);
    hi = __shfl_xor(hi, lmask, 64);
    return ((unsigned long long)hi << 32) | lo;
}
__global__ __launch_bounds__(1024) void k_sort(const unsigned long long* __restrict__ ckeys,
                                               const unsigned int* __restrict__ cc,
                                               const float* __restrict__ boxes,
                                               float* __restrict__ bk) {
    __shared__ unsigned long long S[8192];
    const int tid = threadIdx.x;
    const int b = blockIdx.x;
    const int cnt = (int)cc[b];
    const int base = tid * 8;

    unsigned long long v[8];
#pragma unroll
    for (int e = 0; e < 8; ++e) {
        int i = base + e;
        v[e] = (i < cnt) ? ckeys[(size_t)b * 8192 + i] : 0ull;
    }

    cswap_u64(v[0], v[1], true);  cswap_u64(v[2], v[3], false);
    cswap_u64(v[4], v[5], true);  cswap_u64(v[6], v[7], false);
    cswap_u64(v[0], v[2], true);  cswap_u64(v[1], v[3], true);
    cswap_u64(v[4], v[6], false); cswap_u64(v[5], v[7], false);
    cswap_u64(v[0], v[1], true);  cswap_u64(v[2], v[3], true);
    cswap_u64(v[4], v[5], false); cswap_u64(v[6], v[7], false);
    net8(v, (tid & 1) == 0);

    for (int k = 16; k <= 8192; k <<= 1) {
        for (int j = k >> 1; j >= 8; j >>= 1) {
            const bool keep_max = (((base & k) == 0) != ((base & j) != 0));
            if (j >= 512) {
                __syncthreads();
#pragma unroll
                for (int e = 0; e < 8; ++e) S[base + e] = v[e];
                __syncthreads();
                const int pb = base ^ j;
#pragma unroll
                for (int e = 0; e < 8; ++e) {
                    unsigned long long p = S[pb + e];
                    v[e] = keep_max ? (v[e] >= p ? v[e] : p) : (v[e] <= p ? v[e] : p);
                }
            } else {
                const int lmask = j >> 3;
#pragma unroll
                for (int e = 0; e < 8; ++e) {
                    unsigned long long p = shfl_xor_u64(v[e], lmask);
                    v[e] = keep_max ? (v[e] >= p ? v[e] : p) : (v[e] <= p ? v[e] : p);
                }
            }
        }
        net8(v, (base & k) == 0);
    }

#pragma unroll
    for (int e = 0; e < 8; ++e) {
        int i = base + e;
        if (i < NPRE) {
            unsigned long long key = v[e];
            unsigned int idx = 0xFFFFFFFFu - (unsigned int)(key & 0xFFFFFFFFull);
            if (idx >= NANCH) idx = NANCH - 1;   // safety
            float4 bx = ((const float4*)boxes)[(size_t)b * NANCH + idx];
            ((float4*)bk)[(size_t)b * NPRE + i] = bx;
        }
    }
}

// ---------------- IoU bitmask, COLUMN-major — division-free bit-exact predicate ----------------
__global__ __launch_bounds__(256) void k_mask(const float* __restrict__ bk,
                                              unsigned long long* __restrict__ MT,
                                              const unsigned int* __restrict__ cc,
                                              int iwbase, int checkdone) {
    const int iw = iwbase + blockIdx.x;
    const int gb = blockIdx.y;
    const int b = blockIdx.z;
    if (checkdone && cc[8 + b] != 0u) return;   // speculation succeeded; rows not needed
    if (iw > 4 * gb + 3) return;
    const int tid = threadIdx.x;
    __shared__ float4 jb[64];
    __shared__ float ja[64];
    if (tid < 64) {
        int j = iw * 64 + tid;
        float4 v = (j < NPRE) ? ((const float4*)bk)[(size_t)b * NPRE + j]
                              : make_float4(0.f, 0.f, 0.f, 0.f);
        jb[tid] = v;
        ja[tid] = (v.z - v.x) * (v.w - v.y);
    }
    __syncthreads();
    const int g = gb * 256 + tid;
    float4 bi = (g < NPRE) ? ((const float4*)bk)[(size_t)b * NPRE + g]
                           : make_float4(0.f, 0.f, 0.f, 0.f);
    float ai = (bi.z - bi.x) * (bi.w - bi.y);
    const double MD = (double)0.7f + 0x1p-25;   // exact rounding midpoint
    unsigned long long word = 0ull;
#pragma unroll 8
    for (int jj = 0; jj < 64; ++jj) {
        float4 bj = jb[jj];
        float aj = ja[jj];
        float ty = fmaxf(bi.x, bj.x), tx = fmaxf(bi.y, bj.y);
        float by = fminf(bi.z, bj.z), bx = fminf(bi.w, bj.w);
        float ihh = fmaxf(by - ty, 0.f), iww = fmaxf(bx - tx, 0.f);
        float inter = ihh * iww;
        float den = ai + aj - inter + 1e-9f;
        if ((double)inter >= MD * (double)den) word |= (1ull << jj);
    }
    if (g < GCOLS)
        MT[((size_t)b * NWORDS + iw) * GCOLS + g] = word;
}

// ---------------- greedy NMS, speculative try over first LOROWS chunks ----------------
__global__ __launch_bounds__(1024) void k_nms_try(const unsigned long long* __restrict__ MT,
                                                  const float* __restrict__ bk,
                                                  float* __restrict__ out,
                                                  unsigned int* __restrict__ cc) {
    const int b = blockIdx.x;
    const int tid = threadIdx.x;
    const int lane = tid & 63;
    __shared__ unsigned long long keptw[NWORDS];
    __shared__ unsigned long long dead[LOROWS];
    __shared__ int sel[NPOST];
    __shared__ int totkept;
    const unsigned long long* mtb = MT + (size_t)b * NWORDS * GCOLS;

    for (int i = tid; i < NWORDS; i += 1024) keptw[i] = 0ull;
    if (tid < LOROWS) dead[tid] = 0ull;
    if (tid == 0) totkept = 0;
    __syncthreads();

    for (int c = 0; c < LOROWS; ++c) {
        if (tid < 64) {   // wave 0: in-chunk greedy closure
            const int g = c * 64 + lane;
            unsigned long long diag = mtb[(size_t)c * GCOLS + g];
            bool deadl = (((dead[c] >> lane) & 1ull) != 0ull) || (g >= NPRE);
            unsigned long long undec = ~__ballot(deadl);
            unsigned long long kc = 0ull;
            while (undec) {
                int i = __builtin_ctzll(undec);
                kc |= (1ull << i);
                unsigned long long supm = __ballot((diag >> i) & 1ull);
                undec &= ~(supm | (1ull << i));
            }
            if (lane == 0) { keptw[c] = kc; totkept += __popcll(kc); }
        }
        __syncthreads();
        if (totkept >= NPOST) break;          // later chunks can't affect the output
        const unsigned long long kc = keptw[c];
        if (kc) {
            for (int g2 = (c + 1) * 64 + tid; g2 < LOROWS * 64; g2 += 1024) {
                unsigned long long w = mtb[(size_t)c * GCOLS + g2] & kc;
                unsigned long long m = __ballot(w != 0ull);
                if (lane == 0 && m) atomicOr(&dead[g2 >> 6], m);
            }
        }
        __syncthreads();
    }

    const int done = (totkept >= NPOST) ? 1 : 0;
    if (tid == 0) cc[8 + b] = (unsigned int)done;
    if (!done) return;                        // fall back to k_mask(hi) + k_nms_full

    if (tid == 0) {
        int pos = 0;
        for (int w = 0; w < NWORDS && pos < NPOST; ++w) {
            unsigned long long kw = keptw[w];
            while (kw && pos < NPOST) {
                int i2 = __builtin_ctzll(kw);
                sel[pos++] = w * 64 + i2;
                kw &= kw - 1;
            }
        }
    }
    __syncthreads();
    for (int s2 = tid; s2 < NPOST; s2 += 1024) {
        int i = sel[s2];
        float4 bx = ((const float4*)bk)[(size_t)b * NPRE + i];
        ((float4*)(out + OUT_ROIS))[b * NPOST + s2] = bx;
        out[OUT_RIDX + b * NPOST + s2] = (float)b;
    }
}

// ---------------- full greedy NMS fallback (runs only when try didn't finish) ----------------
__global__ __launch_bounds__(1024) void k_nms_full(const unsigned long long* __restrict__ MT,
                                                   const float* __restrict__ bk,
                                                   float* __restrict__ out,
                                                   const unsigned int* __restrict__ cc) {
    const int b = blockIdx.x;
    if (cc[8 + b] != 0u) return;              // speculation succeeded
    const int tid = threadIdx.x;
    const int lane = tid & 63;
    __shared__ unsigned long long keptw[NWORDS];
    __shared__ unsigned long long dead[NWORDS];
    __shared__ int sel[NPOST];
    __shared__ int totkept;
    const unsigned long long* mtb = MT + (size_t)b * NWORDS * GCOLS;

    for (int i = tid; i < NWORDS; i += 1024) { dead[i] = 0ull; keptw[i] = 0ull; }
    if (tid == 0) totkept = 0;
    __syncthreads();

    for (int c = 0; c < NWORDS; ++c) {
        if (tid < 64) {   // wave 0: in-chunk greedy closure
            const int g = c * 64 + lane;
            unsigned long long diag = mtb[(size_t)c * GCOLS + g];
            bool deadl = (((dead[c] >> lane) & 1ull) != 0ull) || (g >= NPRE);
            unsigned long long undec = ~__ballot(deadl);
            unsigned long long kc = 0ull;
            while (undec) {
                int i = __builtin_ctzll(undec);
                kc |= (1ull << i);
                unsigned long long supm = __ballot((diag >> i) & 1ull);
                undec &= ~(supm | (1ull << i));
            }
            if (lane == 0) { keptw[c] = kc; totkept += __popcll(kc); }
        }
        __syncthreads();
        if (totkept >= NPOST) break;          // later chunks can't affect the output
        const unsigned long long kc = keptw[c];
        if (kc) {
            for (int g2 = (c + 1) * 64 + tid; g2 < GCOLS; g2 += 1024) {
                unsigned long long w = mtb[(size_t)c * GCOLS + g2] & kc;
                unsigned long long m = __ballot(w != 0ull);
                if (lane == 0 && m) atomicOr(&dead[g2 >> 6], m);
            }
        }
        __syncthreads();
    }

    if (tid == 0) {
        int pos = 0;
        for (int w = 0; w < NWORDS && pos < NPOST; ++w) {
            unsigned long long kw = keptw[w];
            while (kw && pos < NPOST) {
                int i2 = __builtin_ctzll(kw);
                sel[pos++] = w * 64 + i2;
                kw &= kw - 1;
            }
        }
        for (int w = 0; w < NWORDS && pos < NPOST; ++w) {
            int nvalid = NPRE - w * 64; if (nvalid > 64) nvalid = 64;
            unsigned long long vm = (nvalid >= 64) ? ~0ull : ((1ull << nvalid) - 1ull);
            unsigned long long sw = (~keptw[w]) & vm;
            while (sw && pos < NPOST) {
                int i2 = __builtin_ctzll(sw);
                sel[pos++] = w * 64 + i2;
                sw &= sw - 1;
            }
        }
    }
    __syncthreads();
    for (int s2 = tid; s2 < NPOST; s2 += 1024) {
        int i = sel[s2];
        float4 bx = ((const float4*)bk)[(size_t)b * NPRE + i];
        ((float4*)(out + OUT_ROIS))[b * NPOST + s2] = bx;
        out[OUT_RIDX + b * NPOST + s2] = (float)b;
    }
}

// ---------------- launch ----------------
extern "C" void kernel_launch(void* const* d_in, const int* in_sizes, int n_in,
                              void* d_out, int out_size, void* d_ws, size_t ws_size,
                              hipStream_t stream) {
    const float* x = (const float*)d_in[0];
    const float* conv1_w = (const float*)d_in[1];
    const float* conv1_b = (const float*)d_in[2];
    const float* score_w = (const float*)d_in[3];
    const float* score_b = (const float*)d_in[4];
    const float* loc_w = (const float*)d_in[5];
    const float* loc_b = (const float*)d_in[6];
    const int* ihp = (const int*)d_in[7];
    const int* iwp = (const int*)d_in[8];
    float* out = (float*)d_out;
    char* ws = (char*)d_ws;
    float* h = (float*)(ws + H_OFF);
    _Float16* w3h = (_Float16*)(ws + WT_OFF);
    _Float16* w3l = (_Float16*)(ws + WT_OFF + 1179648ul);
    float* boxes = (float*)(ws + BOX_OFF);
    unsigned int* ubuf = (unsigned int*)(ws + U_OFF);
    unsigned long long* ckeys = (unsigned long long*)(ws + CK_OFF);
    unsigned int* cc = (unsigned int*)(ws + CC_OFF);
    float* bk = (float*)(ws + BK_OFF);
    unsigned long long* MT = (unsigned long long*)(ws + M_OFF);

    hipLaunchKernelGGL(k_prep_w, dim3(2304), dim3(256), 0, stream, conv1_w, w3h, w3l);
    hipLaunchKernelGGL(k_anchors, dim3(144), dim3(256), 0, stream, out, cc);
    hipLaunchKernelGGL(k_conv1m, dim3(32, 8), dim3(1024), 0, stream, x, w3h, w3l, conv1_b, h);
    hipLaunchKernelGGL(k_heads, dim3(32, 8), dim3(256), 0, stream,
                       h, loc_w, score_w, loc_b, score_b, ihp, iwp, out, boxes, ubuf);
    hipLaunchKernelGGL(k_select, dim3(8), dim3(1024), 0, stream, ubuf, ckeys, cc);
    hipLaunchKernelGGL(k_sort, dim3(8), dim3(1024), 0, stream, ckeys, cc, boxes, bk);
    // speculative low rows -> NMS try -> (conditional) high rows -> (conditional) full NMS
    hipLaunchKernelGGL(k_mask, dim3(LOROWS, 24, 8), dim3(256), 0, stream, bk, MT, cc, 0, 0);
    hipLaunchKernelGGL(k_nms_try, dim3(8), dim3(1024), 0, stream, MT, bk, out, cc);
    hipLaunchKernelGGL(k_mask, dim3(NWORDS - LOROWS, 24, 8), dim3(256), 0, stream, bk, MT, cc, LOROWS, 1);
    hipLaunchKernelGGL(k_nms_full, dim3(8), dim3(1024), 0, stream, MT, bk, out, cc);
}

// Round 10
// 440.388 us; speedup vs baseline: 1.3579x; 1.1293x over previous
//
#include <hip/hip_runtime.h>
#include <cstdint>
#include <cstddef>

// ---------------- problem constants ----------------
#define NBATCH 8
#define MID 256
#define HIMG 64
#define WIMG 64
#define NA 9
#define NPRE 6000
#define NPOST 300
#define NANCH (HIMG*WIMG*NA)   // 36864
#define NWORDS 94              // ceil(6000/64)
#define GCOLS 6016             // 94*64 padded columns
#define LOROWS 16              // speculative mask rows for the NMS early-break fast path

// output float offsets
#define OUT_LOC   0
#define OUT_SCORE 1179648
#define OUT_ROIS  1769472
#define OUT_RIDX  1779072
#define OUT_ANCH  1781472

// workspace byte offsets
#define H_OFF    0ul
#define H_BYTES  (8ul*256*64*64*4)         // 33554432
#define WT_OFF   (H_OFF + H_BYTES)
#define WT_BYTES (2304ul*256*4)            // 2359296 = exactly w3h+w3l (half)
#define BOX_OFF  (WT_OFF + WT_BYTES)
#define BOX_BYTES (8ul*36864*4*4)          // 4718592
#define U_OFF    (BOX_OFF + BOX_BYTES)
#define U_BYTES  (8ul*36864*4)
#define CK_OFF   (U_OFF + U_BYTES)
#define CK_BYTES (8ul*8192*8)
#define CC_OFF   (CK_OFF + CK_BYTES)
#define CC_BYTES 64ul
#define BK_OFF   (CC_OFF + CC_BYTES)
#define BK_BYTES (8ul*6000*16)
#define M_OFF    (BK_OFF + BK_BYTES + 64)
#define M_BYTES  (8ul*NWORDS*GCOLS*8)      // 36.2 MB, column-major mask

typedef _Float16 f16x8 __attribute__((ext_vector_type(8)));
typedef _Float16 f16x4 __attribute__((ext_vector_type(4)));
typedef float f32x16 __attribute__((ext_vector_type(16)));

// ---------------- weight prep: conv1_w[oc][ic][ky][kx] -> w3{h,l}[s][kb][g][oc][8] fp16 hi/lo ----------
// Whole problem scaled by 64 (exact pow2); residuals fp16-normal; epilogue multiplies by 2^-12.
__global__ __launch_bounds__(256) void k_prep_w(const float* __restrict__ w,
                                                _Float16* __restrict__ w3h,
                                                _Float16* __restrict__ w3l) {
    int idx = blockIdx.x * 256 + threadIdx.x;   // 589824 = 9*16*2*256*8
    if (idx >= 589824) return;
    int e  = idx & 7;
    int t  = idx >> 3;
    int oc = t & 255; t >>= 8;
    int g  = t & 1;   t >>= 1;
    int kb = t & 15;  t >>= 4;
    int s  = t;                               // 0..8
    int ic = kb * 16 + g * 8 + e;
    float v = w[(oc * 256 + ic) * 9 + s] * 64.0f;   // exact pow2 scale
    _Float16 vh = (_Float16)v;
    float r = v - (float)vh;                  // exact in fp32
    w3h[idx] = vh;
    w3l[idx] = (_Float16)r;                   // fp16-normal (64-scale)
}

// ---------------- anchors output (exact double->f32 like numpy) + zero counters ----------------
__global__ void k_anchors(float* __restrict__ out, unsigned int* __restrict__ cc) {
    int idx = blockIdx.x * 256 + threadIdx.x;
    if (blockIdx.x == 0 && threadIdx.x < 16) cc[threadIdx.x] = 0u;
    if (idx >= NANCH) return;
    int p = idx / 9, a = idx - p * 9;
    int y = p >> 6, xg = p & 63;
    double rr = (a < 3) ? 0.5 : ((a < 6) ? 1.0 : 2.0);
    int sj = a % 3;
    double ssc = (sj == 0) ? 8.0 : ((sj == 1) ? 16.0 : 32.0);
    double hh = 7.0 * ssc * sqrt(rr);
    double ww = 7.0 * ssc * sqrt(1.0 / rr);
    float a0 = (float)(3.5 - 0.5 * hh), a2 = (float)(3.5 + 0.5 * hh);
    float b0 = (float)(3.5 - 0.5 * ww), b2 = (float)(3.5 + 0.5 * ww);
    float* dst = out + OUT_ANCH + (size_t)idx * 4;
    dst[0] = y * 16.0f + a0;
    dst[1] = xg * 16.0f + b0;
    dst[2] = y * 16.0f + a2;
    dst[3] = xg * 16.0f + b2;
}

// ---------------- conv1 3x3 + bias + relu via fp16 hi/lo split MFMA (unchanged) ----------------
__global__ __launch_bounds__(1024) void k_conv1m(const float* __restrict__ x,
                                                 const _Float16* __restrict__ w3h,
                                                 const _Float16* __restrict__ w3l,
                                                 const float* __restrict__ bias,
                                                 float* __restrict__ h) {
    __shared__ __align__(16) _Float16 bt0[4 * 66 * 26];   // hi
    __shared__ __align__(16) _Float16 bt1[4 * 66 * 26];   // lo
    __shared__ float bsh[256];

    const int tid = threadIdx.x;
    const int lane = tid & 63;
    const int wv = tid >> 6;        // 0..15
    const int ocg = wv >> 1;        // 0..7 : oc block 32*ocg
    const int wn = wv & 1;          // 0..1 : image row y0+wn
    const int y0 = blockIdx.x * 2;
    const int n  = blockIdx.y;
    const int bl31 = lane & 31;
    const int g = lane >> 5;        // ic-subgroup for fragments

    for (int i = tid; i < 858; i += 1024) {
        ((f16x8*)bt0)[i] = (f16x8){};
        ((f16x8*)bt1)[i] = (f16x8){};
    }
    if (tid < 256) bsh[tid] = bias[tid];

    f32x16 acc[2];
#pragma unroll
    for (int j = 0; j < 2; ++j)
#pragma unroll
        for (int e = 0; e < 16; ++e) acc[j][e] = 0.0f;

    const int scol = lane;          // 0..63
    const int sr   = wv & 3;        // halo row 0..3 -> gy = y0-1+sr
    const int sg   = wv >> 2;       // ic-subgroup 0..3 (4 ic each)
    const int sgy  = y0 - 1 + sr;
    const bool gyok = (sgy >= 0) && (sgy < 64);
    const float* xrow = x + (size_t)n * 1048576 + sgy * 64 + scol;
    const int bto = (sr * 66 + scol + 1) * 26 + sg * 4;

    const int aoffl = (g * 256 + ocg * 32 + bl31) * 8;
    const _Float16* wph = w3h + aoffl;
    const _Float16* wpl = w3l + aoffl;

    float xr[4];
#pragma unroll
    for (int q = 0; q < 4; ++q)
        xr[q] = gyok ? xrow[(size_t)(sg * 4 + q) * 4096] : 0.0f;

    f16x8 AhC = *(const f16x8*)(wph);
    f16x8 AlC = *(const f16x8*)(wpl);

    for (int kb = 0; kb < 16; ++kb) {
        __syncthreads();
        {
            f16x4 hh, hl;
#pragma unroll
            for (int q = 0; q < 4; ++q) {
                float v = xr[q] * 64.0f;           // exact pow2 scale
                _Float16 vh = (_Float16)v;
                hh[q] = vh;
                hl[q] = (_Float16)(v - (float)vh); // fp16-normal residual
            }
            *(f16x4*)&bt0[bto] = hh;
            *(f16x4*)&bt1[bto] = hl;
        }
        __syncthreads();
        if (kb < 15) {
#pragma unroll
            for (int q = 0; q < 4; ++q)
                xr[q] = gyok ? xrow[(size_t)((kb + 1) * 16 + sg * 4 + q) * 4096] : 0.0f;
        }

        const int ent00 = wn * 66 + bl31;
        f16x8 Bh0C = *(const f16x8*)&bt0[ent00 * 26 + g * 8];
        f16x8 Bl0C = *(const f16x8*)&bt1[ent00 * 26 + g * 8];
        f16x8 Bh1C = *(const f16x8*)&bt0[(ent00 + 32) * 26 + g * 8];
        f16x8 Bl1C = *(const f16x8*)&bt1[(ent00 + 32) * 26 + g * 8];

        const int kbn_base = (kb < 15) ? (kb + 1) : 15;
#pragma unroll
        for (int s = 0; s < 9; ++s) {
            const int sn  = (s == 8) ? 0 : (s + 1);
            const int kbn = (s == 8) ? kbn_base : kb;
            const _Float16* phn = wph + (size_t)kbn * 4096 + (size_t)sn * 65536;
            const _Float16* pln = wpl + (size_t)kbn * 4096 + (size_t)sn * 65536;
            f16x8 AhN = *(const f16x8*)(phn);
            f16x8 AlN = *(const f16x8*)(pln);

            f16x8 Bh0N = Bh0C, Bl0N = Bl0C, Bh1N = Bh1C, Bl1N = Bl1C;
            if (s < 8) {
                const int dyn = sn / 3 - 1, dxn = sn % 3 - 1;
                const int entn = (wn + dyn + 1) * 66 + dxn + 1 + bl31;
                const int en0 = entn * 26 + g * 8;
                const int en1 = (entn + 32) * 26 + g * 8;
                Bh0N = *(const f16x8*)&bt0[en0];
                Bl0N = *(const f16x8*)&bt1[en0];
                Bh1N = *(const f16x8*)&bt0[en1];
                Bl1N = *(const f16x8*)&bt1[en1];
            }

            __builtin_amdgcn_s_setprio(1);
            acc[0] = __builtin_amdgcn_mfma_f32_32x32x16_f16(AhC, Bh0C, acc[0], 0, 0, 0);
            acc[1] = __builtin_amdgcn_mfma_f32_32x32x16_f16(AhC, Bh1C, acc[1], 0, 0, 0);
            acc[0] = __builtin_amdgcn_mfma_f32_32x32x16_f16(AhC, Bl0C, acc[0], 0, 0, 0);
            acc[1] = __builtin_amdgcn_mfma_f32_32x32x16_f16(AhC, Bl1C, acc[1], 0, 0, 0);
            acc[0] = __builtin_amdgcn_mfma_f32_32x32x16_f16(AlC, Bh0C, acc[0], 0, 0, 0);
            acc[1] = __builtin_amdgcn_mfma_f32_32x32x16_f16(AlC, Bh1C, acc[1], 0, 0, 0);
            __builtin_amdgcn_s_setprio(0);

            AhC = AhN; AlC = AlN;
            Bh0C = Bh0N; Bl0C = Bl0N; Bh1C = Bh1N; Bl1C = Bl1N;
        }
    }

    const int colw = lane & 31;
    const int rgh = (lane >> 5) * 4;
    float* hn = h + (size_t)n * 1048576 + (size_t)(y0 + wn) * 64;
#pragma unroll
    for (int pcb = 0; pcb < 2; ++pcb)
#pragma unroll
        for (int reg = 0; reg < 16; ++reg) {
            const int row = (reg & 3) + 8 * (reg >> 2) + rgh;
            const int oc = ocg * 32 + row;
            float v = acc[pcb][reg] * 2.44140625e-4f + bsh[oc];   // *2^-12
            hn[(size_t)oc * 4096 + pcb * 32 + colw] = fmaxf(v, 0.0f);
        }
}

// ---------------- 1x1 heads — unchanged (verified) ----------------
__global__ __launch_bounds__(256) void k_heads(const float* __restrict__ h,
                                               const float* __restrict__ loc_w,
                                               const float* __restrict__ score_w,
                                               const float* __restrict__ loc_b,
                                               const float* __restrict__ score_b,
                                               const int* __restrict__ ihp,
                                               const int* __restrict__ iwp,
                                               float* __restrict__ out,
                                               float* __restrict__ boxes,
                                               unsigned int* __restrict__ ubuf) {
    __shared__ float Wl[54 * 64];     // [c][kk]
    __shared__ float outb[128 * 57];  // [p][c] pitch 57
    const int tid = threadIdx.x;
    const int pl = tid & 127, chalf = tid >> 7;
    const int c0 = chalf * 27;
    const int ptile = blockIdx.x;
    const int n = blockIdx.y;
    const int pg = ptile * 128 + pl;

    float acc[27];
#pragma unroll
    for (int i = 0; i < 27; ++i) acc[i] = 0.f;

    for (int kc = 0; kc < 4; ++kc) {
        __syncthreads();
        for (int idx = tid; idx < 54 * 64; idx += 256) {
            int c = idx >> 6, kk = idx & 63;
            int gk = kc * 64 + kk;
            Wl[idx] = (c < 36) ? loc_w[c * 256 + gk] : score_w[(c - 36) * 256 + gk];
        }
        __syncthreads();
        for (int k4 = 0; k4 < 64; k4 += 4) {
            int gk = kc * 64 + k4;
            float hv0 = h[(n * 256 + gk + 0) * 4096 + pg];
            float hv1 = h[(n * 256 + gk + 1) * 4096 + pg];
            float hv2 = h[(n * 256 + gk + 2) * 4096 + pg];
            float hv3 = h[(n * 256 + gk + 3) * 4096 + pg];
#pragma unroll
            for (int ci = 0; ci < 27; ++ci) {
                float4 w4 = *(const float4*)&Wl[(c0 + ci) * 64 + k4];
                acc[ci] += hv0 * w4.x + hv1 * w4.y + hv2 * w4.z + hv3 * w4.w;
            }
        }
    }
#pragma unroll
    for (int ci = 0; ci < 27; ++ci) {
        int c = c0 + ci;
        float bv = (c < 36) ? loc_b[c] : score_b[c - 36];
        outb[pl * 57 + c] = acc[ci] + bv;
    }
    __syncthreads();

    const float fh = (float)(*ihp), fwid = (float)(*iwp);
    for (int slot = tid; slot < 128 * 9; slot += 256) {
        int pli = slot / 9, a = slot - pli * 9;
        int p = ptile * 128 + pli;
        int y = p >> 6, xg = p & 63;
        float l0 = outb[pli * 57 + a * 4 + 0];
        float l1 = outb[pli * 57 + a * 4 + 1];
        float l2 = outb[pli * 57 + a * 4 + 2];
        float l3 = outb[pli * 57 + a * 4 + 3];
        float s0 = outb[pli * 57 + 36 + a * 2 + 0];
        float s1 = outb[pli * 57 + 36 + a * 2 + 1];
        size_t base = (size_t)n * NANCH + (size_t)p * 9 + a;
        ((float4*)(out + OUT_LOC))[base] = make_float4(l0, l1, l2, l3);
        ((float2*)(out + OUT_SCORE))[base] = make_float2(s0, s1);
        float mx = fmaxf(s0, s1);
        float e0 = expf(s0 - mx), e1 = expf(s1 - mx);
        float fg = e1 / (e0 + e1);
        double rr = (a < 3) ? 0.5 : ((a < 6) ? 1.0 : 2.0);
        int sj = a % 3;
        double ssc = (sj == 0) ? 8.0 : ((sj == 1) ? 16.0 : 32.0);
        double hhd = 7.0 * ssc * sqrt(rr);
        double wwd = 7.0 * ssc * sqrt(1.0 / rr);
        float a0 = (float)(3.5 - 0.5 * hhd), a2 = (float)(3.5 + 0.5 * hhd);
        float b0 = (float)(3.5 - 0.5 * wwd), b2 = (float)(3.5 + 0.5 * wwd);
        float ay1 = y * 16.0f + a0, ay2 = y * 16.0f + a2;
        float ax1 = xg * 16.0f + b0, ax2 = xg * 16.0f + b2;
        float ah = ay2 - ay1, aw = ax2 - ax1;
        float acy = ay1 + 0.5f * ah, acx = ax1 + 0.5f * aw;
        float cy = l0 * ah + acy, cx = l1 * aw + acx;
        float bh = expf(l2) * ah, bw = expf(l3) * aw;
        float y1 = fminf(fmaxf(cy - 0.5f * bh, 0.f), fh);
        float x1 = fminf(fmaxf(cx - 0.5f * bw, 0.f), fwid);
        float y2 = fminf(fmaxf(cy + 0.5f * bh, 0.f), fh);
        float x2 = fminf(fmaxf(cx + 0.5f * bw, 0.f), fwid);
        ((float4*)boxes)[base] = make_float4(y1, x1, y2, x2);
        bool valid = ((y2 - y1) >= 16.0f) && ((x2 - x1) >= 16.0f);
        float sc = valid ? fg : -__builtin_inff();
        unsigned int ub = __float_as_uint(sc);
        ub = (ub & 0x80000000u) ? ~ub : (ub | 0x80000000u);
        ubuf[base] = ub;
    }
}

// ---------------- exact top-6000 per batch: wave-aggregated radix select (unchanged from R9) ----------------
__global__ __launch_bounds__(1024) void k_select(const unsigned int* __restrict__ ubuf,
                                                 unsigned long long* __restrict__ ckeys,
                                                 unsigned int* __restrict__ cc) {
    __shared__ unsigned int hist[256];
    __shared__ unsigned int selb;
    __shared__ int rank_s;
    __shared__ unsigned int lcnt;
    const int tid = threadIdx.x;
    const int lane = tid & 63;
    const int b = blockIdx.x;
    const unsigned int* ub = ubuf + (size_t)b * NANCH;
    if (tid == 0) { rank_s = NPRE - 1; lcnt = 0; }
    unsigned int prefix = 0;
    for (int pass = 0; pass < 4; ++pass) {
        int shift = 24 - 8 * pass;
        if (tid < 256) hist[tid] = 0;
        __syncthreads();
        for (int i = tid; i < NANCH; i += 1024) {
            unsigned int u = ub[i];
            bool ok = (pass == 0) || ((u >> (shift + 8)) == (prefix >> (shift + 8)));
            unsigned int byt = (u >> shift) & 255u;
            if (pass == 0) {
                unsigned long long todo = __ballot(ok);
                while (todo) {
                    int src = __builtin_ctzll(todo);
                    unsigned int bb = __shfl(byt, src, 64);
                    unsigned long long m = __ballot(ok && (byt == bb));
                    if (lane == src) atomicAdd(&hist[bb], (unsigned int)__popcll(m));
                    todo &= ~m;
                }
            } else {
                if (ok) atomicAdd(&hist[byt], 1u);
            }
        }
        __syncthreads();
        const int r = rank_s;
        for (int off = 1; off < 256; off <<= 1) {
            unsigned int v = 0;
            if (tid < 256 && tid + off < 256) v = hist[tid + off];
            __syncthreads();
            if (tid < 256) hist[tid] += v;
            __syncthreads();
        }
        if (tid < 256) {
            unsigned int inc = hist[tid];
            unsigned int above = (tid == 255) ? 0u : hist[tid + 1];
            if ((int)inc > r && (int)above <= r) {
                selb = (unsigned int)tid;
                rank_s = r - (int)above;
            }
        }
        __syncthreads();
        prefix |= (selb << shift);
        __syncthreads();
    }
    const unsigned int ustar = prefix;
    for (int i = tid; i < NANCH; i += 1024) {
        unsigned int u = ub[i];
        bool sel2 = (u >= ustar);
        unsigned long long m = __ballot(sel2);
        if (m) {
            int src = __builtin_ctzll(m);
            unsigned int base2 = 0;
            if (lane == src) base2 = atomicAdd(&lcnt, (unsigned int)__popcll(m));
            base2 = __shfl(base2, src, 64);
            if (sel2) {
                unsigned int pos = base2 + (unsigned int)__popcll(m & ((1ull << lane) - 1ull));
                if (pos < 8192)
                    ckeys[(size_t)b * 8192 + pos] =
                        ((unsigned long long)u << 32) | (unsigned int)(0xFFFFFFFFu - (unsigned int)i);
            }
        }
    }
    __syncthreads();
    if (tid == 0) cc[b] = (lcnt > 8192u) ? 8192u : lcnt;
}

// ---------------- bitonic sort 8192 — segment-decomposed (R10): 4 blocks/batch ----------------
// Same compare-exchange network as the single-block version (direction bits use GLOBAL index)
// -> bit-identical result. Stages j<=1024 are intra-2048-segment (32 blocks, 4x CUs);
// only k=4096:j=2048 and k=8192:j=4096,2048 are cross-segment (3 tiny global kernels).
__device__ __forceinline__ void cswap_u64(unsigned long long& a, unsigned long long& c, bool desc) {
    bool sw = desc ? (a < c) : (a > c);
    unsigned long long t0 = sw ? c : a;
    unsigned long long t1 = sw ? a : c;
    a = t0; c = t1;
}
__device__ __forceinline__ void net8(unsigned long long v[8], bool d) {
    cswap_u64(v[0], v[4], d); cswap_u64(v[1], v[5], d); cswap_u64(v[2], v[6], d); cswap_u64(v[3], v[7], d);
    cswap_u64(v[0], v[2], d); cswap_u64(v[1], v[3], d); cswap_u64(v[4], v[6], d); cswap_u64(v[5], v[7], d);
    cswap_u64(v[0], v[1], d); cswap_u64(v[2], v[3], d); cswap_u64(v[4], v[5], d); cswap_u64(v[6], v[7], d);
}
__device__ __forceinline__ unsigned long long shfl_xor_u64(unsigned long long x, int lmask) {
    unsigned int lo = (unsigned int)x, hi = (unsigned int)(x >> 32);
    lo = __shfl_xor(lo, lmask, 64);
    hi = __shfl_xor(hi, lmask, 64);
    return ((unsigned long long)hi << 32) | lo;
}

// local sort of one 2048-key segment through k=2048 (in-place in ckeys)
__global__ __launch_bounds__(256) void k_sort_loc(unsigned long long* __restrict__ ckeys,
                                                  const unsigned int* __restrict__ cc) {
    __shared__ unsigned long long S[2048];
    const int tid = threadIdx.x;
    const int seg = blockIdx.x;        // 0..3
    const int b = blockIdx.y;
    const int cnt = (int)cc[b];
    const int gbase = seg * 2048 + tid * 8;
    const int lb = tid * 8;
    unsigned long long* ck = ckeys + (size_t)b * 8192;

    unsigned long long v[8];
#pragma unroll
    for (int e = 0; e < 8; ++e) {
        int i = gbase + e;
        v[e] = (i < cnt) ? ck[i] : 0ull;
    }
    // k=2, k=4 (patterns depend only on low 3 bits of index; gbase % 8 == 0)
    cswap_u64(v[0], v[1], true);  cswap_u64(v[2], v[3], false);
    cswap_u64(v[4], v[5], true);  cswap_u64(v[6], v[7], false);
    cswap_u64(v[0], v[2], true);  cswap_u64(v[1], v[3], true);
    cswap_u64(v[4], v[6], false); cswap_u64(v[5], v[7], false);
    cswap_u64(v[0], v[1], true);  cswap_u64(v[2], v[3], true);
    cswap_u64(v[4], v[5], false); cswap_u64(v[6], v[7], false);
    net8(v, (gbase & 8) == 0);

    for (int k = 16; k <= 2048; k <<= 1) {
        for (int j = k >> 1; j >= 8; j >>= 1) {
            const bool keep_max = (((gbase & k) == 0) != ((gbase & j) != 0));
            if (j >= 512) {
                __syncthreads();
#pragma unroll
                for (int e = 0; e < 8; ++e) S[lb + e] = v[e];
                __syncthreads();
                const int pb = lb ^ j;
#pragma unroll
                for (int e = 0; e < 8; ++e) {
                    unsigned long long p = S[pb + e];
                    v[e] = keep_max ? (v[e] >= p ? v[e] : p) : (v[e] <= p ? v[e] : p);
                }
            } else {
                const int lmask = j >> 3;
#pragma unroll
                for (int e = 0; e < 8; ++e) {
                    unsigned long long p = shfl_xor_u64(v[e], lmask);
                    v[e] = keep_max ? (v[e] >= p ? v[e] : p) : (v[e] <= p ? v[e] : p);
                }
            }
        }
        net8(v, (gbase & k) == 0);
    }
#pragma unroll
    for (int e = 0; e < 8; ++e) ck[gbase + e] = v[e];
}

// one cross-segment compare-exchange stage (j in {2048,4096}) over global memory
__global__ __launch_bounds__(256) void k_sort_gmerge(unsigned long long* __restrict__ ckeys,
                                                     int j, int k) {
    const int t = blockIdx.x * 256 + threadIdx.x;   // pair index 0..4095
    const int b = blockIdx.y;
    const int i = ((t & ~(j - 1)) << 1) | (t & (j - 1));
    const int l = i | j;
    unsigned long long* ck = ckeys + (size_t)b * 8192;
    unsigned long long a = ck[i], c = ck[l];
    const bool desc = ((i & k) == 0);
    bool sw = desc ? (a < c) : (a > c);
    if (sw) { ck[i] = c; ck[l] = a; }
}

// finish j<=1024 stages of merge level k within each segment; optionally gather boxes
__global__ __launch_bounds__(256) void k_sort_tail(unsigned long long* __restrict__ ckeys,
                                                   int k,
                                                   const float* __restrict__ boxes,
                                                   float* __restrict__ bk,
                                                   int dogather) {
    __shared__ unsigned long long S[2048];
    const int tid = threadIdx.x;
    const int seg = blockIdx.x;
    const int b = blockIdx.y;
    const int gbase = seg * 2048 + tid * 8;
    const int lb = tid * 8;
    unsigned long long* ck = ckeys + (size_t)b * 8192;

    unsigned long long v[8];
#pragma unroll
    for (int e = 0; e < 8; ++e) v[e] = ck[gbase + e];

    for (int j = 1024; j >= 8; j >>= 1) {
        const bool keep_max = (((gbase & k) == 0) != ((gbase & j) != 0));
        if (j >= 512) {
            __syncthreads();
#pragma unroll
            for (int e = 0; e < 8; ++e) S[lb + e] = v[e];
            __syncthreads();
            const int pb = lb ^ j;
#pragma unroll
            for (int e = 0; e < 8; ++e) {
                unsigned long long p = S[pb + e];
                v[e] = keep_max ? (v[e] >= p ? v[e] : p) : (v[e] <= p ? v[e] : p);
            }
        } else {
            const int lmask = j >> 3;
#pragma unroll
            for (int e = 0; e < 8; ++e) {
                unsigned long long p = shfl_xor_u64(v[e], lmask);
                v[e] = keep_max ? (v[e] >= p ? v[e] : p) : (v[e] <= p ? v[e] : p);
            }
        }
    }
    net8(v, (gbase & k) == 0);

    if (!dogather) {
#pragma unroll
        for (int e = 0; e < 8; ++e) ck[gbase + e] = v[e];
    } else {
#pragma unroll
        for (int e = 0; e < 8; ++e) {
            int i = gbase + e;
            if (i < NPRE) {
                unsigned int idx = 0xFFFFFFFFu - (unsigned int)(v[e] & 0xFFFFFFFFull);
                if (idx >= NANCH) idx = NANCH - 1;   // safety
                float4 bx = ((const float4*)boxes)[(size_t)b * NANCH + idx];
                ((float4*)bk)[(size_t)b * NPRE + i] = bx;
            }
        }
    }
}

// ---------------- IoU bitmask, COLUMN-major — division-free bit-exact predicate ----------------
__global__ __launch_bounds__(256) void k_mask(const float* __restrict__ bk,
                                              unsigned long long* __restrict__ MT,
                                              const unsigned int* __restrict__ cc,
                                              int iwbase, int checkdone) {
    const int iw = iwbase + blockIdx.x;
    const int gb = blockIdx.y;
    const int b = blockIdx.z;
    if (checkdone && cc[8 + b] != 0u) return;   // speculation succeeded; rows not needed
    if (iw > 4 * gb + 3) return;
    const int tid = threadIdx.x;
    __shared__ float4 jb[64];
    __shared__ float ja[64];
    if (tid < 64) {
        int j = iw * 64 + tid;
        float4 v = (j < NPRE) ? ((const float4*)bk)[(size_t)b * NPRE + j]
                              : make_float4(0.f, 0.f, 0.f, 0.f);
        jb[tid] = v;
        ja[tid] = (v.z - v.x) * (v.w - v.y);
    }
    __syncthreads();
    const int g = gb * 256 + tid;
    float4 bi = (g < NPRE) ? ((const float4*)bk)[(size_t)b * NPRE + g]
                           : make_float4(0.f, 0.f, 0.f, 0.f);
    float ai = (bi.z - bi.x) * (bi.w - bi.y);
    const double MD = (double)0.7f + 0x1p-25;   // exact rounding midpoint
    unsigned long long word = 0ull;
#pragma unroll 8
    for (int jj = 0; jj < 64; ++jj) {
        float4 bj = jb[jj];
        float aj = ja[jj];
        float ty = fmaxf(bi.x, bj.x), tx = fmaxf(bi.y, bj.y);
        float by = fminf(bi.z, bj.z), bx = fminf(bi.w, bj.w);
        float ihh = fmaxf(by - ty, 0.f), iww = fmaxf(bx - tx, 0.f);
        float inter = ihh * iww;
        float den = ai + aj - inter + 1e-9f;
        if ((double)inter >= MD * (double)den) word |= (1ull << jj);
    }
    if (g < GCOLS)
        MT[((size_t)b * NWORDS + iw) * GCOLS + g] = word;
}

// ---------------- greedy NMS, speculative try over first LOROWS chunks ----------------
__global__ __launch_bounds__(1024) void k_nms_try(const unsigned long long* __restrict__ MT,
                                                  const float* __restrict__ bk,
                                                  float* __restrict__ out,
                                                  unsigned int* __restrict__ cc) {
    const int b = blockIdx.x;
    const int tid = threadIdx.x;
    const int lane = tid & 63;
    __shared__ unsigned long long keptw[NWORDS];
    __shared__ unsigned long long dead[LOROWS];
    __shared__ int sel[NPOST];
    __shared__ int totkept;
    const unsigned long long* mtb = MT + (size_t)b * NWORDS * GCOLS;

    for (int i = tid; i < NWORDS; i += 1024) keptw[i] = 0ull;
    if (tid < LOROWS) dead[tid] = 0ull;
    if (tid == 0) totkept = 0;
    __syncthreads();

    for (int c = 0; c < LOROWS; ++c) {
        if (tid < 64) {   // wave 0: in-chunk greedy closure
            const int g = c * 64 + lane;
            unsigned long long diag = mtb[(size_t)c * GCOLS + g];
            bool deadl = (((dead[c] >> lane) & 1ull) != 0ull) || (g >= NPRE);
            unsigned long long undec = ~__ballot(deadl);
            unsigned long long kc = 0ull;
            while (undec) {
                int i = __builtin_ctzll(undec);
                kc |= (1ull << i);
                unsigned long long supm = __ballot((diag >> i) & 1ull);
                undec &= ~(supm | (1ull << i));
            }
            if (lane == 0) { keptw[c] = kc; totkept += __popcll(kc); }
        }
        __syncthreads();
        if (totkept >= NPOST) break;          // later chunks can't affect the output
        const unsigned long long kc = keptw[c];
        if (kc) {
            for (int g2 = (c + 1) * 64 + tid; g2 < LOROWS * 64; g2 += 1024) {
                unsigned long long w = mtb[(size_t)c * GCOLS + g2] & kc;
                unsigned long long m = __ballot(w != 0ull);
                if (lane == 0 && m) atomicOr(&dead[g2 >> 6], m);
            }
        }
        __syncthreads();
    }

    const int done = (totkept >= NPOST) ? 1 : 0;
    if (tid == 0) cc[8 + b] = (unsigned int)done;
    if (!done) return;                        // fall back to k_mask(hi) + k_nms_full

    if (tid == 0) {
        int pos = 0;
        for (int w = 0; w < NWORDS && pos < NPOST; ++w) {
            unsigned long long kw = keptw[w];
            while (kw && pos < NPOST) {
                int i2 = __builtin_ctzll(kw);
                sel[pos++] = w * 64 + i2;
                kw &= kw - 1;
            }
        }
    }
    __syncthreads();
    for (int s2 = tid; s2 < NPOST; s2 += 1024) {
        int i = sel[s2];
        float4 bx = ((const float4*)bk)[(size_t)b * NPRE + i];
        ((float4*)(out + OUT_ROIS))[b * NPOST + s2] = bx;
        out[OUT_RIDX + b * NPOST + s2] = (float)b;
    }
}

// ---------------- full greedy NMS fallback (runs only when try didn't finish) ----------------
__global__ __launch_bounds__(1024) void k_nms_full(const unsigned long long* __restrict__ MT,
                                                   const float* __restrict__ bk,
                                                   float* __restrict__ out,
                                                   const unsigned int* __restrict__ cc) {
    const int b = blockIdx.x;
    if (cc[8 + b] != 0u) return;              // speculation succeeded
    const int tid = threadIdx.x;
    const int lane = tid & 63;
    __shared__ unsigned long long keptw[NWORDS];
    __shared__ unsigned long long dead[NWORDS];
    __shared__ int sel[NPOST];
    __shared__ int totkept;
    const unsigned long long* mtb = MT + (size_t)b * NWORDS * GCOLS;

    for (int i = tid; i < NWORDS; i += 1024) { dead[i] = 0ull; keptw[i] = 0ull; }
    if (tid == 0) totkept = 0;
    __syncthreads();

    for (int c = 0; c < NWORDS; ++c) {
        if (tid < 64) {   // wave 0: in-chunk greedy closure
            const int g = c * 64 + lane;
            unsigned long long diag = mtb[(size_t)c * GCOLS + g];
            bool deadl = (((dead[c] >> lane) & 1ull) != 0ull) || (g >= NPRE);
            unsigned long long undec = ~__ballot(deadl);
            unsigned long long kc = 0ull;
            while (undec) {
                int i = __builtin_ctzll(undec);
                kc |= (1ull << i);
                unsigned long long supm = __ballot((diag >> i) & 1ull);
                undec &= ~(supm | (1ull << i));
            }
            if (lane == 0) { keptw[c] = kc; totkept += __popcll(kc); }
        }
        __syncthreads();
        if (totkept >= NPOST) break;          // later chunks can't affect the output
        const unsigned long long kc = keptw[c];
        if (kc) {
            for (int g2 = (c + 1) * 64 + tid; g2 < GCOLS; g2 += 1024) {
                unsigned long long w = mtb[(size_t)c * GCOLS + g2] & kc;
                unsigned long long m = __ballot(w != 0ull);
                if (lane == 0 && m) atomicOr(&dead[g2 >> 6], m);
            }
        }
        __syncthreads();
    }

    if (tid == 0) {
        int pos = 0;
        for (int w = 0; w < NWORDS && pos < NPOST; ++w) {
            unsigned long long kw = keptw[w];
            while (kw && pos < NPOST) {
                int i2 = __builtin_ctzll(kw);
                sel[pos++] = w * 64 + i2;
                kw &= kw - 1;
            }
        }
        for (int w = 0; w < NWORDS && pos < NPOST; ++w) {
            int nvalid = NPRE - w * 64; if (nvalid > 64) nvalid = 64;
            unsigned long long vm = (nvalid >= 64) ? ~0ull : ((1ull << nvalid) - 1ull);
            unsigned long long sw = (~keptw[w]) & vm;
            while (sw && pos < NPOST) {
                int i2 = __builtin_ctzll(sw);
                sel[pos++] = w * 64 + i2;
                sw &= sw - 1;
            }
        }
    }
    __syncthreads();
    for (int s2 = tid; s2 < NPOST; s2 += 1024) {
        int i = sel[s2];
        float4 bx = ((const float4*)bk)[(size_t)b * NPRE + i];
        ((float4*)(out + OUT_ROIS))[b * NPOST + s2] = bx;
        out[OUT_RIDX + b * NPOST + s2] = (float)b;
    }
}

// ---------------- launch ----------------
extern "C" void kernel_launch(void* const* d_in, const int* in_sizes, int n_in,
                              void* d_out, int out_size, void* d_ws, size_t ws_size,
                              hipStream_t stream) {
    const float* x = (const float*)d_in[0];
    const float* conv1_w = (const float*)d_in[1];
    const float* conv1_b = (const float*)d_in[2];
    const float* score_w = (const float*)d_in[3];
    const float* score_b = (const float*)d_in[4];
    const float* loc_w = (const float*)d_in[5];
    const float* loc_b = (const float*)d_in[6];
    const int* ihp = (const int*)d_in[7];
    const int* iwp = (const int*)d_in[8];
    float* out = (float*)d_out;
    char* ws = (char*)d_ws;
    float* h = (float*)(ws + H_OFF);
    _Float16* w3h = (_Float16*)(ws + WT_OFF);
    _Float16* w3l = (_Float16*)(ws + WT_OFF + 1179648ul);
    float* boxes = (float*)(ws + BOX_OFF);
    unsigned int* ubuf = (unsigned int*)(ws + U_OFF);
    unsigned long long* ckeys = (unsigned long long*)(ws + CK_OFF);
    unsigned int* cc = (unsigned int*)(ws + CC_OFF);
    float* bk = (float*)(ws + BK_OFF);
    unsigned long long* MT = (unsigned long long*)(ws + M_OFF);

    hipLaunchKernelGGL(k_prep_w, dim3(2304), dim3(256), 0, stream, conv1_w, w3h, w3l);
    hipLaunchKernelGGL(k_anchors, dim3(144), dim3(256), 0, stream, out, cc);
    hipLaunchKernelGGL(k_conv1m, dim3(32, 8), dim3(1024), 0, stream, x, w3h, w3l, conv1_b, h);
    hipLaunchKernelGGL(k_heads, dim3(32, 8), dim3(256), 0, stream,
                       h, loc_w, score_w, loc_b, score_b, ihp, iwp, out, boxes, ubuf);
    hipLaunchKernelGGL(k_select, dim3(8), dim3(1024), 0, stream, ubuf, ckeys, cc);
    // segment-decomposed bitonic sort (bit-identical network, 4x CU parallelism)
    hipLaunchKernelGGL(k_sort_loc, dim3(4, 8), dim3(256), 0, stream, ckeys, cc);
    hipLaunchKernelGGL(k_sort_gmerge, dim3(16, 8), dim3(256), 0, stream, ckeys, 2048, 4096);
    hipLaunchKernelGGL(k_sort_tail, dim3(4, 8), dim3(256), 0, stream, ckeys, 4096, boxes, bk, 0);
    hipLaunchKernelGGL(k_sort_gmerge, dim3(16, 8), dim3(256), 0, stream, ckeys, 4096, 8192);
    hipLaunchKernelGGL(k_sort_gmerge, dim3(16, 8), dim3(256), 0, stream, ckeys, 2048, 8192);
    hipLaunchKernelGGL(k_sort_tail, dim3(4, 8), dim3(256), 0, stream, ckeys, 8192, boxes, bk, 1);
    // speculative low rows -> NMS try -> (conditional) high rows -> (conditional) full NMS
    hipLaunchKernelGGL(k_mask, dim3(LOROWS, 24, 8), dim3(256), 0, stream, bk, MT, cc, 0, 0);
    hipLaunchKernelGGL(k_nms_try, dim3(8), dim3(1024), 0, stream, MT, bk, out, cc);
    hipLaunchKernelGGL(k_mask, dim3(NWORDS - LOROWS, 24, 8), dim3(256), 0, stream, bk, MT, cc, LOROWS, 1);
    hipLaunchKernelGGL(k_nms_full, dim3(8), dim3(1024), 0, stream, MT, bk, out, cc);
}

// Round 11
// 392.029 us; speedup vs baseline: 1.5254x; 1.1234x over previous
//
#include <hip/hip_runtime.h>
#include <cstdint>
#include <cstddef>

// ---------------- problem constants ----------------
#define NBATCH 8
#define MID 256
#define HIMG 64
#define WIMG 64
#define NA 9
#define NPRE 6000
#define NPOST 300
#define NANCH (HIMG*WIMG*NA)   // 36864
#define NWORDS 94              // ceil(6000/64)
#define GCOLS 6016             // 94*64 padded columns
#define LOROWS 16              // speculative mask rows for the NMS early-break fast path

// output float offsets
#define OUT_LOC   0
#define OUT_SCORE 1179648
#define OUT_ROIS  1769472
#define OUT_RIDX  1779072
#define OUT_ANCH  1781472

// workspace byte offsets
#define H_OFF    0ul
#define H_BYTES  (8ul*256*64*64*4)         // 33554432
#define WT_OFF   (H_OFF + H_BYTES)
#define WT_BYTES (2304ul*256*4)            // 2359296 = exactly w3h+w3l (half)
#define BOX_OFF  (WT_OFF + WT_BYTES)
#define BOX_BYTES (8ul*36864*4*4)          // 4718592
#define U_OFF    (BOX_OFF + BOX_BYTES)
#define U_BYTES  (8ul*36864*4)
#define CK_OFF   (U_OFF + U_BYTES)
#define CK_BYTES (8ul*8192*8)
#define CC_OFF   (CK_OFF + CK_BYTES)
#define CC_BYTES 64ul
#define BK_OFF   (CC_OFF + CC_BYTES)
#define BK_BYTES (8ul*6000*16)
#define M_OFF    (BK_OFF + BK_BYTES + 64)
#define M_BYTES  (8ul*NWORDS*GCOLS*8)      // 36.2 MB, column-major mask
// head-weight MFMA fragments live in the ckeys region (written later by k_select; disjoint lifetime)

typedef _Float16 f16x8 __attribute__((ext_vector_type(8)));
typedef _Float16 f16x4 __attribute__((ext_vector_type(4)));
typedef float f32x16 __attribute__((ext_vector_type(16)));

// ---------------- weight prep ----------------
// conv1_w -> w3{h,l}[s][kb][g][oc][8] fp16 hi/lo (64-scaled), as before.
// R11: also head weights -> wh{h,l}[kb16][g][c64][8] (54 real c, 10 zero rows), same 64-scale.
__global__ __launch_bounds__(256) void k_prep_w(const float* __restrict__ w,
                                                const float* __restrict__ loc_w,
                                                const float* __restrict__ score_w,
                                                _Float16* __restrict__ w3h,
                                                _Float16* __restrict__ w3l,
                                                _Float16* __restrict__ whh,
                                                _Float16* __restrict__ whl) {
    int idx = blockIdx.x * 256 + threadIdx.x;
    if (idx < 589824) {                        // 9*16*2*256*8 conv fragments
        int e  = idx & 7;
        int t  = idx >> 3;
        int oc = t & 255; t >>= 8;
        int g  = t & 1;   t >>= 1;
        int kb = t & 15;  t >>= 4;
        int s  = t;                            // 0..8
        int ic = kb * 16 + g * 8 + e;
        float v = w[(oc * 256 + ic) * 9 + s] * 64.0f;
        _Float16 vh = (_Float16)v;
        w3h[idx] = vh;
        w3l[idx] = (_Float16)(v - (float)vh);
    } else if (idx < 589824 + 16384) {         // 16kb * 2g * 64c * 8e head fragments
        int j = idx - 589824;
        int e  = j & 7;
        int c  = (j >> 3) & 63;
        int g  = (j >> 9) & 1;
        int kb = j >> 10;
        int k  = kb * 16 + g * 8 + e;
        float v = (c < 36) ? loc_w[c * 256 + k]
                 : ((c < 54) ? score_w[(c - 36) * 256 + k] : 0.0f);
        v *= 64.0f;
        _Float16 vh = (_Float16)v;
        whh[j] = vh;
        whl[j] = (_Float16)(v - (float)vh);
    }
}

// ---------------- anchors output (exact double->f32 like numpy) + zero counters ----------------
__global__ void k_anchors(float* __restrict__ out, unsigned int* __restrict__ cc) {
    int idx = blockIdx.x * 256 + threadIdx.x;
    if (blockIdx.x == 0 && threadIdx.x < 16) cc[threadIdx.x] = 0u;
    if (idx >= NANCH) return;
    int p = idx / 9, a = idx - p * 9;
    int y = p >> 6, xg = p & 63;
    double rr = (a < 3) ? 0.5 : ((a < 6) ? 1.0 : 2.0);
    int sj = a % 3;
    double ssc = (sj == 0) ? 8.0 : ((sj == 1) ? 16.0 : 32.0);
    double hh = 7.0 * ssc * sqrt(rr);
    double ww = 7.0 * ssc * sqrt(1.0 / rr);
    float a0 = (float)(3.5 - 0.5 * hh), a2 = (float)(3.5 + 0.5 * hh);
    float b0 = (float)(3.5 - 0.5 * ww), b2 = (float)(3.5 + 0.5 * ww);
    float* dst = out + OUT_ANCH + (size_t)idx * 4;
    dst[0] = y * 16.0f + a0;
    dst[1] = xg * 16.0f + b0;
    dst[2] = y * 16.0f + a2;
    dst[3] = xg * 16.0f + b2;
}

// ---------------- conv1 3x3 + bias + relu via fp16 hi/lo split MFMA (unchanged) ----------------
__global__ __launch_bounds__(1024) void k_conv1m(const float* __restrict__ x,
                                                 const _Float16* __restrict__ w3h,
                                                 const _Float16* __restrict__ w3l,
                                                 const float* __restrict__ bias,
                                                 float* __restrict__ h) {
    __shared__ __align__(16) _Float16 bt0[4 * 66 * 26];   // hi
    __shared__ __align__(16) _Float16 bt1[4 * 66 * 26];   // lo
    __shared__ float bsh[256];

    const int tid = threadIdx.x;
    const int lane = tid & 63;
    const int wv = tid >> 6;        // 0..15
    const int ocg = wv >> 1;        // 0..7 : oc block 32*ocg
    const int wn = wv & 1;          // 0..1 : image row y0+wn
    const int y0 = blockIdx.x * 2;
    const int n  = blockIdx.y;
    const int bl31 = lane & 31;
    const int g = lane >> 5;        // ic-subgroup for fragments

    for (int i = tid; i < 858; i += 1024) {
        ((f16x8*)bt0)[i] = (f16x8){};
        ((f16x8*)bt1)[i] = (f16x8){};
    }
    if (tid < 256) bsh[tid] = bias[tid];

    f32x16 acc[2];
#pragma unroll
    for (int j = 0; j < 2; ++j)
#pragma unroll
        for (int e = 0; e < 16; ++e) acc[j][e] = 0.0f;

    const int scol = lane;          // 0..63
    const int sr   = wv & 3;        // halo row 0..3 -> gy = y0-1+sr
    const int sg   = wv >> 2;       // ic-subgroup 0..3 (4 ic each)
    const int sgy  = y0 - 1 + sr;
    const bool gyok = (sgy >= 0) && (sgy < 64);
    const float* xrow = x + (size_t)n * 1048576 + sgy * 64 + scol;
    const int bto = (sr * 66 + scol + 1) * 26 + sg * 4;

    const int aoffl = (g * 256 + ocg * 32 + bl31) * 8;
    const _Float16* wph = w3h + aoffl;
    const _Float16* wpl = w3l + aoffl;

    float xr[4];
#pragma unroll
    for (int q = 0; q < 4; ++q)
        xr[q] = gyok ? xrow[(size_t)(sg * 4 + q) * 4096] : 0.0f;

    f16x8 AhC = *(const f16x8*)(wph);
    f16x8 AlC = *(const f16x8*)(wpl);

    for (int kb = 0; kb < 16; ++kb) {
        __syncthreads();
        {
            f16x4 hh, hl;
#pragma unroll
            for (int q = 0; q < 4; ++q) {
                float v = xr[q] * 64.0f;           // exact pow2 scale
                _Float16 vh = (_Float16)v;
                hh[q] = vh;
                hl[q] = (_Float16)(v - (float)vh); // fp16-normal residual
            }
            *(f16x4*)&bt0[bto] = hh;
            *(f16x4*)&bt1[bto] = hl;
        }
        __syncthreads();
        if (kb < 15) {
#pragma unroll
            for (int q = 0; q < 4; ++q)
                xr[q] = gyok ? xrow[(size_t)((kb + 1) * 16 + sg * 4 + q) * 4096] : 0.0f;
        }

        const int ent00 = wn * 66 + bl31;
        f16x8 Bh0C = *(const f16x8*)&bt0[ent00 * 26 + g * 8];
        f16x8 Bl0C = *(const f16x8*)&bt1[ent00 * 26 + g * 8];
        f16x8 Bh1C = *(const f16x8*)&bt0[(ent00 + 32) * 26 + g * 8];
        f16x8 Bl1C = *(const f16x8*)&bt1[(ent00 + 32) * 26 + g * 8];

        const int kbn_base = (kb < 15) ? (kb + 1) : 15;
#pragma unroll
        for (int s = 0; s < 9; ++s) {
            const int sn  = (s == 8) ? 0 : (s + 1);
            const int kbn = (s == 8) ? kbn_base : kb;
            const _Float16* phn = wph + (size_t)kbn * 4096 + (size_t)sn * 65536;
            const _Float16* pln = wpl + (size_t)kbn * 4096 + (size_t)sn * 65536;
            f16x8 AhN = *(const f16x8*)(phn);
            f16x8 AlN = *(const f16x8*)(pln);

            f16x8 Bh0N = Bh0C, Bl0N = Bl0C, Bh1N = Bh1C, Bl1N = Bl1C;
            if (s < 8) {
                const int dyn = sn / 3 - 1, dxn = sn % 3 - 1;
                const int entn = (wn + dyn + 1) * 66 + dxn + 1 + bl31;
                const int en0 = entn * 26 + g * 8;
                const int en1 = (entn + 32) * 26 + g * 8;
                Bh0N = *(const f16x8*)&bt0[en0];
                Bl0N = *(const f16x8*)&bt1[en0];
                Bh1N = *(const f16x8*)&bt0[en1];
                Bl1N = *(const f16x8*)&bt1[en1];
            }

            __builtin_amdgcn_s_setprio(1);
            acc[0] = __builtin_amdgcn_mfma_f32_32x32x16_f16(AhC, Bh0C, acc[0], 0, 0, 0);
            acc[1] = __builtin_amdgcn_mfma_f32_32x32x16_f16(AhC, Bh1C, acc[1], 0, 0, 0);
            acc[0] = __builtin_amdgcn_mfma_f32_32x32x16_f16(AhC, Bl0C, acc[0], 0, 0, 0);
            acc[1] = __builtin_amdgcn_mfma_f32_32x32x16_f16(AhC, Bl1C, acc[1], 0, 0, 0);
            acc[0] = __builtin_amdgcn_mfma_f32_32x32x16_f16(AlC, Bh0C, acc[0], 0, 0, 0);
            acc[1] = __builtin_amdgcn_mfma_f32_32x32x16_f16(AlC, Bh1C, acc[1], 0, 0, 0);
            __builtin_amdgcn_s_setprio(0);

            AhC = AhN; AlC = AlN;
            Bh0C = Bh0N; Bl0C = Bl0N; Bh1C = Bh1N; Bl1C = Bl1N;
        }
    }

    const int colw = lane & 31;
    const int rgh = (lane >> 5) * 4;
    float* hn = h + (size_t)n * 1048576 + (size_t)(y0 + wn) * 64;
#pragma unroll
    for (int pcb = 0; pcb < 2; ++pcb)
#pragma unroll
        for (int reg = 0; reg < 16; ++reg) {
            const int row = (reg & 3) + 8 * (reg >> 2) + rgh;
            const int oc = ocg * 32 + row;
            float v = acc[pcb][reg] * 2.44140625e-4f + bsh[oc];   // *2^-12
            hn[(size_t)oc * 4096 + pcb * 32 + colw] = fmaxf(v, 0.0f);
        }
}

// ---------------- 1x1 heads via MFMA (R11) ----------------
// GEMM: outb[c][px] = sum_k W[c][k] * h[k][px], c<54 (padded to 64), K=256, 128 px/block.
// Same 64-scale fp16 hi/lo 3-term emulation as conv. Decode slot-loop VERBATIM from the
// verified scalar k_heads (reads the identical outb[pl*57+c] layout).
__global__ __launch_bounds__(256) void k_headsm(const float* __restrict__ h,
                                                const _Float16* __restrict__ whh,
                                                const _Float16* __restrict__ whl,
                                                const float* __restrict__ loc_b,
                                                const float* __restrict__ score_b,
                                                const int* __restrict__ ihp,
                                                const int* __restrict__ iwp,
                                                float* __restrict__ out,
                                                float* __restrict__ boxes,
                                                unsigned int* __restrict__ ubuf) {
    __shared__ __align__(16) _Float16 bt0[128 * 18];   // [px][k] pitch 18 (16 used)
    __shared__ __align__(16) _Float16 bt1[128 * 18];
    __shared__ float outb[128 * 57];                   // [px][c] pitch 57 (identical to scalar)
    __shared__ float bsh[54];
    const int tid = threadIdx.x;
    const int lane = tid & 63;
    const int wv = tid >> 6;        // 0..3
    const int wm = wv >> 1;         // c tile 0..1 (32 c each)
    const int wpx = wv & 1;         // px half 0..1 (64 px each)
    const int ptile = blockIdx.x;   // 0..31
    const int n = blockIdx.y;
    const int pxbase = ptile * 128;
    const int bl31 = lane & 31;
    const int g = lane >> 5;

    if (tid < 54) bsh[tid] = (tid < 36) ? loc_b[tid] : score_b[tid - 36];

    f32x16 acc[2];
#pragma unroll
    for (int j = 0; j < 2; ++j)
#pragma unroll
        for (int e = 0; e < 16; ++e) acc[j][e] = 0.0f;

    const int spx = tid >> 1;            // staging px 0..127
    const int skg = (tid & 1) * 8;       // staging k subgroup 0 or 8
    const float* hp = h + (size_t)n * 1048576 + pxbase + spx;
    const int aoff = (g * 64 + wm * 32 + bl31) * 8;

    for (int kb = 0; kb < 16; ++kb) {
        __syncthreads();                 // previous bt fully consumed
        {
            f16x8 hh, hl;
#pragma unroll
            for (int q = 0; q < 8; ++q) {
                float v = hp[(size_t)(kb * 16 + skg + q) * 4096] * 64.0f;
                _Float16 vh = (_Float16)v;
                hh[q] = vh;
                hl[q] = (_Float16)(v - (float)vh);
            }
            *(f16x8*)&bt0[spx * 18 + skg] = hh;
            *(f16x8*)&bt1[spx * 18 + skg] = hl;
        }
        __syncthreads();                 // bt ready
        const _Float16* ph = whh + kb * 1024 + aoff;
        const _Float16* pl = whl + kb * 1024 + aoff;
        f16x8 Ah = *(const f16x8*)ph;
        f16x8 Al = *(const f16x8*)pl;
#pragma unroll
        for (int j = 0; j < 2; ++j) {
            const int px = wpx * 64 + j * 32 + bl31;
            f16x8 Bh = *(const f16x8*)&bt0[px * 18 + g * 8];
            f16x8 Bl = *(const f16x8*)&bt1[px * 18 + g * 8];
            acc[j] = __builtin_amdgcn_mfma_f32_32x32x16_f16(Ah, Bh, acc[j], 0, 0, 0);
            acc[j] = __builtin_amdgcn_mfma_f32_32x32x16_f16(Ah, Bl, acc[j], 0, 0, 0);
            acc[j] = __builtin_amdgcn_mfma_f32_32x32x16_f16(Al, Bh, acc[j], 0, 0, 0);
        }
    }

    // C/D layout: col = lane&31 (px), row = (reg&3)+8*(reg>>2)+4*(lane>>5) (c)
#pragma unroll
    for (int j = 0; j < 2; ++j)
#pragma unroll
        for (int reg = 0; reg < 16; ++reg) {
            const int row = (reg & 3) + 8 * (reg >> 2) + (g << 2);
            const int c = wm * 32 + row;
            if (c < 54) {
                const int px = wpx * 64 + j * 32 + bl31;
                outb[px * 57 + c] = acc[j][reg] * 2.44140625e-4f + bsh[c];  // *2^-12
            }
        }
    __syncthreads();

    // ---- decode slot-loop: VERBATIM from verified scalar k_heads ----
    const float fh = (float)(*ihp), fwid = (float)(*iwp);
    for (int slot = tid; slot < 128 * 9; slot += 256) {
        int pli = slot / 9, a = slot - pli * 9;
        int p = ptile * 128 + pli;
        int y = p >> 6, xg = p & 63;
        float l0 = outb[pli * 57 + a * 4 + 0];
        float l1 = outb[pli * 57 + a * 4 + 1];
        float l2 = outb[pli * 57 + a * 4 + 2];
        float l3 = outb[pli * 57 + a * 4 + 3];
        float s0 = outb[pli * 57 + 36 + a * 2 + 0];
        float s1 = outb[pli * 57 + 36 + a * 2 + 1];
        size_t base = (size_t)n * NANCH + (size_t)p * 9 + a;
        ((float4*)(out + OUT_LOC))[base] = make_float4(l0, l1, l2, l3);
        ((float2*)(out + OUT_SCORE))[base] = make_float2(s0, s1);
        float mx = fmaxf(s0, s1);
        float e0 = expf(s0 - mx), e1 = expf(s1 - mx);
        float fg = e1 / (e0 + e1);
        double rr = (a < 3) ? 0.5 : ((a < 6) ? 1.0 : 2.0);
        int sj = a % 3;
        double ssc = (sj == 0) ? 8.0 : ((sj == 1) ? 16.0 : 32.0);
        double hhd = 7.0 * ssc * sqrt(rr);
        double wwd = 7.0 * ssc * sqrt(1.0 / rr);
        float a0 = (float)(3.5 - 0.5 * hhd), a2 = (float)(3.5 + 0.5 * hhd);
        float b0 = (float)(3.5 - 0.5 * wwd), b2 = (float)(3.5 + 0.5 * wwd);
        float ay1 = y * 16.0f + a0, ay2 = y * 16.0f + a2;
        float ax1 = xg * 16.0f + b0, ax2 = xg * 16.0f + b2;
        float ah = ay2 - ay1, aw = ax2 - ax1;
        float acy = ay1 + 0.5f * ah, acx = ax1 + 0.5f * aw;
        float cy = l0 * ah + acy, cx = l1 * aw + acx;
        float bh = expf(l2) * ah, bw = expf(l3) * aw;
        float y1 = fminf(fmaxf(cy - 0.5f * bh, 0.f), fh);
        float x1 = fminf(fmaxf(cx - 0.5f * bw, 0.f), fwid);
        float y2 = fminf(fmaxf(cy + 0.5f * bh, 0.f), fh);
        float x2 = fminf(fmaxf(cx + 0.5f * bw, 0.f), fwid);
        ((float4*)boxes)[base] = make_float4(y1, x1, y2, x2);
        bool valid = ((y2 - y1) >= 16.0f) && ((x2 - x1) >= 16.0f);
        float sc = valid ? fg : -__builtin_inff();
        unsigned int ub = __float_as_uint(sc);
        ub = (ub & 0x80000000u) ? ~ub : (ub | 0x80000000u);
        ubuf[base] = ub;
    }
}

// ---------------- exact top-6000 per batch: wave-aggregated radix select (unchanged) ----------------
__global__ __launch_bounds__(1024) void k_select(const unsigned int* __restrict__ ubuf,
                                                 unsigned long long* __restrict__ ckeys,
                                                 unsigned int* __restrict__ cc) {
    __shared__ unsigned int hist[256];
    __shared__ unsigned int selb;
    __shared__ int rank_s;
    __shared__ unsigned int lcnt;
    const int tid = threadIdx.x;
    const int lane = tid & 63;
    const int b = blockIdx.x;
    const unsigned int* ub = ubuf + (size_t)b * NANCH;
    if (tid == 0) { rank_s = NPRE - 1; lcnt = 0; }
    unsigned int prefix = 0;
    for (int pass = 0; pass < 4; ++pass) {
        int shift = 24 - 8 * pass;
        if (tid < 256) hist[tid] = 0;
        __syncthreads();
        for (int i = tid; i < NANCH; i += 1024) {
            unsigned int u = ub[i];
            bool ok = (pass == 0) || ((u >> (shift + 8)) == (prefix >> (shift + 8)));
            unsigned int byt = (u >> shift) & 255u;
            if (pass == 0) {
                unsigned long long todo = __ballot(ok);
                while (todo) {
                    int src = __builtin_ctzll(todo);
                    unsigned int bb = __shfl(byt, src, 64);
                    unsigned long long m = __ballot(ok && (byt == bb));
                    if (lane == src) atomicAdd(&hist[bb], (unsigned int)__popcll(m));
                    todo &= ~m;
                }
            } else {
                if (ok) atomicAdd(&hist[byt], 1u);
            }
        }
        __syncthreads();
        const int r = rank_s;
        for (int off = 1; off < 256; off <<= 1) {
            unsigned int v = 0;
            if (tid < 256 && tid + off < 256) v = hist[tid + off];
            __syncthreads();
            if (tid < 256) hist[tid] += v;
            __syncthreads();
        }
        if (tid < 256) {
            unsigned int inc = hist[tid];
            unsigned int above = (tid == 255) ? 0u : hist[tid + 1];
            if ((int)inc > r && (int)above <= r) {
                selb = (unsigned int)tid;
                rank_s = r - (int)above;
            }
        }
        __syncthreads();
        prefix |= (selb << shift);
        __syncthreads();
    }
    const unsigned int ustar = prefix;
    for (int i = tid; i < NANCH; i += 1024) {
        unsigned int u = ub[i];
        bool sel2 = (u >= ustar);
        unsigned long long m = __ballot(sel2);
        if (m) {
            int src = __builtin_ctzll(m);
            unsigned int base2 = 0;
            if (lane == src) base2 = atomicAdd(&lcnt, (unsigned int)__popcll(m));
            base2 = __shfl(base2, src, 64);
            if (sel2) {
                unsigned int pos = base2 + (unsigned int)__popcll(m & ((1ull << lane) - 1ull));
                if (pos < 8192)
                    ckeys[(size_t)b * 8192 + pos] =
                        ((unsigned long long)u << 32) | (unsigned int)(0xFFFFFFFFu - (unsigned int)i);
            }
        }
    }
    __syncthreads();
    if (tid == 0) cc[b] = (lcnt > 8192u) ? 8192u : lcnt;
}

// ---------------- bitonic sort 8192 — segment-decomposed (unchanged from R10) ----------------
__device__ __forceinline__ void cswap_u64(unsigned long long& a, unsigned long long& c, bool desc) {
    bool sw = desc ? (a < c) : (a > c);
    unsigned long long t0 = sw ? c : a;
    unsigned long long t1 = sw ? a : c;
    a = t0; c = t1;
}
__device__ __forceinline__ void net8(unsigned long long v[8], bool d) {
    cswap_u64(v[0], v[4], d); cswap_u64(v[1], v[5], d); cswap_u64(v[2], v[6], d); cswap_u64(v[3], v[7], d);
    cswap_u64(v[0], v[2], d); cswap_u64(v[1], v[3], d); cswap_u64(v[4], v[6], d); cswap_u64(v[5], v[7], d);
    cswap_u64(v[0], v[1], d); cswap_u64(v[2], v[3], d); cswap_u64(v[4], v[5], d); cswap_u64(v[6], v[7], d);
}
__device__ __forceinline__ unsigned long long shfl_xor_u64(unsigned long long x, int lmask) {
    unsigned int lo = (unsigned int)x, hi = (unsigned int)(x >> 32);
    lo = __shfl_xor(lo, lmask, 64);
    hi = __shfl_xor(hi, lmask, 64);
    return ((unsigned long long)hi << 32) | lo;
}

__global__ __launch_bounds__(256) void k_sort_loc(unsigned long long* __restrict__ ckeys,
                                                  const unsigned int* __restrict__ cc) {
    __shared__ unsigned long long S[2048];
    const int tid = threadIdx.x;
    const int seg = blockIdx.x;        // 0..3
    const int b = blockIdx.y;
    const int cnt = (int)cc[b];
    const int gbase = seg * 2048 + tid * 8;
    const int lb = tid * 8;
    unsigned long long* ck = ckeys + (size_t)b * 8192;

    unsigned long long v[8];
#pragma unroll
    for (int e = 0; e < 8; ++e) {
        int i = gbase + e;
        v[e] = (i < cnt) ? ck[i] : 0ull;
    }
    cswap_u64(v[0], v[1], true);  cswap_u64(v[2], v[3], false);
    cswap_u64(v[4], v[5], true);  cswap_u64(v[6], v[7], false);
    cswap_u64(v[0], v[2], true);  cswap_u64(v[1], v[3], true);
    cswap_u64(v[4], v[6], false); cswap_u64(v[5], v[7], false);
    cswap_u64(v[0], v[1], true);  cswap_u64(v[2], v[3], true);
    cswap_u64(v[4], v[5], false); cswap_u64(v[6], v[7], false);
    net8(v, (gbase & 8) == 0);

    for (int k = 16; k <= 2048; k <<= 1) {
        for (int j = k >> 1; j >= 8; j >>= 1) {
            const bool keep_max = (((gbase & k) == 0) != ((gbase & j) != 0));
            if (j >= 512) {
                __syncthreads();
#pragma unroll
                for (int e = 0; e < 8; ++e) S[lb + e] = v[e];
                __syncthreads();
                const int pb = lb ^ j;
#pragma unroll
                for (int e = 0; e < 8; ++e) {
                    unsigned long long p = S[pb + e];
                    v[e] = keep_max ? (v[e] >= p ? v[e] : p) : (v[e] <= p ? v[e] : p);
                }
            } else {
                const int lmask = j >> 3;
#pragma unroll
                for (int e = 0; e < 8; ++e) {
                    unsigned long long p = shfl_xor_u64(v[e], lmask);
                    v[e] = keep_max ? (v[e] >= p ? v[e] : p) : (v[e] <= p ? v[e] : p);
                }
            }
        }
        net8(v, (gbase & k) == 0);
    }
#pragma unroll
    for (int e = 0; e < 8; ++e) ck[gbase + e] = v[e];
}

__global__ __launch_bounds__(256) void k_sort_gmerge(unsigned long long* __restrict__ ckeys,
                                                     int j, int k) {
    const int t = blockIdx.x * 256 + threadIdx.x;   // pair index 0..4095
    const int b = blockIdx.y;
    const int i = ((t & ~(j - 1)) << 1) | (t & (j - 1));
    const int l = i | j;
    unsigned long long* ck = ckeys + (size_t)b * 8192;
    unsigned long long a = ck[i], c = ck[l];
    const bool desc = ((i & k) == 0);
    bool sw = desc ? (a < c) : (a > c);
    if (sw) { ck[i] = c; ck[l] = a; }
}

__global__ __launch_bounds__(256) void k_sort_tail(unsigned long long* __restrict__ ckeys,
                                                   int k,
                                                   const float* __restrict__ boxes,
                                                   float* __restrict__ bk,
                                                   int dogather) {
    __shared__ unsigned long long S[2048];
    const int tid = threadIdx.x;
    const int seg = blockIdx.x;
    const int b = blockIdx.y;
    const int gbase = seg * 2048 + tid * 8;
    const int lb = tid * 8;
    unsigned long long* ck = ckeys + (size_t)b * 8192;

    unsigned long long v[8];
#pragma unroll
    for (int e = 0; e < 8; ++e) v[e] = ck[gbase + e];

    for (int j = 1024; j >= 8; j >>= 1) {
        const bool keep_max = (((gbase & k) == 0) != ((gbase & j) != 0));
        if (j >= 512) {
            __syncthreads();
#pragma unroll
            for (int e = 0; e < 8; ++e) S[lb + e] = v[e];
            __syncthreads();
            const int pb = lb ^ j;
#pragma unroll
            for (int e = 0; e < 8; ++e) {
                unsigned long long p = S[pb + e];
                v[e] = keep_max ? (v[e] >= p ? v[e] : p) : (v[e] <= p ? v[e] : p);
            }
        } else {
            const int lmask = j >> 3;
#pragma unroll
            for (int e = 0; e < 8; ++e) {
                unsigned long long p = shfl_xor_u64(v[e], lmask);
                v[e] = keep_max ? (v[e] >= p ? v[e] : p) : (v[e] <= p ? v[e] : p);
            }
        }
    }
    net8(v, (gbase & k) == 0);

    if (!dogather) {
#pragma unroll
        for (int e = 0; e < 8; ++e) ck[gbase + e] = v[e];
    } else {
#pragma unroll
        for (int e = 0; e < 8; ++e) {
            int i = gbase + e;
            if (i < NPRE) {
                unsigned int idx = 0xFFFFFFFFu - (unsigned int)(v[e] & 0xFFFFFFFFull);
                if (idx >= NANCH) idx = NANCH - 1;   // safety
                float4 bx = ((const float4*)boxes)[(size_t)b * NANCH + idx];
                ((float4*)bk)[(size_t)b * NPRE + i] = bx;
            }
        }
    }
}

// ---------------- IoU bitmask, COLUMN-major — division-free bit-exact predicate ----------------
__global__ __launch_bounds__(256) void k_mask(const float* __restrict__ bk,
                                              unsigned long long* __restrict__ MT,
                                              const unsigned int* __restrict__ cc,
                                              int iwbase, int checkdone) {
    const int iw = iwbase + blockIdx.x;
    const int gb = blockIdx.y;
    const int b = blockIdx.z;
    if (checkdone && cc[8 + b] != 0u) return;   // speculation succeeded; rows not needed
    if (iw > 4 * gb + 3) return;
    const int tid = threadIdx.x;
    __shared__ float4 jb[64];
    __shared__ float ja[64];
    if (tid < 64) {
        int j = iw * 64 + tid;
        float4 v = (j < NPRE) ? ((const float4*)bk)[(size_t)b * NPRE + j]
                              : make_float4(0.f, 0.f, 0.f, 0.f);
        jb[tid] = v;
        ja[tid] = (v.z - v.x) * (v.w - v.y);
    }
    __syncthreads();
    const int g = gb * 256 + tid;
    float4 bi = (g < NPRE) ? ((const float4*)bk)[(size_t)b * NPRE + g]
                           : make_float4(0.f, 0.f, 0.f, 0.f);
    float ai = (bi.z - bi.x) * (bi.w - bi.y);
    const double MD = (double)0.7f + 0x1p-25;   // exact rounding midpoint
    unsigned long long word = 0ull;
#pragma unroll 8
    for (int jj = 0; jj < 64; ++jj) {
        float4 bj = jb[jj];
        float aj = ja[jj];
        float ty = fmaxf(bi.x, bj.x), tx = fmaxf(bi.y, bj.y);
        float by = fminf(bi.z, bj.z), bx = fminf(bi.w, bj.w);
        float ihh = fmaxf(by - ty, 0.f), iww = fmaxf(bx - tx, 0.f);
        float inter = ihh * iww;
        float den = ai + aj - inter + 1e-9f;
        if ((double)inter >= MD * (double)den) word |= (1ull << jj);
    }
    if (g < GCOLS)
        MT[((size_t)b * NWORDS + iw) * GCOLS + g] = word;
}

// ---------------- greedy NMS, speculative try over first LOROWS chunks ----------------
__global__ __launch_bounds__(1024) void k_nms_try(const unsigned long long* __restrict__ MT,
                                                  const float* __restrict__ bk,
                                                  float* __restrict__ out,
                                                  unsigned int* __restrict__ cc) {
    const int b = blockIdx.x;
    const int tid = threadIdx.x;
    const int lane = tid & 63;
    __shared__ unsigned long long keptw[NWORDS];
    __shared__ unsigned long long dead[LOROWS];
    __shared__ int sel[NPOST];
    __shared__ int totkept;
    const unsigned long long* mtb = MT + (size_t)b * NWORDS * GCOLS;

    for (int i = tid; i < NWORDS; i += 1024) keptw[i] = 0ull;
    if (tid < LOROWS) dead[tid] = 0ull;
    if (tid == 0) totkept = 0;
    __syncthreads();

    for (int c = 0; c < LOROWS; ++c) {
        if (tid < 64) {   // wave 0: in-chunk greedy closure
            const int g = c * 64 + lane;
            unsigned long long diag = mtb[(size_t)c * GCOLS + g];
            bool deadl = (((dead[c] >> lane) & 1ull) != 0ull) || (g >= NPRE);
            unsigned long long undec = ~__ballot(deadl);
            unsigned long long kc = 0ull;
            while (undec) {
                int i = __builtin_ctzll(undec);
                kc |= (1ull << i);
                unsigned long long supm = __ballot((diag >> i) & 1ull);
                undec &= ~(supm | (1ull << i));
            }
            if (lane == 0) { keptw[c] = kc; totkept += __popcll(kc); }
        }
        __syncthreads();
        if (totkept >= NPOST) break;          // later chunks can't affect the output
        const unsigned long long kc = keptw[c];
        if (kc) {
            for (int g2 = (c + 1) * 64 + tid; g2 < LOROWS * 64; g2 += 1024) {
                unsigned long long w = mtb[(size_t)c * GCOLS + g2] & kc;
                unsigned long long m = __ballot(w != 0ull);
                if (lane == 0 && m) atomicOr(&dead[g2 >> 6], m);
            }
        }
        __syncthreads();
    }

    const int done = (totkept >= NPOST) ? 1 : 0;
    if (tid == 0) cc[8 + b] = (unsigned int)done;
    if (!done) return;                        // fall back to k_mask(hi) + k_nms_full

    if (tid == 0) {
        int pos = 0;
        for (int w = 0; w < NWORDS && pos < NPOST; ++w) {
            unsigned long long kw = keptw[w];
            while (kw && pos < NPOST) {
                int i2 = __builtin_ctzll(kw);
                sel[pos++] = w * 64 + i2;
                kw &= kw - 1;
            }
        }
    }
    __syncthreads();
    for (int s2 = tid; s2 < NPOST; s2 += 1024) {
        int i = sel[s2];
        float4 bx = ((const float4*)bk)[(size_t)b * NPRE + i];
        ((float4*)(out + OUT_ROIS))[b * NPOST + s2] = bx;
        out[OUT_RIDX + b * NPOST + s2] = (float)b;
    }
}

// ---------------- full greedy NMS fallback (runs only when try didn't finish) ----------------
__global__ __launch_bounds__(1024) void k_nms_full(const unsigned long long* __restrict__ MT,
                                                   const float* __restrict__ bk,
                                                   float* __restrict__ out,
                                                   const unsigned int* __restrict__ cc) {
    const int b = blockIdx.x;
    if (cc[8 + b] != 0u) return;              // speculation succeeded
    const int tid = threadIdx.x;
    const int lane = tid & 63;
    __shared__ unsigned long long keptw[NWORDS];
    __shared__ unsigned long long dead[NWORDS];
    __shared__ int sel[NPOST];
    __shared__ int totkept;
    const unsigned long long* mtb = MT + (size_t)b * NWORDS * GCOLS;

    for (int i = tid; i < NWORDS; i += 1024) { dead[i] = 0ull; keptw[i] = 0ull; }
    if (tid == 0) totkept = 0;
    __syncthreads();

    for (int c = 0; c < NWORDS; ++c) {
        if (tid < 64) {   // wave 0: in-chunk greedy closure
            const int g = c * 64 + lane;
            unsigned long long diag = mtb[(size_t)c * GCOLS + g];
            bool deadl = (((dead[c] >> lane) & 1ull) != 0ull) || (g >= NPRE);
            unsigned long long undec = ~__ballot(deadl);
            unsigned long long kc = 0ull;
            while (undec) {
                int i = __builtin_ctzll(undec);
                kc |= (1ull << i);
                unsigned long long supm = __ballot((diag >> i) & 1ull);
                undec &= ~(supm | (1ull << i));
            }
            if (lane == 0) { keptw[c] = kc; totkept += __popcll(kc); }
        }
        __syncthreads();
        if (totkept >= NPOST) break;          // later chunks can't affect the output
        const unsigned long long kc = keptw[c];
        if (kc) {
            for (int g2 = (c + 1) * 64 + tid; g2 < GCOLS; g2 += 1024) {
                unsigned long long w = mtb[(size_t)c * GCOLS + g2] & kc;
                unsigned long long m = __ballot(w != 0ull);
                if (lane == 0 && m) atomicOr(&dead[g2 >> 6], m);
            }
        }
        __syncthreads();
    }

    if (tid == 0) {
        int pos = 0;
        for (int w = 0; w < NWORDS && pos < NPOST; ++w) {
            unsigned long long kw = keptw[w];
            while (kw && pos < NPOST) {
                int i2 = __builtin_ctzll(kw);
                sel[pos++] = w * 64 + i2;
                kw &= kw - 1;
            }
        }
        for (int w = 0; w < NWORDS && pos < NPOST; ++w) {
            int nvalid = NPRE - w * 64; if (nvalid > 64) nvalid = 64;
            unsigned long long vm = (nvalid >= 64) ? ~0ull : ((1ull << nvalid) - 1ull);
            unsigned long long sw = (~keptw[w]) & vm;
            while (sw && pos < NPOST) {
                int i2 = __builtin_ctzll(sw);
                sel[pos++] = w * 64 + i2;
                sw &= sw - 1;
            }
        }
    }
    __syncthreads();
    for (int s2 = tid; s2 < NPOST; s2 += 1024) {
        int i = sel[s2];
        float4 bx = ((const float4*)bk)[(size_t)b * NPRE + i];
        ((float4*)(out + OUT_ROIS))[b * NPOST + s2] = bx;
        out[OUT_RIDX + b * NPOST + s2] = (float)b;
    }
}

// ---------------- launch ----------------
extern "C" void kernel_launch(void* const* d_in, const int* in_sizes, int n_in,
                              void* d_out, int out_size, void* d_ws, size_t ws_size,
                              hipStream_t stream) {
    const float* x = (const float*)d_in[0];
    const float* conv1_w = (const float*)d_in[1];
    const float* conv1_b = (const float*)d_in[2];
    const float* score_w = (const float*)d_in[3];
    const float* score_b = (const float*)d_in[4];
    const float* loc_w = (const float*)d_in[5];
    const float* loc_b = (const float*)d_in[6];
    const int* ihp = (const int*)d_in[7];
    const int* iwp = (const int*)d_in[8];
    float* out = (float*)d_out;
    char* ws = (char*)d_ws;
    float* h = (float*)(ws + H_OFF);
    _Float16* w3h = (_Float16*)(ws + WT_OFF);
    _Float16* w3l = (_Float16*)(ws + WT_OFF + 1179648ul);
    float* boxes = (float*)(ws + BOX_OFF);
    unsigned int* ubuf = (unsigned int*)(ws + U_OFF);
    unsigned long long* ckeys = (unsigned long long*)(ws + CK_OFF);
    unsigned int* cc = (unsigned int*)(ws + CC_OFF);
    float* bk = (float*)(ws + BK_OFF);
    unsigned long long* MT = (unsigned long long*)(ws + M_OFF);
    // head-weight fragments: stored in ckeys region (64KB << 512KB; lifetime ends before k_select)
    _Float16* whh = (_Float16*)(ws + CK_OFF);
    _Float16* whl = (_Float16*)(ws + CK_OFF + 32768ul);

    hipLaunchKernelGGL(k_prep_w, dim3(2368), dim3(256), 0, stream,
                       conv1_w, loc_w, score_w, w3h, w3l, whh, whl);
    hipLaunchKernelGGL(k_anchors, dim3(144), dim3(256), 0, stream, out, cc);
    hipLaunchKernelGGL(k_conv1m, dim3(32, 8), dim3(1024), 0, stream, x, w3h, w3l, conv1_b, h);
    hipLaunchKernelGGL(k_headsm, dim3(32, 8), dim3(256), 0, stream,
                       h, whh, whl, loc_b, score_b, ihp, iwp, out, boxes, ubuf);
    hipLaunchKernelGGL(k_select, dim3(8), dim3(1024), 0, stream, ubuf, ckeys, cc);
    // segment-decomposed bitonic sort (bit-identical network, 4x CU parallelism)
    hipLaunchKernelGGL(k_sort_loc, dim3(4, 8), dim3(256), 0, stream, ckeys, cc);
    hipLaunchKernelGGL(k_sort_gmerge, dim3(16, 8), dim3(256), 0, stream, ckeys, 2048, 4096);
    hipLaunchKernelGGL(k_sort_tail, dim3(4, 8), dim3(256), 0, stream, ckeys, 4096, boxes, bk, 0);
    hipLaunchKernelGGL(k_sort_gmerge, dim3(16, 8), dim3(256), 0, stream, ckeys, 4096, 8192);
    hipLaunchKernelGGL(k_sort_gmerge, dim3(16, 8), dim3(256), 0, stream, ckeys, 2048, 8192);
    hipLaunchKernelGGL(k_sort_tail, dim3(4, 8), dim3(256), 0, stream, ckeys, 8192, boxes, bk, 1);
    // speculative low rows -> NMS try -> (conditional) high rows -> (conditional) full NMS
    hipLaunchKernelGGL(k_mask, dim3(LOROWS, 24, 8), dim3(256), 0, stream, bk, MT, cc, 0, 0);
    hipLaunchKernelGGL(k_nms_try, dim3(8), dim3(1024), 0, stream, MT, bk, out, cc);
    hipLaunchKernelGGL(k_mask, dim3(NWORDS - LOROWS, 24, 8), dim3(256), 0, stream, bk, MT, cc, LOROWS, 1);
    hipLaunchKernelGGL(k_nms_full, dim3(8), dim3(1024), 0, stream, MT, bk, out, cc);
}